// Round 15
// baseline (723.297 us; speedup 1.0000x reference)
//
#include <hip/hip_runtime.h>
#include <float.h>
#include <math.h>
#include <stdint.h>

#define LT 1360
#define BB 4
#define DM 512
#define NHH 8
#define NBLE 2785280   // BB*LT*512 elements
#define MBW 24         // mask words (uint64) per row
#define QSCALE 0.18033688f   // 0.125 * log2(e)
#define NFLASH 704     // flash blocks in fused attention dispatch (32 bh x 22 qt)

typedef __attribute__((ext_vector_type(8))) short short8;
typedef __attribute__((ext_vector_type(4))) float f32x4;
typedef unsigned long long u64;

__device__ __forceinline__ ushort f2b(float x){
    uint32_t u = __float_as_uint(x);
    return (ushort)((u + 0x7fffu + ((u >> 16) & 1u)) >> 16);
}
__device__ __forceinline__ float b2f(ushort u){
    return __uint_as_float(((uint32_t)u) << 16);
}
// raw v_exp_f32 (2^x). Safe here: masked-out lanes cndmask to 0, live lanes bounded.
__device__ __forceinline__ float ex2(float x){
    float r;
    asm("v_exp_f32 %0, %1" : "=v"(r) : "v"(x));
    return r;
}
// packed f32x2 -> bf16x2, RNE (same rounding as f2b)
__device__ __forceinline__ uint32_t pkbf(float lo, float hi){
    uint32_t r;
    asm("v_cvt_pk_bf16_f32 %0, %1, %2" : "=v"(r) : "v"(lo), "v"(hi));
    return r;
}

// semantic sim buffer layout (per batch)
#define SG0 0
#define SG1 1048576
#define SG2 (SG1 + 65536)
#define SG3 (SG2 + 4096)
#define SBT (SG3 + 256)

__device__ __forceinline__ void blk_info(int i, int& bi, int& st, int& n){
    if (i < 1024){ bi = 0; st = 0;    n = 1024; }
    else if (i < 1280){ bi = 1; st = 1024; n = 256; }
    else if (i < 1344){ bi = 2; st = 1280; n = 64; }
    else { bi = 3; st = 1344; n = 16; }
}

// ---------------- temporal allowed-index lists (padded to 12 for speculative loads)
__global__ __launch_bounds__(256)
void build_tidx(int* __restrict__ idx, int* __restrict__ cnt){
    int i = blockIdx.x * 256 + threadIdx.x;
    if (i >= LT) return;
    int bi, st, n; blk_info(i, bi, st, n);
    int c = 0; int* row = idx + i * 12;
    int lo = (i - 2 > st) ? i - 2 : st;
    int hi = (i + 2 < st + n - 1) ? i + 2 : st + n - 1;
    for (int j = lo; j <= hi; j++) row[c++] = j;
    if (bi < 3) row[c++] = st + n + (i - st) / 4;
    if (bi > 0){
        int stc = st - n * 4;
        int base = stc + (i - st) * 4;
        for (int t = 0; t < 4; t++) row[c++] = base + t;
    }
    cnt[i] = c;
    for (int t = c; t < 12; t++) row[t] = 0;   // safe pad
}

// ---------------- weight transpose+cast: Wd[n*K+k] = bf16(Ws[k*N+n])
__global__ __launch_bounds__(256)
void wtrans(const float* __restrict__ W, ushort* __restrict__ Wt, int K, int N, long dstStride){
    int mat = blockIdx.z;
    const float* Ws = W + (size_t)mat * K * N;
    ushort* Wd = Wt + (size_t)mat * dstStride;
    int k0 = blockIdx.y << 6, n0 = blockIdx.x << 6;
    __shared__ ushort t[64][72];
    int tid = threadIdx.x;
    #pragma unroll
    for (int p = 0; p < 4; p++){
        int idx = tid + (p << 8);
        int r = idx >> 4, c4 = (idx & 15) << 2;
        float4 v = *(const float4*)(Ws + (size_t)(k0 + r) * N + n0 + c4);
        t[c4+0][r] = f2b(v.x); t[c4+1][r] = f2b(v.y);
        t[c4+2][r] = f2b(v.z); t[c4+3][r] = f2b(v.w);
    }
    __syncthreads();
    #pragma unroll
    for (int p = 0; p < 4; p++){
        int idx = tid + (p << 8);
        int r = idx >> 4, c4 = (idx & 15) << 2;
        *(uint2*)&Wd[(size_t)(n0 + r) * K + k0 + c4] = *(uint2*)&t[r][c4];
    }
}

// ---------------- conv weight repack+cast
__global__ __launch_bounds__(256)
void wconv(const float* __restrict__ cw, ushort* __restrict__ wt){
    int conv = blockIdx.y;
    const float* src = cw + (size_t)conv * 512 * 512 * 4;
    ushort* dst = wt + (size_t)conv * 2048 * 512;
    int idx = blockIdx.x * 256 + threadIdx.x;
    int o = idx >> 11, rest = idx & 2047;
    int k = rest >> 9, ii = rest & 511;
    dst[idx] = f2b(src[((size_t)(o << 9) + ii) * 4 + k]);
}

// ---------------- merged dual-QKV GEMM: bf16 A, 64x128 tile, BK=64, reg-prefetch.
// N=3072 = [Q0|K0|V0|Q1|K1|V1]. Outputs: Q0@0, Q1@N, K0@2N, K1@3N, Vt1@4N, Vn0@5N.
__global__ __launch_bounds__(256)
void gemm_qkv(const ushort* __restrict__ A, const ushort* __restrict__ Bw,
              void* __restrict__ Cout, int M, int N, int K)
{
    __shared__ ushort As[64][72];
    __shared__ ushort Bs[128][72];
    int tid = threadIdx.x;
    int lane = tid & 63, w = tid >> 6, quad = lane >> 4, l15 = lane & 15;
    int gm = blockIdx.y << 6, gn = blockIdx.x << 7;
    int arow = tid >> 2, ac = (tid & 3) << 4;
    int brow = tid >> 1, bc = (tid & 1) << 5;
    f32x4 acc[4][2];
    #pragma unroll
    for (int mi = 0; mi < 4; mi++)
        #pragma unroll
        for (int ni = 0; ni < 2; ni++)
            acc[mi][ni] = (f32x4){0.f,0.f,0.f,0.f};
    const ushort* Ap = A + (size_t)(gm + arow) * K + ac;
    const ushort* Bp = Bw + (size_t)(gn + brow) * K + bc;
    uint4 a0r = *(const uint4*)(Ap);
    uint4 a1r = *(const uint4*)(Ap + 8);
    uint4 b0r = *(const uint4*)(Bp);
    uint4 b1r = *(const uint4*)(Bp + 8);
    uint4 b2r = *(const uint4*)(Bp + 16);
    uint4 b3r = *(const uint4*)(Bp + 24);
    *(uint4*)&As[arow][ac]     = a0r;  *(uint4*)&As[arow][ac + 8]  = a1r;
    *(uint4*)&Bs[brow][bc]     = b0r;  *(uint4*)&Bs[brow][bc + 8]  = b1r;
    *(uint4*)&Bs[brow][bc + 16] = b2r; *(uint4*)&Bs[brow][bc + 24] = b3r;
    __syncthreads();
    for (int k0 = 0; k0 < K; k0 += 64){
        bool nx = (k0 + 64 < K);
        if (nx){
            a0r = *(const uint4*)(Ap + k0 + 64);
            a1r = *(const uint4*)(Ap + k0 + 72);
            b0r = *(const uint4*)(Bp + k0 + 64);
            b1r = *(const uint4*)(Bp + k0 + 72);
            b2r = *(const uint4*)(Bp + k0 + 80);
            b3r = *(const uint4*)(Bp + k0 + 88);
        }
        __builtin_amdgcn_s_setprio(1);
        #pragma unroll
        for (int kk = 0; kk < 2; kk++){
            short8 af[4], bf[2];
            #pragma unroll
            for (int mi = 0; mi < 4; mi++)
                af[mi] = *(const short8*)&As[(mi << 4) + l15][(kk << 5) + (quad << 3)];
            #pragma unroll
            for (int ni = 0; ni < 2; ni++)
                bf[ni] = *(const short8*)&Bs[(w << 5) + (ni << 4) + l15][(kk << 5) + (quad << 3)];
            #pragma unroll
            for (int mi = 0; mi < 4; mi++)
                #pragma unroll
                for (int ni = 0; ni < 2; ni++)
                    acc[mi][ni] = __builtin_amdgcn_mfma_f32_16x16x32_bf16(af[mi], bf[ni], acc[mi][ni], 0, 0, 0);
        }
        __builtin_amdgcn_s_setprio(0);
        if (nx){
            __syncthreads();
            *(uint4*)&As[arow][ac]     = a0r;  *(uint4*)&As[arow][ac + 8]  = a1r;
            *(uint4*)&Bs[brow][bc]     = b0r;  *(uint4*)&Bs[brow][bc + 8]  = b1r;
            *(uint4*)&Bs[brow][bc + 16] = b2r; *(uint4*)&Bs[brow][bc + 24] = b3r;
            __syncthreads();
        }
    }
    int seg = gn >> 9, gc = gn & 511;
    ushort* Ob = (ushort*)Cout;
    if (seg == 2){
        // branch0 V: Vn0 only (scalar stores), @5N
        #pragma unroll
        for (int mi = 0; mi < 4; mi++)
            #pragma unroll
            for (int r = 0; r < 4; r++){
                int row = gm + (mi << 4) + (quad << 2) + r;
                #pragma unroll
                for (int ni = 0; ni < 2; ni++){
                    int cloc = (w << 5) + (ni << 4) + l15;
                    Ob[(size_t)5*NBLE + (size_t)row * 512 + gc + cloc] = f2b(acc[mi][ni][r]);
                }
            }
    } else if (seg == 5){
        // branch1 V: V^T only via LDS transpose, @4N
        __syncthreads();
        #pragma unroll
        for (int mi = 0; mi < 4; mi++)
            #pragma unroll
            for (int r = 0; r < 4; r++){
                int rloc = (mi << 4) + (quad << 2) + r;
                #pragma unroll
                for (int ni = 0; ni < 2; ni++){
                    int cloc = (w << 5) + (ni << 4) + l15;
                    Bs[cloc][rloc] = f2b(acc[mi][ni][r]);
                }
            }
        __syncthreads();
        int colw = tid >> 3;            // 0..31
        int jo = (tid & 7) << 3;        // row offset within tile, 0..56
        int rr = gm + jo;
        int bb = rr / LT;
        int ii = rr - bb * LT;
        #pragma unroll
        for (int cc = 0; cc < 4; cc++){
            int c = colw + (cc << 5);   // 0..127
            uint4 tv = *(const uint4*)&Bs[c][jo];
            ushort* dst = Ob + (size_t)4*NBLE + ((size_t)(bb * 512 + gc + c)) * LT + ii;
            *(uint4*)dst = tv;
        }
    } else {
        // Q/K segments: Q0@0 (scaled), K0@2N, Q1@N (scaled), K1@3N
        size_t base = (seg == 0) ? 0 : (seg == 1) ? (size_t)2*NBLE
                    : (seg == 3) ? (size_t)NBLE : (size_t)3*NBLE;
        float scl = (seg == 0 || seg == 3) ? QSCALE : 1.f;
        #pragma unroll
        for (int mi = 0; mi < 4; mi++)
            #pragma unroll
            for (int r = 0; r < 4; r++){
                int row = gm + (mi << 4) + (quad << 2) + r;
                #pragma unroll
                for (int ni = 0; ni < 2; ni++){
                    int c5 = gc + (w << 5) + (ni << 4) + l15;
                    Ob[base + (size_t)row * 512 + c5] = f2b(acc[mi][ni][r] * scl);
                }
            }
    }
}

// ---------------- generic 64x128-tile bf16 GEMM (qkv inner loop, gemm64t
// epilogue). Dual-branch via blockIdx.z (pass same pointers for single).
// Per-output MFMA accumulation order identical to gemm64t => bit-identical.
__global__ __launch_bounds__(256)
void gemm128(const ushort* __restrict__ A0, const ushort* __restrict__ A1,
             const ushort* __restrict__ B0, const ushort* __restrict__ B1,
             const float* __restrict__ bias0, const float* __restrict__ bias1,
             const float* __restrict__ Rres, void* __restrict__ C0,
             void* __restrict__ C1, int M, int N, int K, int act, int omode)
{
    __shared__ ushort As[64][72];
    __shared__ ushort Bs[128][72];
    const ushort* A  = blockIdx.z ? A1 : A0;
    const ushort* Bw = blockIdx.z ? B1 : B0;
    const float* bias = blockIdx.z ? bias1 : bias0;
    void* Cout = blockIdx.z ? C1 : C0;
    int tid = threadIdx.x;
    int lane = tid & 63, w = tid >> 6, quad = lane >> 4, l15 = lane & 15;
    int gm = blockIdx.y << 6, gn = blockIdx.x << 7;
    int arow = tid >> 2, ac = (tid & 3) << 4;
    int brow = tid >> 1, bc = (tid & 1) << 5;
    f32x4 acc[4][2];
    #pragma unroll
    for (int mi = 0; mi < 4; mi++)
        #pragma unroll
        for (int ni = 0; ni < 2; ni++)
            acc[mi][ni] = (f32x4){0.f,0.f,0.f,0.f};
    const ushort* Ap = A + (size_t)(gm + arow) * K + ac;
    const ushort* Bp = Bw + (size_t)(gn + brow) * K + bc;
    uint4 a0r = *(const uint4*)(Ap);
    uint4 a1r = *(const uint4*)(Ap + 8);
    uint4 b0r = *(const uint4*)(Bp);
    uint4 b1r = *(const uint4*)(Bp + 8);
    uint4 b2r = *(const uint4*)(Bp + 16);
    uint4 b3r = *(const uint4*)(Bp + 24);
    *(uint4*)&As[arow][ac]     = a0r;  *(uint4*)&As[arow][ac + 8]  = a1r;
    *(uint4*)&Bs[brow][bc]     = b0r;  *(uint4*)&Bs[brow][bc + 8]  = b1r;
    *(uint4*)&Bs[brow][bc + 16] = b2r; *(uint4*)&Bs[brow][bc + 24] = b3r;
    __syncthreads();
    for (int k0 = 0; k0 < K; k0 += 64){
        bool nx = (k0 + 64 < K);
        if (nx){
            a0r = *(const uint4*)(Ap + k0 + 64);
            a1r = *(const uint4*)(Ap + k0 + 72);
            b0r = *(const uint4*)(Bp + k0 + 64);
            b1r = *(const uint4*)(Bp + k0 + 72);
            b2r = *(const uint4*)(Bp + k0 + 80);
            b3r = *(const uint4*)(Bp + k0 + 88);
        }
        __builtin_amdgcn_s_setprio(1);
        #pragma unroll
        for (int kk = 0; kk < 2; kk++){
            short8 af[4], bf[2];
            #pragma unroll
            for (int mi = 0; mi < 4; mi++)
                af[mi] = *(const short8*)&As[(mi << 4) + l15][(kk << 5) + (quad << 3)];
            #pragma unroll
            for (int ni = 0; ni < 2; ni++)
                bf[ni] = *(const short8*)&Bs[(w << 5) + (ni << 4) + l15][(kk << 5) + (quad << 3)];
            #pragma unroll
            for (int mi = 0; mi < 4; mi++)
                #pragma unroll
                for (int ni = 0; ni < 2; ni++)
                    acc[mi][ni] = __builtin_amdgcn_mfma_f32_16x16x32_bf16(af[mi], bf[ni], acc[mi][ni], 0, 0, 0);
        }
        __builtin_amdgcn_s_setprio(0);
        if (nx){
            __syncthreads();
            *(uint4*)&As[arow][ac]     = a0r;  *(uint4*)&As[arow][ac + 8]  = a1r;
            *(uint4*)&Bs[brow][bc]     = b0r;  *(uint4*)&Bs[brow][bc + 8]  = b1r;
            *(uint4*)&Bs[brow][bc + 16] = b2r; *(uint4*)&Bs[brow][bc + 24] = b3r;
            __syncthreads();
        }
    }
    #pragma unroll
    for (int mi = 0; mi < 4; mi++){
        #pragma unroll
        for (int r = 0; r < 4; r++){
            int row = gm + (mi << 4) + (quad << 2) + r;
            #pragma unroll
            for (int ni = 0; ni < 2; ni++){
                int col = gn + (w << 5) + (ni << 4) + l15;
                float v = acc[mi][ni][r];
                if (bias) v += bias[col];
                if (Rres) v += Rres[(size_t)row * N + col];
                if (act == 2){ v = fmaxf(v, 0.f); }
                if (omode == 0) ((float*)Cout)[(size_t)row * N + col] = v;
                else            ((ushort*)Cout)[(size_t)row * N + col] = f2b(v);
            }
        }
    }
}

// ---------------- bf16 MFMA GEMM, 64x64 tile, BK=64, reg-prefetch.
// ABF=1: A is bf16; ABF=0: A fp32 (converted at LDS-store time).
// Kept for the bottleneck path (fp32 A, row-remap epilogue).
template<int ABF>
__global__ __launch_bounds__(256)
void gemm64t(const void* __restrict__ Avp, const ushort* __restrict__ Bw,
             const float* __restrict__ bias, const float* __restrict__ Rres,
             void* __restrict__ Cout, int M, int N, int K,
             int act, int omode, int mpb, int orpb, int ooff)
{
    __shared__ ushort As[64][72];
    __shared__ ushort Bs[64][72];
    int tid = threadIdx.x;
    int lane = tid & 63, w = tid >> 6, quad = lane >> 4, l15 = lane & 15;
    int gm = blockIdx.y << 6, gn = blockIdx.x << 6;
    int wr = (w >> 1) << 5, wc = (w & 1) << 5;
    int srow = tid >> 2, sc = (tid & 3) << 4;
    f32x4 acc[2][2];
    #pragma unroll
    for (int mi = 0; mi < 2; mi++)
        #pragma unroll
        for (int ni = 0; ni < 2; ni++)
            acc[mi][ni] = (f32x4){0.f,0.f,0.f,0.f};
    const float*  Af = (const float*)Avp;
    const ushort* Ab = (const ushort*)Avp;
    size_t aoff = (size_t)(gm + srow) * K + sc;
    const ushort* Bp = Bw + (size_t)(gn + srow) * K + sc;
    uint4 aR0, aR1, bR0, bR1;
    float4 f0, f1, f2v, f3v;
    if (ABF){
        aR0 = *(const uint4*)(Ab + aoff);
        aR1 = *(const uint4*)(Ab + aoff + 8);
    } else {
        f0  = *(const float4*)(Af + aoff);
        f1  = *(const float4*)(Af + aoff + 4);
        f2v = *(const float4*)(Af + aoff + 8);
        f3v = *(const float4*)(Af + aoff + 12);
    }
    bR0 = *(const uint4*)(Bp);
    bR1 = *(const uint4*)(Bp + 8);
    if (!ABF){
        aR0.x = (uint32_t)f2b(f0.x)  | ((uint32_t)f2b(f0.y)  << 16);
        aR0.y = (uint32_t)f2b(f0.z)  | ((uint32_t)f2b(f0.w)  << 16);
        aR0.z = (uint32_t)f2b(f1.x)  | ((uint32_t)f2b(f1.y)  << 16);
        aR0.w = (uint32_t)f2b(f1.z)  | ((uint32_t)f2b(f1.w)  << 16);
        aR1.x = (uint32_t)f2b(f2v.x) | ((uint32_t)f2b(f2v.y) << 16);
        aR1.y = (uint32_t)f2b(f2v.z) | ((uint32_t)f2b(f2v.w) << 16);
        aR1.z = (uint32_t)f2b(f3v.x) | ((uint32_t)f2b(f3v.y) << 16);
        aR1.w = (uint32_t)f2b(f3v.z) | ((uint32_t)f2b(f3v.w) << 16);
    }
    *(uint4*)&As[srow][sc]     = aR0;
    *(uint4*)&As[srow][sc + 8] = aR1;
    *(uint4*)&Bs[srow][sc]     = bR0;
    *(uint4*)&Bs[srow][sc + 8] = bR1;
    __syncthreads();
    for (int k0 = 0; k0 < K; k0 += 64){
        bool nx = (k0 + 64 < K);
        if (nx){
            if (ABF){
                aR0 = *(const uint4*)(Ab + aoff + k0 + 64);
                aR1 = *(const uint4*)(Ab + aoff + k0 + 72);
            } else {
                f0  = *(const float4*)(Af + aoff + k0 + 64);
                f1  = *(const float4*)(Af + aoff + k0 + 68);
                f2v = *(const float4*)(Af + aoff + k0 + 72);
                f3v = *(const float4*)(Af + aoff + k0 + 76);
            }
            bR0 = *(const uint4*)(Bp + k0 + 64);
            bR1 = *(const uint4*)(Bp + k0 + 72);
        }
        __builtin_amdgcn_s_setprio(1);
        #pragma unroll
        for (int kk = 0; kk < 2; kk++){
            short8 af0 = *(const short8*)&As[wr + l15][(kk << 5) + (quad << 3)];
            short8 af1 = *(const short8*)&As[wr + 16 + l15][(kk << 5) + (quad << 3)];
            short8 bf0 = *(const short8*)&Bs[wc + l15][(kk << 5) + (quad << 3)];
            short8 bf1 = *(const short8*)&Bs[wc + 16 + l15][(kk << 5) + (quad << 3)];
            acc[0][0] = __builtin_amdgcn_mfma_f32_16x16x32_bf16(af0, bf0, acc[0][0], 0, 0, 0);
            acc[0][1] = __builtin_amdgcn_mfma_f32_16x16x32_bf16(af0, bf1, acc[0][1], 0, 0, 0);
            acc[1][0] = __builtin_amdgcn_mfma_f32_16x16x32_bf16(af1, bf0, acc[1][0], 0, 0, 0);
            acc[1][1] = __builtin_amdgcn_mfma_f32_16x16x32_bf16(af1, bf1, acc[1][1], 0, 0, 0);
        }
        __builtin_amdgcn_s_setprio(0);
        if (nx){
            __syncthreads();
            if (!ABF){
                aR0.x = (uint32_t)f2b(f0.x)  | ((uint32_t)f2b(f0.y)  << 16);
                aR0.y = (uint32_t)f2b(f0.z)  | ((uint32_t)f2b(f0.w)  << 16);
                aR0.z = (uint32_t)f2b(f1.x)  | ((uint32_t)f2b(f1.y)  << 16);
                aR0.w = (uint32_t)f2b(f1.z)  | ((uint32_t)f2b(f1.w)  << 16);
                aR1.x = (uint32_t)f2b(f2v.x) | ((uint32_t)f2b(f2v.y) << 16);
                aR1.y = (uint32_t)f2b(f2v.z) | ((uint32_t)f2b(f2v.w) << 16);
                aR1.z = (uint32_t)f2b(f3v.x) | ((uint32_t)f2b(f3v.y) << 16);
                aR1.w = (uint32_t)f2b(f3v.z) | ((uint32_t)f2b(f3v.w) << 16);
            }
            *(uint4*)&As[srow][sc]     = aR0;
            *(uint4*)&As[srow][sc + 8] = aR1;
            *(uint4*)&Bs[srow][sc]     = bR0;
            *(uint4*)&Bs[srow][sc + 8] = bR1;
            __syncthreads();
        }
    }
    #pragma unroll
    for (int mi = 0; mi < 2; mi++){
        #pragma unroll
        for (int r = 0; r < 4; r++){
            int row = gm + wr + (mi << 4) + (quad << 2) + r;
            #pragma unroll
            for (int ni = 0; ni < 2; ni++){
                int col = gn + wc + (ni << 4) + l15;
                float v = acc[mi][ni][r];
                if (bias) v += bias[col];
                if (Rres) v += Rres[(size_t)row * N + col];
                if (act == 2){ v = fmaxf(v, 0.f); }
                if (omode == 0){
                    int orow = mpb ? (row / mpb) * orpb + ooff + (row % mpb) : row;
                    ((float*)Cout)[(size_t)orow * N + col] = v;
                } else {
                    ((ushort*)Cout)[(size_t)row * N + col] = f2b(v);
                }
            }
        }
    }
}

// ---------------- split-K bf16 GEMM for tiny-M conv chain (v2: BK=64,
// register prefetch, setprio; accumulation order unchanged => bit-identical).
__global__ __launch_bounds__(256)
void gemm_sk(const float* __restrict__ A, const ushort* __restrict__ Bw,
             float* __restrict__ P, int M, int N, int K, int kslice)
{
    __shared__ ushort As[64][72];
    __shared__ ushort Bs[64][72];
    int tid = threadIdx.x;
    int lane = tid & 63, w = tid >> 6, quad = lane >> 4, l15 = lane & 15;
    int gm = blockIdx.y << 6, gn = blockIdx.x << 6;
    int wr = (w >> 1) << 5, wc = (w & 1) << 5;
    int srow = tid >> 2, sc = (tid & 3) << 4;
    int ks = blockIdx.z * kslice;
    f32x4 acc[2][2];
    #pragma unroll
    for (int mi = 0; mi < 2; mi++)
        #pragma unroll
        for (int ni = 0; ni < 2; ni++)
            acc[mi][ni] = (f32x4){0.f,0.f,0.f,0.f};
    size_t aoff = (size_t)(gm + srow) * K + ks + sc;
    const ushort* Bp = Bw + (size_t)(gn + srow) * K + ks + sc;
    uint4 aR0, aR1, bR0, bR1;
    float4 f0, f1, f2v, f3v;
    f0  = *(const float4*)(A + aoff);
    f1  = *(const float4*)(A + aoff + 4);
    f2v = *(const float4*)(A + aoff + 8);
    f3v = *(const float4*)(A + aoff + 12);
    bR0 = *(const uint4*)(Bp);
    bR1 = *(const uint4*)(Bp + 8);
    aR0.x = (uint32_t)f2b(f0.x)  | ((uint32_t)f2b(f0.y)  << 16);
    aR0.y = (uint32_t)f2b(f0.z)  | ((uint32_t)f2b(f0.w)  << 16);
    aR0.z = (uint32_t)f2b(f1.x)  | ((uint32_t)f2b(f1.y)  << 16);
    aR0.w = (uint32_t)f2b(f1.z)  | ((uint32_t)f2b(f1.w)  << 16);
    aR1.x = (uint32_t)f2b(f2v.x) | ((uint32_t)f2b(f2v.y) << 16);
    aR1.y = (uint32_t)f2b(f2v.z) | ((uint32_t)f2b(f2v.w) << 16);
    aR1.z = (uint32_t)f2b(f3v.x) | ((uint32_t)f2b(f3v.y) << 16);
    aR1.w = (uint32_t)f2b(f3v.z) | ((uint32_t)f2b(f3v.w) << 16);
    *(uint4*)&As[srow][sc]     = aR0;
    *(uint4*)&As[srow][sc + 8] = aR1;
    *(uint4*)&Bs[srow][sc]     = bR0;
    *(uint4*)&Bs[srow][sc + 8] = bR1;
    __syncthreads();
    for (int kc = 0; kc < kslice; kc += 64){
        bool nx = (kc + 64 < kslice);
        if (nx){
            f0  = *(const float4*)(A + aoff + kc + 64);
            f1  = *(const float4*)(A + aoff + kc + 68);
            f2v = *(const float4*)(A + aoff + kc + 72);
            f3v = *(const float4*)(A + aoff + kc + 76);
            bR0 = *(const uint4*)(Bp + kc + 64);
            bR1 = *(const uint4*)(Bp + kc + 72);
        }
        __builtin_amdgcn_s_setprio(1);
        #pragma unroll
        for (int kk = 0; kk < 2; kk++){
            short8 af0 = *(const short8*)&As[wr + l15][(kk << 5) + (quad << 3)];
            short8 af1 = *(const short8*)&As[wr + 16 + l15][(kk << 5) + (quad << 3)];
            short8 bf0 = *(const short8*)&Bs[wc + l15][(kk << 5) + (quad << 3)];
            short8 bf1 = *(const short8*)&Bs[wc + 16 + l15][(kk << 5) + (quad << 3)];
            acc[0][0] = __builtin_amdgcn_mfma_f32_16x16x32_bf16(af0, bf0, acc[0][0], 0, 0, 0);
            acc[0][1] = __builtin_amdgcn_mfma_f32_16x16x32_bf16(af0, bf1, acc[0][1], 0, 0, 0);
            acc[1][0] = __builtin_amdgcn_mfma_f32_16x16x32_bf16(af1, bf0, acc[1][0], 0, 0, 0);
            acc[1][1] = __builtin_amdgcn_mfma_f32_16x16x32_bf16(af1, bf1, acc[1][1], 0, 0, 0);
        }
        __builtin_amdgcn_s_setprio(0);
        if (nx){
            __syncthreads();
            aR0.x = (uint32_t)f2b(f0.x)  | ((uint32_t)f2b(f0.y)  << 16);
            aR0.y = (uint32_t)f2b(f0.z)  | ((uint32_t)f2b(f0.w)  << 16);
            aR0.z = (uint32_t)f2b(f1.x)  | ((uint32_t)f2b(f1.y)  << 16);
            aR0.w = (uint32_t)f2b(f1.z)  | ((uint32_t)f2b(f1.w)  << 16);
            aR1.x = (uint32_t)f2b(f2v.x) | ((uint32_t)f2b(f2v.y) << 16);
            aR1.y = (uint32_t)f2b(f2v.z) | ((uint32_t)f2b(f2v.w) << 16);
            aR1.z = (uint32_t)f2b(f3v.x) | ((uint32_t)f2b(f3v.y) << 16);
            aR1.w = (uint32_t)f2b(f3v.z) | ((uint32_t)f2b(f3v.w) << 16);
            *(uint4*)&As[srow][sc]     = aR0;
            *(uint4*)&As[srow][sc + 8] = aR1;
            *(uint4*)&Bs[srow][sc]     = bR0;
            *(uint4*)&Bs[srow][sc + 8] = bR1;
            __syncthreads();
        }
    }
    float* Pz = P + (size_t)blockIdx.z * M * N;
    #pragma unroll
    for (int mi = 0; mi < 2; mi++){
        #pragma unroll
        for (int r = 0; r < 4; r++){
            int row = gm + wr + (mi << 4) + (quad << 2) + r;
            #pragma unroll
            for (int ni = 0; ni < 2; ni++){
                int col = gn + wc + (ni << 4) + l15;
                Pz[(size_t)row * N + col] = acc[mi][ni][r];
            }
        }
    }
}

// ---------------- split-K reduce + bias + scaled ELU (conv epilogue)
__global__ __launch_bounds__(256)
void sk_reduce(const float* __restrict__ P, const float* __restrict__ bias,
               float* __restrict__ C, int MN, int S)
{
    int idx = (blockIdx.x * 256 + threadIdx.x) << 2;
    if (idx >= MN) return;
    float4 s = {0.f, 0.f, 0.f, 0.f};
    for (int z = 0; z < S; z++){
        float4 v = *(const float4*)(P + (size_t)z * MN + idx);
        s.x += v.x; s.y += v.y; s.z += v.z; s.w += v.w;
    }
    const float cscale = 0.9999950000375f;
    int col = idx & 511;
    float o[4] = {s.x, s.y, s.z, s.w};
    #pragma unroll
    for (int t = 0; t < 4; t++){
        float v = (o[t] + bias[col + t]) * cscale;
        o[t] = (v > 0.f) ? v : expm1f(v);
    }
    *(float4*)(C + idx) = (float4){o[0], o[1], o[2], o[3]};
}

// ---------------- semantic sim via split-bf16 MFMA (hi/lo precomputed)
// v2: register-staged prefetch + setprio on the 12-MFMA cluster.
__global__ __launch_bounds__(256)
void sim_mfma(const ushort* __restrict__ XH, const ushort* __restrict__ XL,
              float* __restrict__ SIM){
    __shared__ ushort Ah[64][40], Al[64][40], Bh[64][40], Bl[64][40];
    int x = blockIdx.x, b = blockIdx.y;
    int ti, tj, st, n, goff;
    if (x < 256){ ti = x >> 4; tj = x & 15; st = 0; n = 1024; goff = SG0; }
    else if (x < 272){ int y = x - 256; ti = y >> 2; tj = y & 3; st = 1024; n = 256; goff = SG1; }
    else if (x == 272){ ti = 0; tj = 0; st = 1280; n = 64; goff = SG2; }
    else { ti = 0; tj = 0; st = 1344; n = 16; goff = SG3; }
    const ushort* XbH = XH + (((size_t)b * LT + st) << 9);
    const ushort* XbL = XL + (((size_t)b * LT + st) << 9);
    float* Cb = SIM + (size_t)b * SBT + goff;
    int gm = ti << 6, gn = tj << 6;
    int tid = threadIdx.x;
    int lane = tid & 63, w = tid >> 6, quad = lane >> 4, l15 = lane & 15;
    int wr = (w >> 1) << 5, wc = (w & 1) << 5;
    int srow = tid >> 2, sc8 = (tid & 3) << 3;
    int ra = gm + srow; if (ra > n - 1) ra = n - 1;
    int rb = gn + srow; if (rb > n - 1) rb = n - 1;
    f32x4 acc[2][2];
    #pragma unroll
    for (int mi = 0; mi < 2; mi++)
        #pragma unroll
        for (int ni = 0; ni < 2; ni++)
            acc[mi][ni] = (f32x4){0.f,0.f,0.f,0.f};
    const ushort* pAh = XbH + ((size_t)ra << 9) + sc8;
    const ushort* pAl = XbL + ((size_t)ra << 9) + sc8;
    const ushort* pBh = XbH + ((size_t)rb << 9) + sc8;
    const ushort* pBl = XbL + ((size_t)rb << 9) + sc8;
    uint4 vah = *(const uint4*)pAh;
    uint4 val = *(const uint4*)pAl;
    uint4 vbh = *(const uint4*)pBh;
    uint4 vbl = *(const uint4*)pBl;
    *(uint4*)&Ah[srow][sc8] = vah;
    *(uint4*)&Al[srow][sc8] = val;
    *(uint4*)&Bh[srow][sc8] = vbh;
    *(uint4*)&Bl[srow][sc8] = vbl;
    __syncthreads();
    for (int k0 = 0; k0 < 512; k0 += 32){
        bool nx = (k0 + 32 < 512);
        if (nx){
            vah = *(const uint4*)(pAh + k0 + 32);
            val = *(const uint4*)(pAl + k0 + 32);
            vbh = *(const uint4*)(pBh + k0 + 32);
            vbl = *(const uint4*)(pBl + k0 + 32);
        }
        __builtin_amdgcn_s_setprio(1);
        short8 ah0 = *(const short8*)&Ah[wr + l15][quad << 3];
        short8 ah1 = *(const short8*)&Ah[wr + 16 + l15][quad << 3];
        short8 al0 = *(const short8*)&Al[wr + l15][quad << 3];
        short8 al1 = *(const short8*)&Al[wr + 16 + l15][quad << 3];
        short8 bh0 = *(const short8*)&Bh[wc + l15][quad << 3];
        short8 bh1 = *(const short8*)&Bh[wc + 16 + l15][quad << 3];
        short8 bl0 = *(const short8*)&Bl[wc + l15][quad << 3];
        short8 bl1 = *(const short8*)&Bl[wc + 16 + l15][quad << 3];
        acc[0][0] = __builtin_amdgcn_mfma_f32_16x16x32_bf16(ah0, bh0, acc[0][0], 0, 0, 0);
        acc[0][0] = __builtin_amdgcn_mfma_f32_16x16x32_bf16(ah0, bl0, acc[0][0], 0, 0, 0);
        acc[0][0] = __builtin_amdgcn_mfma_f32_16x16x32_bf16(al0, bh0, acc[0][0], 0, 0, 0);
        acc[0][1] = __builtin_amdgcn_mfma_f32_16x16x32_bf16(ah0, bh1, acc[0][1], 0, 0, 0);
        acc[0][1] = __builtin_amdgcn_mfma_f32_16x16x32_bf16(ah0, bl1, acc[0][1], 0, 0, 0);
        acc[0][1] = __builtin_amdgcn_mfma_f32_16x16x32_bf16(al0, bh1, acc[0][1], 0, 0, 0);
        acc[1][0] = __builtin_amdgcn_mfma_f32_16x16x32_bf16(ah1, bh0, acc[1][0], 0, 0, 0);
        acc[1][0] = __builtin_amdgcn_mfma_f32_16x16x32_bf16(ah1, bl0, acc[1][0], 0, 0, 0);
        acc[1][0] = __builtin_amdgcn_mfma_f32_16x16x32_bf16(al1, bh0, acc[1][0], 0, 0, 0);
        acc[1][1] = __builtin_amdgcn_mfma_f32_16x16x32_bf16(ah1, bh1, acc[1][1], 0, 0, 0);
        acc[1][1] = __builtin_amdgcn_mfma_f32_16x16x32_bf16(ah1, bl1, acc[1][1], 0, 0, 0);
        acc[1][1] = __builtin_amdgcn_mfma_f32_16x16x32_bf16(al1, bh1, acc[1][1], 0, 0, 0);
        __builtin_amdgcn_s_setprio(0);
        if (nx){
            __syncthreads();
            *(uint4*)&Ah[srow][sc8] = vah;
            *(uint4*)&Al[srow][sc8] = val;
            *(uint4*)&Bh[srow][sc8] = vbh;
            *(uint4*)&Bl[srow][sc8] = vbl;
            __syncthreads();
        }
    }
    #pragma unroll
    for (int mi = 0; mi < 2; mi++){
        #pragma unroll
        for (int r = 0; r < 4; r++){
            int row = gm + wr + (mi << 4) + (quad << 2) + r;
            if (row < n){
                #pragma unroll
                for (int ni = 0; ni < 2; ni++){
                    int col = gn + wc + (ni << 4) + l15;
                    if (col < n) Cb[(size_t)row * n + col] = acc[mi][ni][r];
                }
            }
        }
    }
}

// ---------------- concat conv pyramids
__global__ __launch_bounds__(256)
void pcat_copy(const float* __restrict__ C1, const float* __restrict__ C2,
               const float* __restrict__ C3, float* __restrict__ PC){
    int idx = blockIdx.x * 256 + threadIdx.x;
    int d = idx & 511;
    int r = (idx >> 9) % 336;
    int b = idx / (336 * 512);
    float v;
    if (r < 256)       v = C1[(((size_t)b * 256 + r) << 9) + d];
    else if (r < 320)  v = C2[(((size_t)b * 64 + (r - 256)) << 9) + d];
    else               v = C3[(((size_t)b * 16 + (r - 320)) << 9) + d];
    PC[idx] = v;
}

__global__ __launch_bounds__(256)
void xenc_copy(const float* __restrict__ xe, float* __restrict__ dst){
    int idx = blockIdx.x * 256 + threadIdx.x;
    int d = idx & 511;
    int l = (idx >> 9) & 1023;
    int b = idx >> 19;
    dst[(((size_t)b * LT + l) << 9) + d] = xe[idx];
}

// ---------------- LayerNorm over 512, wave per row; optional bf16 dual output
// + optional fused row-L2-normalize.
__global__ __launch_bounds__(256)
void ln_kernel(const float* __restrict__ in, const float* __restrict__ g,
               const float* __restrict__ bta, float* __restrict__ out,
               ushort* __restrict__ ob, ushort* __restrict__ xh,
               ushort* __restrict__ xl, float eps){
    int wid = threadIdx.x >> 6, lane = threadIdx.x & 63;
    int row = blockIdx.x * 4 + wid;
    const float* p = in + ((size_t)row << 9);
    float vals[8]; float s = 0.f, s2 = 0.f;
    #pragma unroll
    for (int t = 0; t < 8; t++){
        float v = p[lane + t * 64]; vals[t] = v; s += v; s2 += v * v;
    }
    #pragma unroll
    for (int off = 32; off; off >>= 1){
        s  += __shfl_xor(s,  off, 64);
        s2 += __shfl_xor(s2, off, 64);
    }
    float mu = s * (1.f / 512.f);
    float var = s2 * (1.f / 512.f) - mu * mu;
    float r = rsqrtf(var + eps);
    float* q = out + ((size_t)row << 9);
    ushort* qb = ob ? ob + ((size_t)row << 9) : nullptr;
    float nv[8]; float sn2 = 0.f;
    #pragma unroll
    for (int t = 0; t < 8; t++){
        int c = lane + t * 64;
        float v = (vals[t] - mu) * r * g[c] + bta[c];
        q[c] = v;
        if (qb) qb[c] = f2b(v);
        nv[t] = v; sn2 += v * v;
    }
    if (xh){
        #pragma unroll
        for (int off = 32; off; off >>= 1) sn2 += __shfl_xor(sn2, off, 64);
        float inv = 1.f / fmaxf(sqrtf(sn2), 1e-8f);
        ushort* qh = xh + ((size_t)row << 9);
        ushort* ql = xl + ((size_t)row << 9);
        #pragma unroll
        for (int t = 0; t < 8; t++){
            float v = nv[t] * inv;
            ushort h = f2b(v);
            qh[lane + t * 64] = h;
            ql[lane + t * 64] = f2b(v - b2f(h));
        }
    }
}

// ---------------- fused dual-LN + add3: X = (ln(in0) + ln(in1) + X)/3; bf16 out.
__global__ __launch_bounds__(256)
void ln2_add3(const float* __restrict__ in0, const float* __restrict__ in1,
              const float* __restrict__ g0, const float* __restrict__ b0,
              const float* __restrict__ g1, const float* __restrict__ b1,
              float* __restrict__ X, ushort* __restrict__ ob, float eps){
    int wid = threadIdx.x >> 6, lane = threadIdx.x & 63;
    int row = blockIdx.x * 4 + wid;
    const float* p0 = in0 + ((size_t)row << 9);
    const float* p1 = in1 + ((size_t)row << 9);
    float v0[8], v1[8];
    float s0 = 0.f, q0 = 0.f, s1 = 0.f, q1 = 0.f;
    #pragma unroll
    for (int t = 0; t < 8; t++){
        float a = p0[lane + t * 64]; v0[t] = a; s0 += a; q0 += a * a;
        float c = p1[lane + t * 64]; v1[t] = c; s1 += c; q1 += c * c;
    }
    #pragma unroll
    for (int off = 32; off; off >>= 1){
        s0 += __shfl_xor(s0, off, 64);
        q0 += __shfl_xor(q0, off, 64);
        s1 += __shfl_xor(s1, off, 64);
        q1 += __shfl_xor(q1, off, 64);
    }
    float mu0 = s0 * (1.f / 512.f);
    float r0 = rsqrtf(q0 * (1.f / 512.f) - mu0 * mu0 + eps);
    float mu1 = s1 * (1.f / 512.f);
    float r1 = rsqrtf(q1 * (1.f / 512.f) - mu1 * mu1 + eps);
    float* xp = X + ((size_t)row << 9);
    ushort* qb = ob + ((size_t)row << 9);
    #pragma unroll
    for (int t = 0; t < 8; t++){
        int c = lane + t * 64;
        float sn0 = (v0[t] - mu0) * r0 * g0[c] + b0[c];
        float sn1 = (v1[t] - mu1) * r1 * g1[c] + b1[c];
        float nv = (sn0 + sn1 + xp[c]) * (1.f / 3.f);
        xp[c] = nv;
        qb[c] = f2b(nv);
    }
}

// ---------------- top-k v2: per-lane bitonic sort + xor-butterfly bitonic
// top-32 merge -> exact 32nd-largest V32; ballot-built mask words.
__global__ __launch_bounds__(256)
void topk_sel(const float* __restrict__ SIM, u64* __restrict__ MB){
    int wid = threadIdx.x >> 6, lane = threadIdx.x & 63;
    int r = blockIdx.x * 4 + wid;        // 0..B*LT-1
    int b = r / LT, i = r % LT;
    int bi, st, n; blk_info(i, bi, st, n);
    u64* mrow = MB + ((size_t)b * LT + i) * MBW;
    if (n == 16){                         // all 16 in-block keys banned
        u64 myw = 0;
        if (lane == 21) myw = ~0ULL;
        if (lane < MBW) mrow[lane] = myw;
        return;
    }
    int goff = (bi == 0) ? SG0 : (bi == 1) ? SG1 : SG2;
    const float* srow = SIM + (size_t)b * SBT + goff + (size_t)(i - st) * n;
    int ns = n >> 6;
    float vals[16];
    #pragma unroll
    for (int t = 0; t < 16; t++)
        vals[t] = (t < ns) ? srow[lane + (t << 6)] : -FLT_MAX;

    float c[32];
    #pragma unroll
    for (int t = 0; t < 16; t++) c[t] = vals[t];
    #pragma unroll
    for (int k = 2; k <= 16; k <<= 1){
        #pragma unroll
        for (int j = k >> 1; j > 0; j >>= 1){
            #pragma unroll
            for (int t = 0; t < 16; t++){
                int l = t ^ j;
                if (l > t){
                    float lo = fminf(c[t], c[l]);
                    float hi = fmaxf(c[t], c[l]);
                    if ((t & k) == 0){ c[t] = hi; c[l] = lo; }
                    else             { c[t] = lo; c[l] = hi; }
                }
            }
        }
    }
    #pragma unroll
    for (int t = 16; t < 32; t++) c[t] = -FLT_MAX;

    float V32;
    #pragma unroll
    for (int rd = 0; rd < 6; rd++){
        float f[32];
        #pragma unroll
        for (int t = 0; t < 32; t++) f[t] = __shfl_xor(c[t], 1 << rd, 64);
        float m[32];
        #pragma unroll
        for (int t = 0; t < 32; t++) m[t] = fmaxf(c[t], f[31 - t]);
        if (rd < 5){
            #pragma unroll
            for (int d = 16; d >= 1; d >>= 1){
                #pragma unroll
                for (int t = 0; t < 32; t++){
                    if ((t & d) == 0){
                        float lo = fminf(m[t], m[t + d]);
                        m[t] = fmaxf(m[t], m[t + d]);
                        m[t + d] = lo;
                    }
                }
            }
            #pragma unroll
            for (int t = 0; t < 32; t++) c[t] = m[t];
        } else {
            float mn = m[0];
            #pragma unroll
            for (int t = 1; t < 32; t++) mn = fminf(mn, m[t]);
            V32 = mn;
        }
    }

    int cnt_gt = 0;
    #pragma unroll
    for (int t = 0; t < 16; t++){
        u64 bg = __ballot(vals[t] > V32);
        cnt_gt += __popcll(bg);
    }
    int need = 32 - cnt_gt;
    u64 lmask = (1ULL << lane) - 1;
    u64 myw = 0;
    if (lane == 21) myw = 0xFFFFFFFFFFFF0000ULL;   // pad: keys 1360..1407 banned
    int eqrun = 0;
    int w0 = st >> 6;
    #pragma unroll
    for (int t = 0; t < 16; t++){
        bool eq = (vals[t] == V32);
        u64 beq = __ballot(eq);
        int below = __popcll(beq & lmask);
        bool sel = (vals[t] > V32) || (eq && (eqrun + below) < need);
        eqrun += __popcll(beq);
        u64 wsel = __ballot(sel);
        if (t < ns && lane == w0 + t) myw = wsel;
    }
    if (lane < MBW) mrow[lane] = myw;
}

// ---------------- FUSED attention dispatch: blocks [0,NFLASH) run flash
// (branch 1); blocks [NFLASH, ...) run sparse temporal attention (branch 0).
// Double-buffered flash (R12-best). R13 single-buffer regressed (barrier
// serialization); do not revisit.
__global__ __launch_bounds__(256)
void attn_fused(const ushort* __restrict__ U, const u64* __restrict__ MB,
                const int* __restrict__ IDX, const int* __restrict__ CNT,
                ushort* __restrict__ AO0, ushort* __restrict__ AO1)
{
    __shared__ ushort Ks[2][64][76];
    __shared__ ushort Vs[2][64][76];
    if (blockIdx.x < NFLASH){
        // ================= flash branch (v5 body, flattened grid) =========
        const ushort* Q  = U + (size_t)NBLE;
        const ushort* Kp = U + (size_t)3*NBLE;
        const ushort* Vt = U + (size_t)4*NBLE;
        int fid = blockIdx.x;
        int bh = fid & 31, b = bh >> 3, h = bh & 7;
        int q0 = (fid >> 5) << 6;
        int tid = threadIdx.x;
        int w = tid >> 6, lane = tid & 63, quad = lane >> 4, l15 = lane & 15;

        int qm = q0 + w * 16 + l15;
        int qmc = (qm < LT) ? qm : (LT - 1);
        const ushort* qp = Q + ((size_t)(b * LT + qmc) << 9) + h * 64 + (quad << 3);
        short8 qf0 = *(const short8*)qp;
        short8 qf1 = *(const short8*)(qp + 32);

        float l_part = 0.f;
        f32x4 Oacc[4];
        #pragma unroll
        for (int dt = 0; dt < 4; dt++) Oacc[dt] = (f32x4){0.f,0.f,0.f,0.f};

        int srow = tid >> 2, sc = (tid & 3) << 4;

        const ushort* kpp = Kp + ((size_t)(b * LT + srow) << 9) + h * 64 + sc;
        const ushort* vpp = Vt + (size_t)(b * 512 + h * 64 + srow) * LT + sc;
        const u64* mpp = MB + ((size_t)b * LT + qmc) * MBW;

        int srcA = ((quad & 1) << 5) + l15;
        int srcB = srcA + 16;
        bool ntHi = (quad & 2) != 0;

        {
            uint4 k0v = *(const uint4*)kpp;
            uint4 k1v = *(const uint4*)(kpp + 8);
            uint4 v0v = *(const uint4*)vpp;
            uint4 v1v = *(const uint4*)(vpp + 8);
            kpp += 64 * 512; vpp += 64;
            *(uint4*)&Ks[0][srow][sc]     = k0v;
            *(uint4*)&Ks[0][srow][sc + 8] = k1v;
            *(uint4*)&Vs[0][srow][sc]     = v0v;
            *(uint4*)&Vs[0][srow][sc + 8] = v1v;
        }
        __syncthreads();

        for (int kt = 0; kt < 22; kt++){
            int cur = kt & 1;
            bool havenext = (kt + 1 < 22);
            uint4 kn0, kn1, vn0, vn1;
            if (havenext){
                kn0 = *(const uint4*)kpp;
                kn1 = *(const uint4*)(kpp + 8);
                vn0 = *(const uint4*)vpp;
                vn1 = *(const uint4*)(vpp + 8);
                kpp += 64 * 512; vpp += 64;
            }
            u64 mw = mpp[kt];
            f32x4 s[4];
            #pragma unroll
            for (int nt = 0; nt < 4; nt++) s[nt] = (f32x4){0.f,0.f,0.f,0.f};
            __builtin_amdgcn_s_setprio(1);
            #pragma unroll
            for (int nt = 0; nt < 4; nt++){
                short8 kf0 = *(const short8*)&Ks[cur][(nt << 4) + l15][quad << 3];
                short8 kf1 = *(const short8*)&Ks[cur][(nt << 4) + l15][32 + (quad << 3)];
                s[nt] = __builtin_amdgcn_mfma_f32_16x16x32_bf16(kf0, qf0, s[nt], 0, 0, 0);
                s[nt] = __builtin_amdgcn_mfma_f32_16x16x32_bf16(kf1, qf1, s[nt], 0, 0, 0);
            }
            __builtin_amdgcn_s_setprio(0);
            u64 msh = mw >> (quad << 2);
            uint32_t pk01[4], pk23[4];
            #pragma unroll
            for (int nt = 0; nt < 4; nt++){
                float p0 = ((uint32_t)(msh >> (nt * 16 + 0)) & 1u) ? 0.f : ex2(s[nt][0]);
                float p1 = ((uint32_t)(msh >> (nt * 16 + 1)) & 1u) ? 0.f : ex2(s[nt][1]);
                float p2 = ((uint32_t)(msh >> (nt * 16 + 2)) & 1u) ? 0.f : ex2(s[nt][2]);
                float p3 = ((uint32_t)(msh >> (nt * 16 + 3)) & 1u) ? 0.f : ex2(s[nt][3]);
                l_part += (p0 + p1) + (p2 + p3);
                pk01[nt] = pkbf(p0, p1);
                pk23[nt] = pkbf(p2, p3);
            }
            uint4 pa, pb;
            {
                uint32_t t0, t1;
                t0 = __shfl(pk01[0], srcA, 64); t1 = __shfl(pk01[1], srcA, 64);
                pa.x = ntHi ? t1 : t0;
                t0 = __shfl(pk23[0], srcA, 64); t1 = __shfl(pk23[1], srcA, 64);
                pa.y = ntHi ? t1 : t0;
                t0 = __shfl(pk01[0], srcB, 64); t1 = __shfl(pk01[1], srcB, 64);
                pa.z = ntHi ? t1 : t0;
                t0 = __shfl(pk23[0], srcB, 64); t1 = __shfl(pk23[1], srcB, 64);
                pa.w = ntHi ? t1 : t0;
                t0 = __shfl(pk01[2], srcA, 64); t1 = __shfl(pk01[3], srcA, 64);
                pb.x = ntHi ? t1 : t0;
                t0 = __shfl(pk23[2], srcA, 64); t1 = __shfl(pk23[3], srcA, 64);
                pb.y = ntHi ? t1 : t0;
                t0 = __shfl(pk01[2], srcB, 64); t1 = __shfl(pk01[3], srcB, 64);
                pb.z = ntHi ? t1 : t0;
                t0 = __shfl(pk23[2], srcB, 64); t1 = __shfl(pk23[3], srcB, 64);
                pb.w = ntHi ? t1 : t0;
            }
            short8 pf0 = *(const short8*)&pa;
            short8 pf1 = *(const short8*)&pb;
            __builtin_amdgcn_s_setprio(1);
            #pragma unroll
            for (int dt = 0; dt < 4; dt++){
                short8 vf0 = *(const short8*)&Vs[cur][(dt << 4) + l15][quad << 3];
                short8 vf1 = *(const short8*)&Vs[cur][(dt << 4) + l15][32 + (quad << 3)];
                Oacc[dt] = __builtin_amdgcn_mfma_f32_16x16x32_bf16(pf0, vf0, Oacc[dt], 0, 0, 0);
                Oacc[dt] = __builtin_amdgcn_mfma_f32_16x16x32_bf16(pf1, vf1, Oacc[dt], 0, 0, 0);
            }
            __builtin_amdgcn_s_setprio(0);
            if (havenext){
                int nb = cur ^ 1;
                *(uint4*)&Ks[nb][srow][sc]     = kn0;
                *(uint4*)&Ks[nb][srow][sc + 8] = kn1;
                *(uint4*)&Vs[nb][srow][sc]     = vn0;
                *(uint4*)&Vs[nb][srow][sc + 8] = vn1;
            }
            __syncthreads();
        }
        l_part += __shfl_xor(l_part, 16, 64);
        l_part += __shfl_xor(l_part, 32, 64);
        #pragma unroll
        for (int r = 0; r < 4; r++){
            int qrow = q0 + (w << 4) + (quad << 2) + r;
            if (qrow < LT){
                float lr = __shfl(l_part, (lane & 48) + (quad << 2) + r, 64);
                float inv = 1.f / lr;
                #pragma unroll
                for (int dt = 0; dt < 4; dt++)
                    AO1[((size_t)(b * LT + qrow) << 9) + h * 64 + (dt << 4) + l15] =
                        f2b(Oacc[dt][r] * inv);
            }
        }
    } else {
        // ================= sparse branch v2: quad-parallel keys ===========
        const ushort* Q  = U;
        const ushort* Kp = U + (size_t)2*NBLE;
        const ushort* Vn = U + (size_t)5*NBLE;
        int wid = threadIdx.x >> 6, lane = threadIdx.x & 63;
        int row = (blockIdx.x - NFLASH) * 4 + wid;
        int b = row / (NHH * LT);
        int rem = row % (NHH * LT);
        int h = rem / LT, i = rem % LT;
        int c = CNT[i];
        int quad = lane >> 4, l15 = lane & 15;
        int d0 = l15 << 2;                 // 4 consecutive d per lane
        int jl = IDX[i * 12 + (lane % 12)];
        const ushort* qp = Q + (((size_t)b * LT + i) << 9) + h * 64 + d0;
        uint2 qv = *(const uint2*)qp;
        float qd0 = b2f((ushort)qv.x), qd1 = b2f((ushort)(qv.x >> 16));
        float qd2 = b2f((ushort)qv.y), qd3 = b2f((ushort)(qv.y >> 16));
        const ushort* kb = Kp + (((size_t)b * LT) << 9) + h * 64 + d0;
        const ushort* vb = Vn + (((size_t)b * LT) << 9) + h * 64 + d0;
        float o0 = 0.f, o1 = 0.f, o2 = 0.f, o3 = 0.f;
        float lsum = 0.f;
        #pragma unroll
        for (int rr = 0; rr < 3; rr++){
            int t = (rr << 2) + quad;      // this quad's key index
            int j = __shfl(jl, t, 64);
            uint2 kv2 = *(const uint2*)(kb + ((size_t)j << 9));
            uint2 vv2 = *(const uint2*)(vb + ((size_t)j << 9));
            float s = qd0 * b2f((ushort)kv2.x) + qd1 * b2f((ushort)(kv2.x >> 16))
                    + qd2 * b2f((ushort)kv2.y) + qd3 * b2f((ushort)(kv2.y >> 16));
            s += __shfl_xor(s, 1, 64);
            s += __shfl_xor(s, 2, 64);
            s += __shfl_xor(s, 4, 64);
            s += __shfl_xor(s, 8, 64);     // intra-quad reduce (offsets < 16)
            float p = (t < c) ? ex2(s) : 0.f;
            lsum += p;
            o0 += p * b2f((ushort)vv2.x);
            o1 += p * b2f((ushort)(vv2.x >> 16));
            o2 += p * b2f((ushort)vv2.y);
            o3 += p * b2f((ushort)(vv2.y >> 16));
        }
        // cross-quad reduce: total over all 12 keys for each d-slot
        o0 += __shfl_xor(o0, 16, 64); o0 += __shfl_xor(o0, 32, 64);
        o1 += __shfl_xor(o1, 16, 64); o1 += __shfl_xor(o1, 32, 64);
        o2 += __shfl_xor(o2, 16, 64); o2 += __shfl_xor(o2, 32, 64);
        o3 += __shfl_xor(o3, 16, 64); o3 += __shfl_xor(o3, 32, 64);
        lsum += __shfl_xor(lsum, 16, 64);
        lsum += __shfl_xor(lsum, 32, 64);
        float inv = 1.f / lsum;
        if (quad == 0){
            uint2 ov;
            ov.x = pkbf(o0 * inv, o1 * inv);
            ov.y = pkbf(o2 * inv, o3 * inv);
            *(uint2*)(AO0 + (((size_t)b * LT + i) << 9) + h * 64 + d0) = ov;
        }
    }
}

extern "C" void kernel_launch(void* const* d_in, const int* in_sizes, int n_in,
                              void* d_out, int out_size, void* d_ws, size_t ws_size,
                              hipStream_t stream)
{
    const float* x_enc   = (const float*)d_in[0];
    const float* down_W  = (const float*)d_in[1];
    const float* down_b  = (const float*)d_in[2];
    const float* conv_W  = (const float*)d_in[3];
    const float* conv_b  = (const float*)d_in[4];
    const float* up_W    = (const float*)d_in[5];
    const float* up_b    = (const float*)d_in[6];
    const float* bc_g    = (const float*)d_in[7];
    const float* bc_b    = (const float*)d_in[8];
    const float* aWq     = (const float*)d_in[9];
    const float* aWk     = (const float*)d_in[10];
    const float* aWv     = (const float*)d_in[11];
    const float* afcW    = (const float*)d_in[12];
    const float* afcb    = (const float*)d_in[13];
    const float* alng    = (const float*)d_in[14];
    const float* alnb    = (const float*)d_in[15];
    const float* fW1     = (const float*)d_in[16];
    const float* fb1     = (const float*)d_in[17];
    const float* fW2     = (const float*)d_in[18];
    const float* fb2     = (const float*)d_in[19];
    const float* flng    = (const float*)d_in[20];
    const float* flnb    = (const float*)d_in[21];

    const size_t NBL = (size_t)NBLE;
    float* X   = (float*)d_ws;
    float* TMP = X   + NBL;
    float* Qb  = TMP + NBL;
    float* Kb  = Qb  + NBL;
    float* Vb  = Kb  + NBL;
    float* AO  = Vb  + NBL;
    float* TO  = AO  + NBL;
    float* SO  = TO  + NBL;
    u64* MBm = (u64*)(SO + NBL);                      // B*LT*24 words
    int* TIDX = (int*)(MBm + (size_t)BB * LT * MBW);
    int* TCNT = TIDX + (size_t)LT * 12;
    ushort* WG = (ushort*)(TCNT + LT);
    const size_t M512 = 262144;
    ushort* WdownT = WG;                 size_t wo = M512;
    ushort* WupT   = WG + wo;            wo += M512;
    ushort* Wqkv   = WG + wo;            wo += 12 * M512;   // 4 layers x [Wq|Wk|Wv]^T
    ushort* WfT    = WG + wo;            wo += 4 * M512;
    ushort* W1T    = WG + wo;            wo += 2 * M512;
    ushort* W2T    = WG + wo;            wo += 2 * M512;
    ushort* WCt    = WG + wo;            wo += 3 * 1048576;
    float* LP = (float*)(WG + wo);                        // (kept for sizing)
    (void)LP;
    size_t need = 8 * NBL * sizeof(float) + (size_t)BB * LT * MBW * 8
                + (size_t)LT * 13 * 4 + wo * sizeof(ushort)
                + (size_t)2 * BB * NHH * LT * 4;
    if (ws_size < need) return;

    // aliases (lifetimes disjoint)
    float* Y    = Qb;
    float* C1   = Kb;
    float* C2   = C1 + (size_t)BB*256*512;
    float* C3   = C2 + (size_t)BB*64*512;
    float* PCAT = Vb;
    float* SKP  = AO;                     // split-K partials (bottleneck only)
    ushort* XNh = (ushort*)AO;            // hi/lo bf16 normalized rows
    ushort* XNl = XNh + NBLE;
    float* SIMB = Qb;
    ushort* U   = (ushort*)Qb;            // merged QKV: Q0@0 Q1@N K0@2N K1@3N Vt1@4N Vn0@5N
    ushort* XB  = (ushort*)SO;            // bf16 X (QKV/FFN1 A-operand)
    ushort* AOb0 = (ushort*)AO;           // branch0 attention out [0,N)
    ushort* AOb1 = AOb0 + NBLE;           // branch1 attention out [N,2N)
    ushort* HfB = (ushort*)Qb;            // bf16 FFN hidden
    float* TMP1 = TO;                     // second fc output (TO region reused)

    auto gemmN = [&](const void* A, int abf, const ushort* Bw, const float* bias,
                     const float* res, void* C, int M,
                     int act, int omode, int mpb, int orpb, int ooff){
        dim3 grid(8, M / 64);
        if (abf) gemm64t<1><<<grid, 256, 0, stream>>>(A, Bw, bias, res, C, M, 512, 512,
                                                      act, omode, mpb, orpb, ooff);
        else     gemm64t<0><<<grid, 256, 0, stream>>>(A, Bw, bias, res, C, M, 512, 512,
                                                      act, omode, mpb, orpb, ooff);
    };
    auto convG = [&](const float* A, const ushort* Bw, const float* bias,
                     float* C, int M){
        const int S = 8, K = 2048, N = 512;
        gemm_sk<<<dim3(8, M / 64, S), 256, 0, stream>>>(A, Bw, SKP, M, N, K, K / S);
        sk_reduce<<<(M * N) / 1024, 256, 0, stream>>>(SKP, bias, C, M * N, S);
    };

    build_tidx<<<(LT + 255) / 256, 256, 0, stream>>>(TIDX, TCNT);
    wtrans<<<dim3(8, 8, 1), 256, 0, stream>>>(down_W, WdownT, 512, 512, M512);
    wtrans<<<dim3(8, 8, 1), 256, 0, stream>>>(up_W,   WupT,   512, 512, M512);
    wtrans<<<dim3(8, 8, 4), 256, 0, stream>>>(aWq,  Wqkv + 0 * M512, 512, 512, 3 * (long)M512);
    wtrans<<<dim3(8, 8, 4), 256, 0, stream>>>(aWk,  Wqkv + 1 * M512, 512, 512, 3 * (long)M512);
    wtrans<<<dim3(8, 8, 4), 256, 0, stream>>>(aWv,  Wqkv + 2 * M512, 512, 512, 3 * (long)M512);
    wtrans<<<dim3(8, 8, 4), 256, 0, stream>>>(afcW, WfT, 512, 512, M512);
    wtrans<<<dim3(8, 8, 2), 256, 0, stream>>>(fW1,  W1T, 512, 512, M512);
    wtrans<<<dim3(8, 8, 2), 256, 0, stream>>>(fW2,  W2T, 512, 512, M512);
    wconv<<<dim3(4096, 3), 256, 0, stream>>>(conv_W, WCt);

    // ---- bottleneck
    gemmN(x_enc, 0, WdownT, down_b, nullptr, Y, BB*1024, 0, 0, 0, 0, 0);
    convG(Y,  WCt,             conv_b + 0,    C1, BB*256);
    convG(C1, WCt + 1048576,   conv_b + 512,  C2, BB*64);
    convG(C2, WCt + 2*1048576, conv_b + 1024, C3, BB*16);
    pcat_copy<<<(BB*336*512)/256, 256, 0, stream>>>(C1, C2, C3, PCAT);
    gemmN(PCAT, 0, WupT, up_b, nullptr, TMP, BB*336, 0, 0, 336, LT, 1024);
    xenc_copy<<<(BB*1024*512)/256, 256, 0, stream>>>(x_enc, TMP);
    // ln with fused rownorm (XNh/XNl for layer-0 sim)
    ln_kernel<<<(BB*LT)/4, 256, 0, stream>>>(TMP, bc_g, bc_b, X, XB, XNh, XNl, 1e-5f);

    // ---- transformer layers
    for (int l = 0; l < 2; l++){
        sim_mfma<<<dim3(274, BB), 256, 0, stream>>>(XNh, XNl, SIMB);
        topk_sel<<<(BB*LT)/4, 256, 0, stream>>>(SIMB, MBm);

        // merged dual-QKV (both branches) from bf16 X
        gemm_qkv<<<dim3(24, 85), 256, 0, stream>>>(XB, Wqkv + (size_t)l * 6 * M512,
                                                   U, BB*LT, 3072, 512);
        // fused attention: flash (704 blocks) + sparse (10880 blocks)
        attn_fused<<<dim3(NFLASH + (BB*NHH*LT)/4), 256, 0, stream>>>(
            U, MBm, TIDX, TCNT, AOb0, AOb1);
        // both output projections in one launch (64x128 tile)
        gemm128<<<dim3(4, 85, 2), 256, 0, stream>>>(AOb0, AOb1,
            WfT + (size_t)(2*l) * M512, WfT + (size_t)(2*l + 1) * M512,
            afcb + (size_t)(2*l) * 512, afcb + (size_t)(2*l + 1) * 512,
            X, TMP, TMP1, BB*LT, 512, 512, 0, 0);
        // fused dual-LN + add3
        ln2_add3<<<(BB*LT)/4, 256, 0, stream>>>(TMP, TMP1,
            alng + (size_t)(2*l) * 512, alnb + (size_t)(2*l) * 512,
            alng + (size_t)(2*l + 1) * 512, alnb + (size_t)(2*l + 1) * 512,
            X, XB, 1e-6f);

        // FFN (bf16 A, 64x128 tile)
        gemm128<<<dim3(4, 85, 1), 256, 0, stream>>>(XB, XB,
            W1T + (size_t)l * M512, W1T + (size_t)l * M512,
            fb1 + (size_t)l*512, fb1 + (size_t)l*512,
            nullptr, HfB, HfB, BB*LT, 512, 512, 2, 1);
        gemm128<<<dim3(4, 85, 1), 256, 0, stream>>>(HfB, HfB,
            W2T + (size_t)l * M512, W2T + (size_t)l * M512,
            fb2 + (size_t)l*512, fb2 + (size_t)l*512,
            X, TMP, TMP, BB*LT, 512, 512, 0, 0);
        // final ln: fused rownorm only when a next layer consumes XNh/XNl
        ln_kernel<<<(BB*LT)/4, 256, 0, stream>>>(TMP, flng + (size_t)l*512, flnb + (size_t)l*512,
                                                 (l == 1) ? (float*)d_out : X,
                                                 (l == 1) ? nullptr : XB,
                                                 (l == 1) ? nullptr : XNh,
                                                 (l == 1) ? nullptr : XNl, 1e-6f);
    }
}

// Round 16
// 675.284 us; speedup vs baseline: 1.0711x; 1.0711x over previous
//
#include <hip/hip_runtime.h>
#include <float.h>
#include <math.h>
#include <stdint.h>

#define LT 1360
#define BB 4
#define DM 512
#define NHH 8
#define NBLE 2785280   // BB*LT*512 elements
#define MBW 24         // mask words (uint64) per row
#define QSCALE 0.18033688f   // 0.125 * log2(e)
#define NFLASH 704     // flash blocks in fused attention dispatch (32 bh x 22 qt)

typedef __attribute__((ext_vector_type(8))) short short8;
typedef __attribute__((ext_vector_type(4))) float f32x4;
typedef unsigned long long u64;

__device__ __forceinline__ ushort f2b(float x){
    uint32_t u = __float_as_uint(x);
    return (ushort)((u + 0x7fffu + ((u >> 16) & 1u)) >> 16);
}
__device__ __forceinline__ float b2f(ushort u){
    return __uint_as_float(((uint32_t)u) << 16);
}
// raw v_exp_f32 (2^x). Safe here: masked-out lanes cndmask to 0, live lanes bounded.
__device__ __forceinline__ float ex2(float x){
    float r;
    asm("v_exp_f32 %0, %1" : "=v"(r) : "v"(x));
    return r;
}
// packed f32x2 -> bf16x2, RNE (same rounding as f2b)
__device__ __forceinline__ uint32_t pkbf(float lo, float hi){
    uint32_t r;
    asm("v_cvt_pk_bf16_f32 %0, %1, %2" : "=v"(r) : "v"(lo), "v"(hi));
    return r;
}

// semantic sim buffer layout (per batch)
#define SG0 0
#define SG1 1048576
#define SG2 (SG1 + 65536)
#define SG3 (SG2 + 4096)
#define SBT (SG3 + 256)

__device__ __forceinline__ void blk_info(int i, int& bi, int& st, int& n){
    if (i < 1024){ bi = 0; st = 0;    n = 1024; }
    else if (i < 1280){ bi = 1; st = 1024; n = 256; }
    else if (i < 1344){ bi = 2; st = 1280; n = 64; }
    else { bi = 3; st = 1344; n = 16; }
}

// ---------------- temporal allowed-index lists (padded to 12 for speculative loads)
__global__ __launch_bounds__(256)
void build_tidx(int* __restrict__ idx, int* __restrict__ cnt){
    int i = blockIdx.x * 256 + threadIdx.x;
    if (i >= LT) return;
    int bi, st, n; blk_info(i, bi, st, n);
    int c = 0; int* row = idx + i * 12;
    int lo = (i - 2 > st) ? i - 2 : st;
    int hi = (i + 2 < st + n - 1) ? i + 2 : st + n - 1;
    for (int j = lo; j <= hi; j++) row[c++] = j;
    if (bi < 3) row[c++] = st + n + (i - st) / 4;
    if (bi > 0){
        int stc = st - n * 4;
        int base = stc + (i - st) * 4;
        for (int t = 0; t < 4; t++) row[c++] = base + t;
    }
    cnt[i] = c;
    for (int t = c; t < 12; t++) row[t] = 0;   // safe pad
}

// ---------------- weight transpose+cast: Wd[n*K+k] = bf16(Ws[k*N+n])
__global__ __launch_bounds__(256)
void wtrans(const float* __restrict__ W, ushort* __restrict__ Wt, int K, int N, long dstStride){
    int mat = blockIdx.z;
    const float* Ws = W + (size_t)mat * K * N;
    ushort* Wd = Wt + (size_t)mat * dstStride;
    int k0 = blockIdx.y << 6, n0 = blockIdx.x << 6;
    __shared__ ushort t[64][72];
    int tid = threadIdx.x;
    #pragma unroll
    for (int p = 0; p < 4; p++){
        int idx = tid + (p << 8);
        int r = idx >> 4, c4 = (idx & 15) << 2;
        float4 v = *(const float4*)(Ws + (size_t)(k0 + r) * N + n0 + c4);
        t[c4+0][r] = f2b(v.x); t[c4+1][r] = f2b(v.y);
        t[c4+2][r] = f2b(v.z); t[c4+3][r] = f2b(v.w);
    }
    __syncthreads();
    #pragma unroll
    for (int p = 0; p < 4; p++){
        int idx = tid + (p << 8);
        int r = idx >> 4, c4 = (idx & 15) << 2;
        *(uint2*)&Wd[(size_t)(n0 + r) * K + k0 + c4] = *(uint2*)&t[r][c4];
    }
}

// ---------------- conv weight repack+cast
__global__ __launch_bounds__(256)
void wconv(const float* __restrict__ cw, ushort* __restrict__ wt){
    int conv = blockIdx.y;
    const float* src = cw + (size_t)conv * 512 * 512 * 4;
    ushort* dst = wt + (size_t)conv * 2048 * 512;
    int idx = blockIdx.x * 256 + threadIdx.x;
    int o = idx >> 11, rest = idx & 2047;
    int k = rest >> 9, ii = rest & 511;
    dst[idx] = f2b(src[((size_t)(o << 9) + ii) * 4 + k]);
}

// ---------------- merged dual-QKV GEMM: bf16 A, 64x128 tile, BK=64, reg-prefetch.
// N=3072 = [Q0|K0|V0|Q1|K1|V1]. Outputs: Q0@0, Q1@N, K0@2N, K1@3N, Vt1@4N, Vn0@5N.
// NOTE (R15): the 64x128 tile pays off HERE because grid = 24x85 = 2040
// blocks (8/CU). Porting it to the N=512 GEMMs (grid 340, 1.33/CU) REGRESSED
// +8us/dispatch — tail-wave quantization. Keep 64x64 for N=512.
__global__ __launch_bounds__(256)
void gemm_qkv(const ushort* __restrict__ A, const ushort* __restrict__ Bw,
              void* __restrict__ Cout, int M, int N, int K)
{
    __shared__ ushort As[64][72];
    __shared__ ushort Bs[128][72];
    int tid = threadIdx.x;
    int lane = tid & 63, w = tid >> 6, quad = lane >> 4, l15 = lane & 15;
    int gm = blockIdx.y << 6, gn = blockIdx.x << 7;
    int arow = tid >> 2, ac = (tid & 3) << 4;
    int brow = tid >> 1, bc = (tid & 1) << 5;
    f32x4 acc[4][2];
    #pragma unroll
    for (int mi = 0; mi < 4; mi++)
        #pragma unroll
        for (int ni = 0; ni < 2; ni++)
            acc[mi][ni] = (f32x4){0.f,0.f,0.f,0.f};
    const ushort* Ap = A + (size_t)(gm + arow) * K + ac;
    const ushort* Bp = Bw + (size_t)(gn + brow) * K + bc;
    uint4 a0r = *(const uint4*)(Ap);
    uint4 a1r = *(const uint4*)(Ap + 8);
    uint4 b0r = *(const uint4*)(Bp);
    uint4 b1r = *(const uint4*)(Bp + 8);
    uint4 b2r = *(const uint4*)(Bp + 16);
    uint4 b3r = *(const uint4*)(Bp + 24);
    *(uint4*)&As[arow][ac]     = a0r;  *(uint4*)&As[arow][ac + 8]  = a1r;
    *(uint4*)&Bs[brow][bc]     = b0r;  *(uint4*)&Bs[brow][bc + 8]  = b1r;
    *(uint4*)&Bs[brow][bc + 16] = b2r; *(uint4*)&Bs[brow][bc + 24] = b3r;
    __syncthreads();
    for (int k0 = 0; k0 < K; k0 += 64){
        bool nx = (k0 + 64 < K);
        if (nx){
            a0r = *(const uint4*)(Ap + k0 + 64);
            a1r = *(const uint4*)(Ap + k0 + 72);
            b0r = *(const uint4*)(Bp + k0 + 64);
            b1r = *(const uint4*)(Bp + k0 + 72);
            b2r = *(const uint4*)(Bp + k0 + 80);
            b3r = *(const uint4*)(Bp + k0 + 88);
        }
        __builtin_amdgcn_s_setprio(1);
        #pragma unroll
        for (int kk = 0; kk < 2; kk++){
            short8 af[4], bf[2];
            #pragma unroll
            for (int mi = 0; mi < 4; mi++)
                af[mi] = *(const short8*)&As[(mi << 4) + l15][(kk << 5) + (quad << 3)];
            #pragma unroll
            for (int ni = 0; ni < 2; ni++)
                bf[ni] = *(const short8*)&Bs[(w << 5) + (ni << 4) + l15][(kk << 5) + (quad << 3)];
            #pragma unroll
            for (int mi = 0; mi < 4; mi++)
                #pragma unroll
                for (int ni = 0; ni < 2; ni++)
                    acc[mi][ni] = __builtin_amdgcn_mfma_f32_16x16x32_bf16(af[mi], bf[ni], acc[mi][ni], 0, 0, 0);
        }
        __builtin_amdgcn_s_setprio(0);
        if (nx){
            __syncthreads();
            *(uint4*)&As[arow][ac]     = a0r;  *(uint4*)&As[arow][ac + 8]  = a1r;
            *(uint4*)&Bs[brow][bc]     = b0r;  *(uint4*)&Bs[brow][bc + 8]  = b1r;
            *(uint4*)&Bs[brow][bc + 16] = b2r; *(uint4*)&Bs[brow][bc + 24] = b3r;
            __syncthreads();
        }
    }
    int seg = gn >> 9, gc = gn & 511;
    ushort* Ob = (ushort*)Cout;
    if (seg == 2){
        // branch0 V: Vn0 only (scalar stores), @5N
        #pragma unroll
        for (int mi = 0; mi < 4; mi++)
            #pragma unroll
            for (int r = 0; r < 4; r++){
                int row = gm + (mi << 4) + (quad << 2) + r;
                #pragma unroll
                for (int ni = 0; ni < 2; ni++){
                    int cloc = (w << 5) + (ni << 4) + l15;
                    Ob[(size_t)5*NBLE + (size_t)row * 512 + gc + cloc] = f2b(acc[mi][ni][r]);
                }
            }
    } else if (seg == 5){
        // branch1 V: V^T only via LDS transpose, @4N
        __syncthreads();
        #pragma unroll
        for (int mi = 0; mi < 4; mi++)
            #pragma unroll
            for (int r = 0; r < 4; r++){
                int rloc = (mi << 4) + (quad << 2) + r;
                #pragma unroll
                for (int ni = 0; ni < 2; ni++){
                    int cloc = (w << 5) + (ni << 4) + l15;
                    Bs[cloc][rloc] = f2b(acc[mi][ni][r]);
                }
            }
        __syncthreads();
        int colw = tid >> 3;            // 0..31
        int jo = (tid & 7) << 3;        // row offset within tile, 0..56
        int rr = gm + jo;
        int bb = rr / LT;
        int ii = rr - bb * LT;
        #pragma unroll
        for (int cc = 0; cc < 4; cc++){
            int c = colw + (cc << 5);   // 0..127
            uint4 tv = *(const uint4*)&Bs[c][jo];
            ushort* dst = Ob + (size_t)4*NBLE + ((size_t)(bb * 512 + gc + c)) * LT + ii;
            *(uint4*)dst = tv;
        }
    } else {
        // Q/K segments: Q0@0 (scaled), K0@2N, Q1@N (scaled), K1@3N
        size_t base = (seg == 0) ? 0 : (seg == 1) ? (size_t)2*NBLE
                    : (seg == 3) ? (size_t)NBLE : (size_t)3*NBLE;
        float scl = (seg == 0 || seg == 3) ? QSCALE : 1.f;
        #pragma unroll
        for (int mi = 0; mi < 4; mi++)
            #pragma unroll
            for (int r = 0; r < 4; r++){
                int row = gm + (mi << 4) + (quad << 2) + r;
                #pragma unroll
                for (int ni = 0; ni < 2; ni++){
                    int c5 = gc + (w << 5) + (ni << 4) + l15;
                    Ob[base + (size_t)row * 512 + c5] = f2b(acc[mi][ni][r] * scl);
                }
            }
    }
}

// ---------------- bf16 MFMA GEMM, 64x64 tile, BK=64, reg-prefetch.
// ABF=1: A is bf16; ABF=0: A fp32 (converted at LDS-store time).
// NOTE: BK=128 regressed (R6); 64x128 tile at N=512 regressed (R15). Keep.
template<int ABF>
__global__ __launch_bounds__(256)
void gemm64t(const void* __restrict__ Avp, const ushort* __restrict__ Bw,
             const float* __restrict__ bias, const float* __restrict__ Rres,
             void* __restrict__ Cout, int M, int N, int K,
             int act, int omode, int mpb, int orpb, int ooff)
{
    __shared__ ushort As[64][72];
    __shared__ ushort Bs[64][72];
    int tid = threadIdx.x;
    int lane = tid & 63, w = tid >> 6, quad = lane >> 4, l15 = lane & 15;
    int gm = blockIdx.y << 6, gn = blockIdx.x << 6;
    int wr = (w >> 1) << 5, wc = (w & 1) << 5;
    int srow = tid >> 2, sc = (tid & 3) << 4;
    f32x4 acc[2][2];
    #pragma unroll
    for (int mi = 0; mi < 2; mi++)
        #pragma unroll
        for (int ni = 0; ni < 2; ni++)
            acc[mi][ni] = (f32x4){0.f,0.f,0.f,0.f};
    const float*  Af = (const float*)Avp;
    const ushort* Ab = (const ushort*)Avp;
    size_t aoff = (size_t)(gm + srow) * K + sc;
    const ushort* Bp = Bw + (size_t)(gn + srow) * K + sc;
    uint4 aR0, aR1, bR0, bR1;
    float4 f0, f1, f2v, f3v;
    if (ABF){
        aR0 = *(const uint4*)(Ab + aoff);
        aR1 = *(const uint4*)(Ab + aoff + 8);
    } else {
        f0  = *(const float4*)(Af + aoff);
        f1  = *(const float4*)(Af + aoff + 4);
        f2v = *(const float4*)(Af + aoff + 8);
        f3v = *(const float4*)(Af + aoff + 12);
    }
    bR0 = *(const uint4*)(Bp);
    bR1 = *(const uint4*)(Bp + 8);
    if (!ABF){
        aR0.x = (uint32_t)f2b(f0.x)  | ((uint32_t)f2b(f0.y)  << 16);
        aR0.y = (uint32_t)f2b(f0.z)  | ((uint32_t)f2b(f0.w)  << 16);
        aR0.z = (uint32_t)f2b(f1.x)  | ((uint32_t)f2b(f1.y)  << 16);
        aR0.w = (uint32_t)f2b(f1.z)  | ((uint32_t)f2b(f1.w)  << 16);
        aR1.x = (uint32_t)f2b(f2v.x) | ((uint32_t)f2b(f2v.y) << 16);
        aR1.y = (uint32_t)f2b(f2v.z) | ((uint32_t)f2b(f2v.w) << 16);
        aR1.z = (uint32_t)f2b(f3v.x) | ((uint32_t)f2b(f3v.y) << 16);
        aR1.w = (uint32_t)f2b(f3v.z) | ((uint32_t)f2b(f3v.w) << 16);
    }
    *(uint4*)&As[srow][sc]     = aR0;
    *(uint4*)&As[srow][sc + 8] = aR1;
    *(uint4*)&Bs[srow][sc]     = bR0;
    *(uint4*)&Bs[srow][sc + 8] = bR1;
    __syncthreads();
    for (int k0 = 0; k0 < K; k0 += 64){
        bool nx = (k0 + 64 < K);
        if (nx){
            if (ABF){
                aR0 = *(const uint4*)(Ab + aoff + k0 + 64);
                aR1 = *(const uint4*)(Ab + aoff + k0 + 72);
            } else {
                f0  = *(const float4*)(Af + aoff + k0 + 64);
                f1  = *(const float4*)(Af + aoff + k0 + 68);
                f2v = *(const float4*)(Af + aoff + k0 + 72);
                f3v = *(const float4*)(Af + aoff + k0 + 76);
            }
            bR0 = *(const uint4*)(Bp + k0 + 64);
            bR1 = *(const uint4*)(Bp + k0 + 72);
        }
        __builtin_amdgcn_s_setprio(1);
        #pragma unroll
        for (int kk = 0; kk < 2; kk++){
            short8 af0 = *(const short8*)&As[wr + l15][(kk << 5) + (quad << 3)];
            short8 af1 = *(const short8*)&As[wr + 16 + l15][(kk << 5) + (quad << 3)];
            short8 bf0 = *(const short8*)&Bs[wc + l15][(kk << 5) + (quad << 3)];
            short8 bf1 = *(const short8*)&Bs[wc + 16 + l15][(kk << 5) + (quad << 3)];
            acc[0][0] = __builtin_amdgcn_mfma_f32_16x16x32_bf16(af0, bf0, acc[0][0], 0, 0, 0);
            acc[0][1] = __builtin_amdgcn_mfma_f32_16x16x32_bf16(af0, bf1, acc[0][1], 0, 0, 0);
            acc[1][0] = __builtin_amdgcn_mfma_f32_16x16x32_bf16(af1, bf0, acc[1][0], 0, 0, 0);
            acc[1][1] = __builtin_amdgcn_mfma_f32_16x16x32_bf16(af1, bf1, acc[1][1], 0, 0, 0);
        }
        __builtin_amdgcn_s_setprio(0);
        if (nx){
            __syncthreads();
            if (!ABF){
                aR0.x = (uint32_t)f2b(f0.x)  | ((uint32_t)f2b(f0.y)  << 16);
                aR0.y = (uint32_t)f2b(f0.z)  | ((uint32_t)f2b(f0.w)  << 16);
                aR0.z = (uint32_t)f2b(f1.x)  | ((uint32_t)f2b(f1.y)  << 16);
                aR0.w = (uint32_t)f2b(f1.z)  | ((uint32_t)f2b(f1.w)  << 16);
                aR1.x = (uint32_t)f2b(f2v.x) | ((uint32_t)f2b(f2v.y) << 16);
                aR1.y = (uint32_t)f2b(f2v.z) | ((uint32_t)f2b(f2v.w) << 16);
                aR1.z = (uint32_t)f2b(f3v.x) | ((uint32_t)f2b(f3v.y) << 16);
                aR1.w = (uint32_t)f2b(f3v.z) | ((uint32_t)f2b(f3v.w) << 16);
            }
            *(uint4*)&As[srow][sc]     = aR0;
            *(uint4*)&As[srow][sc + 8] = aR1;
            *(uint4*)&Bs[srow][sc]     = bR0;
            *(uint4*)&Bs[srow][sc + 8] = bR1;
            __syncthreads();
        }
    }
    #pragma unroll
    for (int mi = 0; mi < 2; mi++){
        #pragma unroll
        for (int r = 0; r < 4; r++){
            int row = gm + wr + (mi << 4) + (quad << 2) + r;
            #pragma unroll
            for (int ni = 0; ni < 2; ni++){
                int col = gn + wc + (ni << 4) + l15;
                float v = acc[mi][ni][r];
                if (bias) v += bias[col];
                if (Rres) v += Rres[(size_t)row * N + col];
                if (act == 2){ v = fmaxf(v, 0.f); }
                if (omode == 0){
                    int orow = mpb ? (row / mpb) * orpb + ooff + (row % mpb) : row;
                    ((float*)Cout)[(size_t)orow * N + col] = v;
                } else {
                    ((ushort*)Cout)[(size_t)row * N + col] = f2b(v);
                }
            }
        }
    }
}

// ---------------- batched dual fc GEMM (grid.z selects branch): bf16 A,
// 64x64 tile, BK=64, reg-prefetch; out = A*W + bias + X (fp32).
__global__ __launch_bounds__(256)
void gemm_fc2(const ushort* __restrict__ A0, const ushort* __restrict__ A1,
              const ushort* __restrict__ B0, const ushort* __restrict__ B1,
              const float* __restrict__ bias0, const float* __restrict__ bias1,
              const float* __restrict__ Rres, float* __restrict__ C0,
              float* __restrict__ C1, int M, int N, int K)
{
    __shared__ ushort As[64][72];
    __shared__ ushort Bs[64][72];
    const ushort* Ab = blockIdx.z ? A1 : A0;
    const ushort* Bw = blockIdx.z ? B1 : B0;
    const float* bias = blockIdx.z ? bias1 : bias0;
    float* Cout = blockIdx.z ? C1 : C0;
    int tid = threadIdx.x;
    int lane = tid & 63, w = tid >> 6, quad = lane >> 4, l15 = lane & 15;
    int gm = blockIdx.y << 6, gn = blockIdx.x << 6;
    int wr = (w >> 1) << 5, wc = (w & 1) << 5;
    int srow = tid >> 2, sc = (tid & 3) << 4;
    f32x4 acc[2][2];
    #pragma unroll
    for (int mi = 0; mi < 2; mi++)
        #pragma unroll
        for (int ni = 0; ni < 2; ni++)
            acc[mi][ni] = (f32x4){0.f,0.f,0.f,0.f};
    size_t aoff = (size_t)(gm + srow) * K + sc;
    const ushort* Bp = Bw + (size_t)(gn + srow) * K + sc;
    uint4 aR0 = *(const uint4*)(Ab + aoff);
    uint4 aR1 = *(const uint4*)(Ab + aoff + 8);
    uint4 bR0 = *(const uint4*)(Bp);
    uint4 bR1 = *(const uint4*)(Bp + 8);
    *(uint4*)&As[srow][sc]     = aR0;
    *(uint4*)&As[srow][sc + 8] = aR1;
    *(uint4*)&Bs[srow][sc]     = bR0;
    *(uint4*)&Bs[srow][sc + 8] = bR1;
    __syncthreads();
    for (int k0 = 0; k0 < K; k0 += 64){
        bool nx = (k0 + 64 < K);
        if (nx){
            aR0 = *(const uint4*)(Ab + aoff + k0 + 64);
            aR1 = *(const uint4*)(Ab + aoff + k0 + 72);
            bR0 = *(const uint4*)(Bp + k0 + 64);
            bR1 = *(const uint4*)(Bp + k0 + 72);
        }
        __builtin_amdgcn_s_setprio(1);
        #pragma unroll
        for (int kk = 0; kk < 2; kk++){
            short8 af0 = *(const short8*)&As[wr + l15][(kk << 5) + (quad << 3)];
            short8 af1 = *(const short8*)&As[wr + 16 + l15][(kk << 5) + (quad << 3)];
            short8 bf0 = *(const short8*)&Bs[wc + l15][(kk << 5) + (quad << 3)];
            short8 bf1 = *(const short8*)&Bs[wc + 16 + l15][(kk << 5) + (quad << 3)];
            acc[0][0] = __builtin_amdgcn_mfma_f32_16x16x32_bf16(af0, bf0, acc[0][0], 0, 0, 0);
            acc[0][1] = __builtin_amdgcn_mfma_f32_16x16x32_bf16(af0, bf1, acc[0][1], 0, 0, 0);
            acc[1][0] = __builtin_amdgcn_mfma_f32_16x16x32_bf16(af1, bf0, acc[1][0], 0, 0, 0);
            acc[1][1] = __builtin_amdgcn_mfma_f32_16x16x32_bf16(af1, bf1, acc[1][1], 0, 0, 0);
        }
        __builtin_amdgcn_s_setprio(0);
        if (nx){
            __syncthreads();
            *(uint4*)&As[srow][sc]     = aR0;
            *(uint4*)&As[srow][sc + 8] = aR1;
            *(uint4*)&Bs[srow][sc]     = bR0;
            *(uint4*)&Bs[srow][sc + 8] = bR1;
            __syncthreads();
        }
    }
    #pragma unroll
    for (int mi = 0; mi < 2; mi++){
        #pragma unroll
        for (int r = 0; r < 4; r++){
            int row = gm + wr + (mi << 4) + (quad << 2) + r;
            #pragma unroll
            for (int ni = 0; ni < 2; ni++){
                int col = gn + wc + (ni << 4) + l15;
                float v = acc[mi][ni][r] + bias[col] + Rres[(size_t)row * N + col];
                Cout[(size_t)row * N + col] = v;
            }
        }
    }
}

// ---------------- split-K bf16 GEMM for tiny-M conv chain (v2: BK=64,
// register prefetch, setprio; accumulation order unchanged => bit-identical).
__global__ __launch_bounds__(256)
void gemm_sk(const float* __restrict__ A, const ushort* __restrict__ Bw,
             float* __restrict__ P, int M, int N, int K, int kslice)
{
    __shared__ ushort As[64][72];
    __shared__ ushort Bs[64][72];
    int tid = threadIdx.x;
    int lane = tid & 63, w = tid >> 6, quad = lane >> 4, l15 = lane & 15;
    int gm = blockIdx.y << 6, gn = blockIdx.x << 6;
    int wr = (w >> 1) << 5, wc = (w & 1) << 5;
    int srow = tid >> 2, sc = (tid & 3) << 4;
    int ks = blockIdx.z * kslice;
    f32x4 acc[2][2];
    #pragma unroll
    for (int mi = 0; mi < 2; mi++)
        #pragma unroll
        for (int ni = 0; ni < 2; ni++)
            acc[mi][ni] = (f32x4){0.f,0.f,0.f,0.f};
    size_t aoff = (size_t)(gm + srow) * K + ks + sc;
    const ushort* Bp = Bw + (size_t)(gn + srow) * K + ks + sc;
    uint4 aR0, aR1, bR0, bR1;
    float4 f0, f1, f2v, f3v;
    f0  = *(const float4*)(A + aoff);
    f1  = *(const float4*)(A + aoff + 4);
    f2v = *(const float4*)(A + aoff + 8);
    f3v = *(const float4*)(A + aoff + 12);
    bR0 = *(const uint4*)(Bp);
    bR1 = *(const uint4*)(Bp + 8);
    aR0.x = (uint32_t)f2b(f0.x)  | ((uint32_t)f2b(f0.y)  << 16);
    aR0.y = (uint32_t)f2b(f0.z)  | ((uint32_t)f2b(f0.w)  << 16);
    aR0.z = (uint32_t)f2b(f1.x)  | ((uint32_t)f2b(f1.y)  << 16);
    aR0.w = (uint32_t)f2b(f1.z)  | ((uint32_t)f2b(f1.w)  << 16);
    aR1.x = (uint32_t)f2b(f2v.x) | ((uint32_t)f2b(f2v.y) << 16);
    aR1.y = (uint32_t)f2b(f2v.z) | ((uint32_t)f2b(f2v.w) << 16);
    aR1.z = (uint32_t)f2b(f3v.x) | ((uint32_t)f2b(f3v.y) << 16);
    aR1.w = (uint32_t)f2b(f3v.z) | ((uint32_t)f2b(f3v.w) << 16);
    *(uint4*)&As[srow][sc]     = aR0;
    *(uint4*)&As[srow][sc + 8] = aR1;
    *(uint4*)&Bs[srow][sc]     = bR0;
    *(uint4*)&Bs[srow][sc + 8] = bR1;
    __syncthreads();
    for (int kc = 0; kc < kslice; kc += 64){
        bool nx = (kc + 64 < kslice);
        if (nx){
            f0  = *(const float4*)(A + aoff + kc + 64);
            f1  = *(const float4*)(A + aoff + kc + 68);
            f2v = *(const float4*)(A + aoff + kc + 72);
            f3v = *(const float4*)(A + aoff + kc + 76);
            bR0 = *(const uint4*)(Bp + kc + 64);
            bR1 = *(const uint4*)(Bp + kc + 72);
        }
        __builtin_amdgcn_s_setprio(1);
        #pragma unroll
        for (int kk = 0; kk < 2; kk++){
            short8 af0 = *(const short8*)&As[wr + l15][(kk << 5) + (quad << 3)];
            short8 af1 = *(const short8*)&As[wr + 16 + l15][(kk << 5) + (quad << 3)];
            short8 bf0 = *(const short8*)&Bs[wc + l15][(kk << 5) + (quad << 3)];
            short8 bf1 = *(const short8*)&Bs[wc + 16 + l15][(kk << 5) + (quad << 3)];
            acc[0][0] = __builtin_amdgcn_mfma_f32_16x16x32_bf16(af0, bf0, acc[0][0], 0, 0, 0);
            acc[0][1] = __builtin_amdgcn_mfma_f32_16x16x32_bf16(af0, bf1, acc[0][1], 0, 0, 0);
            acc[1][0] = __builtin_amdgcn_mfma_f32_16x16x32_bf16(af1, bf0, acc[1][0], 0, 0, 0);
            acc[1][1] = __builtin_amdgcn_mfma_f32_16x16x32_bf16(af1, bf1, acc[1][1], 0, 0, 0);
        }
        __builtin_amdgcn_s_setprio(0);
        if (nx){
            __syncthreads();
            aR0.x = (uint32_t)f2b(f0.x)  | ((uint32_t)f2b(f0.y)  << 16);
            aR0.y = (uint32_t)f2b(f0.z)  | ((uint32_t)f2b(f0.w)  << 16);
            aR0.z = (uint32_t)f2b(f1.x)  | ((uint32_t)f2b(f1.y)  << 16);
            aR0.w = (uint32_t)f2b(f1.z)  | ((uint32_t)f2b(f1.w)  << 16);
            aR1.x = (uint32_t)f2b(f2v.x) | ((uint32_t)f2b(f2v.y) << 16);
            aR1.y = (uint32_t)f2b(f2v.z) | ((uint32_t)f2b(f2v.w) << 16);
            aR1.z = (uint32_t)f2b(f3v.x) | ((uint32_t)f2b(f3v.y) << 16);
            aR1.w = (uint32_t)f2b(f3v.z) | ((uint32_t)f2b(f3v.w) << 16);
            *(uint4*)&As[srow][sc]     = aR0;
            *(uint4*)&As[srow][sc + 8] = aR1;
            *(uint4*)&Bs[srow][sc]     = bR0;
            *(uint4*)&Bs[srow][sc + 8] = bR1;
            __syncthreads();
        }
    }
    float* Pz = P + (size_t)blockIdx.z * M * N;
    #pragma unroll
    for (int mi = 0; mi < 2; mi++){
        #pragma unroll
        for (int r = 0; r < 4; r++){
            int row = gm + wr + (mi << 4) + (quad << 2) + r;
            #pragma unroll
            for (int ni = 0; ni < 2; ni++){
                int col = gn + wc + (ni << 4) + l15;
                Pz[(size_t)row * N + col] = acc[mi][ni][r];
            }
        }
    }
}

// ---------------- split-K reduce + bias + scaled ELU (conv epilogue)
__global__ __launch_bounds__(256)
void sk_reduce(const float* __restrict__ P, const float* __restrict__ bias,
               float* __restrict__ C, int MN, int S)
{
    int idx = (blockIdx.x * 256 + threadIdx.x) << 2;
    if (idx >= MN) return;
    float4 s = {0.f, 0.f, 0.f, 0.f};
    for (int z = 0; z < S; z++){
        float4 v = *(const float4*)(P + (size_t)z * MN + idx);
        s.x += v.x; s.y += v.y; s.z += v.z; s.w += v.w;
    }
    const float cscale = 0.9999950000375f;
    int col = idx & 511;
    float o[4] = {s.x, s.y, s.z, s.w};
    #pragma unroll
    for (int t = 0; t < 4; t++){
        float v = (o[t] + bias[col + t]) * cscale;
        o[t] = (v > 0.f) ? v : expm1f(v);
    }
    *(float4*)(C + idx) = (float4){o[0], o[1], o[2], o[3]};
}

// ---------------- semantic sim via split-bf16 MFMA (hi/lo precomputed)
// v2: register-staged prefetch + setprio on the 12-MFMA cluster.
__global__ __launch_bounds__(256)
void sim_mfma(const ushort* __restrict__ XH, const ushort* __restrict__ XL,
              float* __restrict__ SIM){
    __shared__ ushort Ah[64][40], Al[64][40], Bh[64][40], Bl[64][40];
    int x = blockIdx.x, b = blockIdx.y;
    int ti, tj, st, n, goff;
    if (x < 256){ ti = x >> 4; tj = x & 15; st = 0; n = 1024; goff = SG0; }
    else if (x < 272){ int y = x - 256; ti = y >> 2; tj = y & 3; st = 1024; n = 256; goff = SG1; }
    else if (x == 272){ ti = 0; tj = 0; st = 1280; n = 64; goff = SG2; }
    else { ti = 0; tj = 0; st = 1344; n = 16; goff = SG3; }
    const ushort* XbH = XH + (((size_t)b * LT + st) << 9);
    const ushort* XbL = XL + (((size_t)b * LT + st) << 9);
    float* Cb = SIM + (size_t)b * SBT + goff;
    int gm = ti << 6, gn = tj << 6;
    int tid = threadIdx.x;
    int lane = tid & 63, w = tid >> 6, quad = lane >> 4, l15 = lane & 15;
    int wr = (w >> 1) << 5, wc = (w & 1) << 5;
    int srow = tid >> 2, sc8 = (tid & 3) << 3;
    int ra = gm + srow; if (ra > n - 1) ra = n - 1;
    int rb = gn + srow; if (rb > n - 1) rb = n - 1;
    f32x4 acc[2][2];
    #pragma unroll
    for (int mi = 0; mi < 2; mi++)
        #pragma unroll
        for (int ni = 0; ni < 2; ni++)
            acc[mi][ni] = (f32x4){0.f,0.f,0.f,0.f};
    const ushort* pAh = XbH + ((size_t)ra << 9) + sc8;
    const ushort* pAl = XbL + ((size_t)ra << 9) + sc8;
    const ushort* pBh = XbH + ((size_t)rb << 9) + sc8;
    const ushort* pBl = XbL + ((size_t)rb << 9) + sc8;
    uint4 vah = *(const uint4*)pAh;
    uint4 val = *(const uint4*)pAl;
    uint4 vbh = *(const uint4*)pBh;
    uint4 vbl = *(const uint4*)pBl;
    *(uint4*)&Ah[srow][sc8] = vah;
    *(uint4*)&Al[srow][sc8] = val;
    *(uint4*)&Bh[srow][sc8] = vbh;
    *(uint4*)&Bl[srow][sc8] = vbl;
    __syncthreads();
    for (int k0 = 0; k0 < 512; k0 += 32){
        bool nx = (k0 + 32 < 512);
        if (nx){
            vah = *(const uint4*)(pAh + k0 + 32);
            val = *(const uint4*)(pAl + k0 + 32);
            vbh = *(const uint4*)(pBh + k0 + 32);
            vbl = *(const uint4*)(pBl + k0 + 32);
        }
        __builtin_amdgcn_s_setprio(1);
        short8 ah0 = *(const short8*)&Ah[wr + l15][quad << 3];
        short8 ah1 = *(const short8*)&Ah[wr + 16 + l15][quad << 3];
        short8 al0 = *(const short8*)&Al[wr + l15][quad << 3];
        short8 al1 = *(const short8*)&Al[wr + 16 + l15][quad << 3];
        short8 bh0 = *(const short8*)&Bh[wc + l15][quad << 3];
        short8 bh1 = *(const short8*)&Bh[wc + 16 + l15][quad << 3];
        short8 bl0 = *(const short8*)&Bl[wc + l15][quad << 3];
        short8 bl1 = *(const short8*)&Bl[wc + 16 + l15][quad << 3];
        acc[0][0] = __builtin_amdgcn_mfma_f32_16x16x32_bf16(ah0, bh0, acc[0][0], 0, 0, 0);
        acc[0][0] = __builtin_amdgcn_mfma_f32_16x16x32_bf16(ah0, bl0, acc[0][0], 0, 0, 0);
        acc[0][0] = __builtin_amdgcn_mfma_f32_16x16x32_bf16(al0, bh0, acc[0][0], 0, 0, 0);
        acc[0][1] = __builtin_amdgcn_mfma_f32_16x16x32_bf16(ah0, bh1, acc[0][1], 0, 0, 0);
        acc[0][1] = __builtin_amdgcn_mfma_f32_16x16x32_bf16(ah0, bl1, acc[0][1], 0, 0, 0);
        acc[0][1] = __builtin_amdgcn_mfma_f32_16x16x32_bf16(al0, bh1, acc[0][1], 0, 0, 0);
        acc[1][0] = __builtin_amdgcn_mfma_f32_16x16x32_bf16(ah1, bh0, acc[1][0], 0, 0, 0);
        acc[1][0] = __builtin_amdgcn_mfma_f32_16x16x32_bf16(ah1, bl0, acc[1][0], 0, 0, 0);
        acc[1][0] = __builtin_amdgcn_mfma_f32_16x16x32_bf16(al1, bh0, acc[1][0], 0, 0, 0);
        acc[1][1] = __builtin_amdgcn_mfma_f32_16x16x32_bf16(ah1, bh1, acc[1][1], 0, 0, 0);
        acc[1][1] = __builtin_amdgcn_mfma_f32_16x16x32_bf16(ah1, bl1, acc[1][1], 0, 0, 0);
        acc[1][1] = __builtin_amdgcn_mfma_f32_16x16x32_bf16(al1, bh1, acc[1][1], 0, 0, 0);
        __builtin_amdgcn_s_setprio(0);
        if (nx){
            __syncthreads();
            *(uint4*)&Ah[srow][sc8] = vah;
            *(uint4*)&Al[srow][sc8] = val;
            *(uint4*)&Bh[srow][sc8] = vbh;
            *(uint4*)&Bl[srow][sc8] = vbl;
            __syncthreads();
        }
    }
    #pragma unroll
    for (int mi = 0; mi < 2; mi++){
        #pragma unroll
        for (int r = 0; r < 4; r++){
            int row = gm + wr + (mi << 4) + (quad << 2) + r;
            if (row < n){
                #pragma unroll
                for (int ni = 0; ni < 2; ni++){
                    int col = gn + wc + (ni << 4) + l15;
                    if (col < n) Cb[(size_t)row * n + col] = acc[mi][ni][r];
                }
            }
        }
    }
}

// ---------------- concat conv pyramids
__global__ __launch_bounds__(256)
void pcat_copy(const float* __restrict__ C1, const float* __restrict__ C2,
               const float* __restrict__ C3, float* __restrict__ PC){
    int idx = blockIdx.x * 256 + threadIdx.x;
    int d = idx & 511;
    int r = (idx >> 9) % 336;
    int b = idx / (336 * 512);
    float v;
    if (r < 256)       v = C1[(((size_t)b * 256 + r) << 9) + d];
    else if (r < 320)  v = C2[(((size_t)b * 64 + (r - 256)) << 9) + d];
    else               v = C3[(((size_t)b * 16 + (r - 320)) << 9) + d];
    PC[idx] = v;
}

__global__ __launch_bounds__(256)
void xenc_copy(const float* __restrict__ xe, float* __restrict__ dst){
    int idx = blockIdx.x * 256 + threadIdx.x;
    int d = idx & 511;
    int l = (idx >> 9) & 1023;
    int b = idx >> 19;
    dst[(((size_t)b * LT + l) << 9) + d] = xe[idx];
}

// ---------------- LayerNorm over 512, wave per row; optional bf16 dual output
// + optional fused row-L2-normalize.
__global__ __launch_bounds__(256)
void ln_kernel(const float* __restrict__ in, const float* __restrict__ g,
               const float* __restrict__ bta, float* __restrict__ out,
               ushort* __restrict__ ob, ushort* __restrict__ xh,
               ushort* __restrict__ xl, float eps){
    int wid = threadIdx.x >> 6, lane = threadIdx.x & 63;
    int row = blockIdx.x * 4 + wid;
    const float* p = in + ((size_t)row << 9);
    float vals[8]; float s = 0.f, s2 = 0.f;
    #pragma unroll
    for (int t = 0; t < 8; t++){
        float v = p[lane + t * 64]; vals[t] = v; s += v; s2 += v * v;
    }
    #pragma unroll
    for (int off = 32; off; off >>= 1){
        s  += __shfl_xor(s,  off, 64);
        s2 += __shfl_xor(s2, off, 64);
    }
    float mu = s * (1.f / 512.f);
    float var = s2 * (1.f / 512.f) - mu * mu;
    float r = rsqrtf(var + eps);
    float* q = out + ((size_t)row << 9);
    ushort* qb = ob ? ob + ((size_t)row << 9) : nullptr;
    float nv[8]; float sn2 = 0.f;
    #pragma unroll
    for (int t = 0; t < 8; t++){
        int c = lane + t * 64;
        float v = (vals[t] - mu) * r * g[c] + bta[c];
        q[c] = v;
        if (qb) qb[c] = f2b(v);
        nv[t] = v; sn2 += v * v;
    }
    if (xh){
        #pragma unroll
        for (int off = 32; off; off >>= 1) sn2 += __shfl_xor(sn2, off, 64);
        float inv = 1.f / fmaxf(sqrtf(sn2), 1e-8f);
        ushort* qh = xh + ((size_t)row << 9);
        ushort* ql = xl + ((size_t)row << 9);
        #pragma unroll
        for (int t = 0; t < 8; t++){
            float v = nv[t] * inv;
            ushort h = f2b(v);
            qh[lane + t * 64] = h;
            ql[lane + t * 64] = f2b(v - b2f(h));
        }
    }
}

// ---------------- fused dual-LN + add3: X = (ln(in0) + ln(in1) + X)/3; bf16 out.
__global__ __launch_bounds__(256)
void ln2_add3(const float* __restrict__ in0, const float* __restrict__ in1,
              const float* __restrict__ g0, const float* __restrict__ b0,
              const float* __restrict__ g1, const float* __restrict__ b1,
              float* __restrict__ X, ushort* __restrict__ ob, float eps){
    int wid = threadIdx.x >> 6, lane = threadIdx.x & 63;
    int row = blockIdx.x * 4 + wid;
    const float* p0 = in0 + ((size_t)row << 9);
    const float* p1 = in1 + ((size_t)row << 9);
    float v0[8], v1[8];
    float s0 = 0.f, q0 = 0.f, s1 = 0.f, q1 = 0.f;
    #pragma unroll
    for (int t = 0; t < 8; t++){
        float a = p0[lane + t * 64]; v0[t] = a; s0 += a; q0 += a * a;
        float c = p1[lane + t * 64]; v1[t] = c; s1 += c; q1 += c * c;
    }
    #pragma unroll
    for (int off = 32; off; off >>= 1){
        s0 += __shfl_xor(s0, off, 64);
        q0 += __shfl_xor(q0, off, 64);
        s1 += __shfl_xor(s1, off, 64);
        q1 += __shfl_xor(q1, off, 64);
    }
    float mu0 = s0 * (1.f / 512.f);
    float r0 = rsqrtf(q0 * (1.f / 512.f) - mu0 * mu0 + eps);
    float mu1 = s1 * (1.f / 512.f);
    float r1 = rsqrtf(q1 * (1.f / 512.f) - mu1 * mu1 + eps);
    float* xp = X + ((size_t)row << 9);
    ushort* qb = ob + ((size_t)row << 9);
    #pragma unroll
    for (int t = 0; t < 8; t++){
        int c = lane + t * 64;
        float sn0 = (v0[t] - mu0) * r0 * g0[c] + b0[c];
        float sn1 = (v1[t] - mu1) * r1 * g1[c] + b1[c];
        float nv = (sn0 + sn1 + xp[c]) * (1.f / 3.f);
        xp[c] = nv;
        qb[c] = f2b(nv);
    }
}

// ---------------- top-k v2: per-lane bitonic sort + xor-butterfly bitonic
// top-32 merge -> exact 32nd-largest V32; ballot-built mask words.
__global__ __launch_bounds__(256)
void topk_sel(const float* __restrict__ SIM, u64* __restrict__ MB){
    int wid = threadIdx.x >> 6, lane = threadIdx.x & 63;
    int r = blockIdx.x * 4 + wid;        // 0..B*LT-1
    int b = r / LT, i = r % LT;
    int bi, st, n; blk_info(i, bi, st, n);
    u64* mrow = MB + ((size_t)b * LT + i) * MBW;
    if (n == 16){                         // all 16 in-block keys banned
        u64 myw = 0;
        if (lane == 21) myw = ~0ULL;
        if (lane < MBW) mrow[lane] = myw;
        return;
    }
    int goff = (bi == 0) ? SG0 : (bi == 1) ? SG1 : SG2;
    const float* srow = SIM + (size_t)b * SBT + goff + (size_t)(i - st) * n;
    int ns = n >> 6;
    float vals[16];
    #pragma unroll
    for (int t = 0; t < 16; t++)
        vals[t] = (t < ns) ? srow[lane + (t << 6)] : -FLT_MAX;

    float c[32];
    #pragma unroll
    for (int t = 0; t < 16; t++) c[t] = vals[t];
    #pragma unroll
    for (int k = 2; k <= 16; k <<= 1){
        #pragma unroll
        for (int j = k >> 1; j > 0; j >>= 1){
            #pragma unroll
            for (int t = 0; t < 16; t++){
                int l = t ^ j;
                if (l > t){
                    float lo = fminf(c[t], c[l]);
                    float hi = fmaxf(c[t], c[l]);
                    if ((t & k) == 0){ c[t] = hi; c[l] = lo; }
                    else             { c[t] = lo; c[l] = hi; }
                }
            }
        }
    }
    #pragma unroll
    for (int t = 16; t < 32; t++) c[t] = -FLT_MAX;

    float V32;
    #pragma unroll
    for (int rd = 0; rd < 6; rd++){
        float f[32];
        #pragma unroll
        for (int t = 0; t < 32; t++) f[t] = __shfl_xor(c[t], 1 << rd, 64);
        float m[32];
        #pragma unroll
        for (int t = 0; t < 32; t++) m[t] = fmaxf(c[t], f[31 - t]);
        if (rd < 5){
            #pragma unroll
            for (int d = 16; d >= 1; d >>= 1){
                #pragma unroll
                for (int t = 0; t < 32; t++){
                    if ((t & d) == 0){
                        float lo = fminf(m[t], m[t + d]);
                        m[t] = fmaxf(m[t], m[t + d]);
                        m[t + d] = lo;
                    }
                }
            }
            #pragma unroll
            for (int t = 0; t < 32; t++) c[t] = m[t];
        } else {
            float mn = m[0];
            #pragma unroll
            for (int t = 1; t < 32; t++) mn = fminf(mn, m[t]);
            V32 = mn;
        }
    }

    int cnt_gt = 0;
    #pragma unroll
    for (int t = 0; t < 16; t++){
        u64 bg = __ballot(vals[t] > V32);
        cnt_gt += __popcll(bg);
    }
    int need = 32 - cnt_gt;
    u64 lmask = (1ULL << lane) - 1;
    u64 myw = 0;
    if (lane == 21) myw = 0xFFFFFFFFFFFF0000ULL;   // pad: keys 1360..1407 banned
    int eqrun = 0;
    int w0 = st >> 6;
    #pragma unroll
    for (int t = 0; t < 16; t++){
        bool eq = (vals[t] == V32);
        u64 beq = __ballot(eq);
        int below = __popcll(beq & lmask);
        bool sel = (vals[t] > V32) || (eq && (eqrun + below) < need);
        eqrun += __popcll(beq);
        u64 wsel = __ballot(sel);
        if (t < ns && lane == w0 + t) myw = wsel;
    }
    if (lane < MBW) mrow[lane] = myw;
}

// ---------------- FUSED attention dispatch: blocks [0,NFLASH) run flash
// (branch 1); blocks [NFLASH, ...) run sparse temporal attention (branch 0).
// Double-buffered flash (R12-best). R13 single-buffer regressed; do not revisit.
__global__ __launch_bounds__(256)
void attn_fused(const ushort* __restrict__ U, const u64* __restrict__ MB,
                const int* __restrict__ IDX, const int* __restrict__ CNT,
                ushort* __restrict__ AO0, ushort* __restrict__ AO1)
{
    __shared__ ushort Ks[2][64][76];
    __shared__ ushort Vs[2][64][76];
    if (blockIdx.x < NFLASH){
        // ================= flash branch (v5 body, flattened grid) =========
        const ushort* Q  = U + (size_t)NBLE;
        const ushort* Kp = U + (size_t)3*NBLE;
        const ushort* Vt = U + (size_t)4*NBLE;
        int fid = blockIdx.x;
        int bh = fid & 31, b = bh >> 3, h = bh & 7;
        int q0 = (fid >> 5) << 6;
        int tid = threadIdx.x;
        int w = tid >> 6, lane = tid & 63, quad = lane >> 4, l15 = lane & 15;

        int qm = q0 + w * 16 + l15;
        int qmc = (qm < LT) ? qm : (LT - 1);
        const ushort* qp = Q + ((size_t)(b * LT + qmc) << 9) + h * 64 + (quad << 3);
        short8 qf0 = *(const short8*)qp;
        short8 qf1 = *(const short8*)(qp + 32);

        float l_part = 0.f;
        f32x4 Oacc[4];
        #pragma unroll
        for (int dt = 0; dt < 4; dt++) Oacc[dt] = (f32x4){0.f,0.f,0.f,0.f};

        int srow = tid >> 2, sc = (tid & 3) << 4;

        const ushort* kpp = Kp + ((size_t)(b * LT + srow) << 9) + h * 64 + sc;
        const ushort* vpp = Vt + (size_t)(b * 512 + h * 64 + srow) * LT + sc;
        const u64* mpp = MB + ((size_t)b * LT + qmc) * MBW;

        int srcA = ((quad & 1) << 5) + l15;
        int srcB = srcA + 16;
        bool ntHi = (quad & 2) != 0;

        {
            uint4 k0v = *(const uint4*)kpp;
            uint4 k1v = *(const uint4*)(kpp + 8);
            uint4 v0v = *(const uint4*)vpp;
            uint4 v1v = *(const uint4*)(vpp + 8);
            kpp += 64 * 512; vpp += 64;
            *(uint4*)&Ks[0][srow][sc]     = k0v;
            *(uint4*)&Ks[0][srow][sc + 8] = k1v;
            *(uint4*)&Vs[0][srow][sc]     = v0v;
            *(uint4*)&Vs[0][srow][sc + 8] = v1v;
        }
        __syncthreads();

        for (int kt = 0; kt < 22; kt++){
            int cur = kt & 1;
            bool havenext = (kt + 1 < 22);
            uint4 kn0, kn1, vn0, vn1;
            if (havenext){
                kn0 = *(const uint4*)kpp;
                kn1 = *(const uint4*)(kpp + 8);
                vn0 = *(const uint4*)vpp;
                vn1 = *(const uint4*)(vpp + 8);
                kpp += 64 * 512; vpp += 64;
            }
            u64 mw = mpp[kt];
            f32x4 s[4];
            #pragma unroll
            for (int nt = 0; nt < 4; nt++) s[nt] = (f32x4){0.f,0.f,0.f,0.f};
            __builtin_amdgcn_s_setprio(1);
            #pragma unroll
            for (int nt = 0; nt < 4; nt++){
                short8 kf0 = *(const short8*)&Ks[cur][(nt << 4) + l15][quad << 3];
                short8 kf1 = *(const short8*)&Ks[cur][(nt << 4) + l15][32 + (quad << 3)];
                s[nt] = __builtin_amdgcn_mfma_f32_16x16x32_bf16(kf0, qf0, s[nt], 0, 0, 0);
                s[nt] = __builtin_amdgcn_mfma_f32_16x16x32_bf16(kf1, qf1, s[nt], 0, 0, 0);
            }
            __builtin_amdgcn_s_setprio(0);
            u64 msh = mw >> (quad << 2);
            uint32_t pk01[4], pk23[4];
            #pragma unroll
            for (int nt = 0; nt < 4; nt++){
                float p0 = ((uint32_t)(msh >> (nt * 16 + 0)) & 1u) ? 0.f : ex2(s[nt][0]);
                float p1 = ((uint32_t)(msh >> (nt * 16 + 1)) & 1u) ? 0.f : ex2(s[nt][1]);
                float p2 = ((uint32_t)(msh >> (nt * 16 + 2)) & 1u) ? 0.f : ex2(s[nt][2]);
                float p3 = ((uint32_t)(msh >> (nt * 16 + 3)) & 1u) ? 0.f : ex2(s[nt][3]);
                l_part += (p0 + p1) + (p2 + p3);
                pk01[nt] = pkbf(p0, p1);
                pk23[nt] = pkbf(p2, p3);
            }
            uint4 pa, pb;
            {
                uint32_t t0, t1;
                t0 = __shfl(pk01[0], srcA, 64); t1 = __shfl(pk01[1], srcA, 64);
                pa.x = ntHi ? t1 : t0;
                t0 = __shfl(pk23[0], srcA, 64); t1 = __shfl(pk23[1], srcA, 64);
                pa.y = ntHi ? t1 : t0;
                t0 = __shfl(pk01[0], srcB, 64); t1 = __shfl(pk01[1], srcB, 64);
                pa.z = ntHi ? t1 : t0;
                t0 = __shfl(pk23[0], srcB, 64); t1 = __shfl(pk23[1], srcB, 64);
                pa.w = ntHi ? t1 : t0;
                t0 = __shfl(pk01[2], srcA, 64); t1 = __shfl(pk01[3], srcA, 64);
                pb.x = ntHi ? t1 : t0;
                t0 = __shfl(pk23[2], srcA, 64); t1 = __shfl(pk23[3], srcA, 64);
                pb.y = ntHi ? t1 : t0;
                t0 = __shfl(pk01[2], srcB, 64); t1 = __shfl(pk01[3], srcB, 64);
                pb.z = ntHi ? t1 : t0;
                t0 = __shfl(pk23[2], srcB, 64); t1 = __shfl(pk23[3], srcB, 64);
                pb.w = ntHi ? t1 : t0;
            }
            short8 pf0 = *(const short8*)&pa;
            short8 pf1 = *(const short8*)&pb;
            __builtin_amdgcn_s_setprio(1);
            #pragma unroll
            for (int dt = 0; dt < 4; dt++){
                short8 vf0 = *(const short8*)&Vs[cur][(dt << 4) + l15][quad << 3];
                short8 vf1 = *(const short8*)&Vs[cur][(dt << 4) + l15][32 + (quad << 3)];
                Oacc[dt] = __builtin_amdgcn_mfma_f32_16x16x32_bf16(pf0, vf0, Oacc[dt], 0, 0, 0);
                Oacc[dt] = __builtin_amdgcn_mfma_f32_16x16x32_bf16(pf1, vf1, Oacc[dt], 0, 0, 0);
            }
            __builtin_amdgcn_s_setprio(0);
            if (havenext){
                int nb = cur ^ 1;
                *(uint4*)&Ks[nb][srow][sc]     = kn0;
                *(uint4*)&Ks[nb][srow][sc + 8] = kn1;
                *(uint4*)&Vs[nb][srow][sc]     = vn0;
                *(uint4*)&Vs[nb][srow][sc + 8] = vn1;
            }
            __syncthreads();
        }
        l_part += __shfl_xor(l_part, 16, 64);
        l_part += __shfl_xor(l_part, 32, 64);
        #pragma unroll
        for (int r = 0; r < 4; r++){
            int qrow = q0 + (w << 4) + (quad << 2) + r;
            if (qrow < LT){
                float lr = __shfl(l_part, (lane & 48) + (quad << 2) + r, 64);
                float inv = 1.f / lr;
                #pragma unroll
                for (int dt = 0; dt < 4; dt++)
                    AO1[((size_t)(b * LT + qrow) << 9) + h * 64 + (dt << 4) + l15] =
                        f2b(Oacc[dt][r] * inv);
            }
        }
    } else {
        // ================= sparse branch v2: quad-parallel keys ===========
        const ushort* Q  = U;
        const ushort* Kp = U + (size_t)2*NBLE;
        const ushort* Vn = U + (size_t)5*NBLE;
        int wid = threadIdx.x >> 6, lane = threadIdx.x & 63;
        int row = (blockIdx.x - NFLASH) * 4 + wid;
        int b = row / (NHH * LT);
        int rem = row % (NHH * LT);
        int h = rem / LT, i = rem % LT;
        int c = CNT[i];
        int quad = lane >> 4, l15 = lane & 15;
        int d0 = l15 << 2;                 // 4 consecutive d per lane
        int jl = IDX[i * 12 + (lane % 12)];
        const ushort* qp = Q + (((size_t)b * LT + i) << 9) + h * 64 + d0;
        uint2 qv = *(const uint2*)qp;
        float qd0 = b2f((ushort)qv.x), qd1 = b2f((ushort)(qv.x >> 16));
        float qd2 = b2f((ushort)qv.y), qd3 = b2f((ushort)(qv.y >> 16));
        const ushort* kb = Kp + (((size_t)b * LT) << 9) + h * 64 + d0;
        const ushort* vb = Vn + (((size_t)b * LT) << 9) + h * 64 + d0;
        float o0 = 0.f, o1 = 0.f, o2 = 0.f, o3 = 0.f;
        float lsum = 0.f;
        #pragma unroll
        for (int rr = 0; rr < 3; rr++){
            int t = (rr << 2) + quad;      // this quad's key index
            int j = __shfl(jl, t, 64);
            uint2 kv2 = *(const uint2*)(kb + ((size_t)j << 9));
            uint2 vv2 = *(const uint2*)(vb + ((size_t)j << 9));
            float s = qd0 * b2f((ushort)kv2.x) + qd1 * b2f((ushort)(kv2.x >> 16))
                    + qd2 * b2f((ushort)kv2.y) + qd3 * b2f((ushort)(kv2.y >> 16));
            s += __shfl_xor(s, 1, 64);
            s += __shfl_xor(s, 2, 64);
            s += __shfl_xor(s, 4, 64);
            s += __shfl_xor(s, 8, 64);     // intra-quad reduce (offsets < 16)
            float p = (t < c) ? ex2(s) : 0.f;
            lsum += p;
            o0 += p * b2f((ushort)vv2.x);
            o1 += p * b2f((ushort)(vv2.x >> 16));
            o2 += p * b2f((ushort)vv2.y);
            o3 += p * b2f((ushort)(vv2.y >> 16));
        }
        // cross-quad reduce: total over all 12 keys for each d-slot
        o0 += __shfl_xor(o0, 16, 64); o0 += __shfl_xor(o0, 32, 64);
        o1 += __shfl_xor(o1, 16, 64); o1 += __shfl_xor(o1, 32, 64);
        o2 += __shfl_xor(o2, 16, 64); o2 += __shfl_xor(o2, 32, 64);
        o3 += __shfl_xor(o3, 16, 64); o3 += __shfl_xor(o3, 32, 64);
        lsum += __shfl_xor(lsum, 16, 64);
        lsum += __shfl_xor(lsum, 32, 64);
        float inv = 1.f / lsum;
        if (quad == 0){
            uint2 ov;
            ov.x = pkbf(o0 * inv, o1 * inv);
            ov.y = pkbf(o2 * inv, o3 * inv);
            *(uint2*)(AO0 + (((size_t)b * LT + i) << 9) + h * 64 + d0) = ov;
        }
    }
}

extern "C" void kernel_launch(void* const* d_in, const int* in_sizes, int n_in,
                              void* d_out, int out_size, void* d_ws, size_t ws_size,
                              hipStream_t stream)
{
    const float* x_enc   = (const float*)d_in[0];
    const float* down_W  = (const float*)d_in[1];
    const float* down_b  = (const float*)d_in[2];
    const float* conv_W  = (const float*)d_in[3];
    const float* conv_b  = (const float*)d_in[4];
    const float* up_W    = (const float*)d_in[5];
    const float* up_b    = (const float*)d_in[6];
    const float* bc_g    = (const float*)d_in[7];
    const float* bc_b    = (const float*)d_in[8];
    const float* aWq     = (const float*)d_in[9];
    const float* aWk     = (const float*)d_in[10];
    const float* aWv     = (const float*)d_in[11];
    const float* afcW    = (const float*)d_in[12];
    const float* afcb    = (const float*)d_in[13];
    const float* alng    = (const float*)d_in[14];
    const float* alnb    = (const float*)d_in[15];
    const float* fW1     = (const float*)d_in[16];
    const float* fb1     = (const float*)d_in[17];
    const float* fW2     = (const float*)d_in[18];
    const float* fb2     = (const float*)d_in[19];
    const float* flng    = (const float*)d_in[20];
    const float* flnb    = (const float*)d_in[21];

    const size_t NBL = (size_t)NBLE;
    float* X   = (float*)d_ws;
    float* TMP = X   + NBL;
    float* Qb  = TMP + NBL;
    float* Kb  = Qb  + NBL;
    float* Vb  = Kb  + NBL;
    float* AO  = Vb  + NBL;
    float* TO  = AO  + NBL;
    float* SO  = TO  + NBL;
    u64* MBm = (u64*)(SO + NBL);                      // B*LT*24 words
    int* TIDX = (int*)(MBm + (size_t)BB * LT * MBW);
    int* TCNT = TIDX + (size_t)LT * 12;
    ushort* WG = (ushort*)(TCNT + LT);
    const size_t M512 = 262144;
    ushort* WdownT = WG;                 size_t wo = M512;
    ushort* WupT   = WG + wo;            wo += M512;
    ushort* Wqkv   = WG + wo;            wo += 12 * M512;   // 4 layers x [Wq|Wk|Wv]^T
    ushort* WfT    = WG + wo;            wo += 4 * M512;
    ushort* W1T    = WG + wo;            wo += 2 * M512;
    ushort* W2T    = WG + wo;            wo += 2 * M512;
    ushort* WCt    = WG + wo;            wo += 3 * 1048576;
    float* LP = (float*)(WG + wo);                        // (kept for sizing)
    (void)LP;
    size_t need = 8 * NBL * sizeof(float) + (size_t)BB * LT * MBW * 8
                + (size_t)LT * 13 * 4 + wo * sizeof(ushort)
                + (size_t)2 * BB * NHH * LT * 4;
    if (ws_size < need) return;

    // aliases (lifetimes disjoint)
    float* Y    = Qb;
    float* C1   = Kb;
    float* C2   = C1 + (size_t)BB*256*512;
    float* C3   = C2 + (size_t)BB*64*512;
    float* PCAT = Vb;
    float* SKP  = AO;                     // split-K partials (bottleneck only)
    ushort* XNh = (ushort*)AO;            // hi/lo bf16 normalized rows
    ushort* XNl = XNh + NBLE;
    float* SIMB = Qb;
    ushort* U   = (ushort*)Qb;            // merged QKV: Q0@0 Q1@N K0@2N K1@3N Vt1@4N Vn0@5N
    ushort* XB  = (ushort*)SO;            // bf16 X (QKV/FFN1 A-operand)
    ushort* AOb0 = (ushort*)AO;           // branch0 attention out [0,N)
    ushort* AOb1 = AOb0 + NBLE;           // branch1 attention out [N,2N)
    ushort* HfB = (ushort*)Qb;            // bf16 FFN hidden
    float* TMP1 = TO;                     // second fc output (TO region reused)

    auto gemmN = [&](const void* A, int abf, const ushort* Bw, const float* bias,
                     const float* res, void* C, int M,
                     int act, int omode, int mpb, int orpb, int ooff){
        dim3 grid(8, M / 64);
        if (abf) gemm64t<1><<<grid, 256, 0, stream>>>(A, Bw, bias, res, C, M, 512, 512,
                                                      act, omode, mpb, orpb, ooff);
        else     gemm64t<0><<<grid, 256, 0, stream>>>(A, Bw, bias, res, C, M, 512, 512,
                                                      act, omode, mpb, orpb, ooff);
    };
    auto convG = [&](const float* A, const ushort* Bw, const float* bias,
                     float* C, int M){
        const int S = 8, K = 2048, N = 512;
        gemm_sk<<<dim3(8, M / 64, S), 256, 0, stream>>>(A, Bw, SKP, M, N, K, K / S);
        sk_reduce<<<(M * N) / 1024, 256, 0, stream>>>(SKP, bias, C, M * N, S);
    };

    build_tidx<<<(LT + 255) / 256, 256, 0, stream>>>(TIDX, TCNT);
    wtrans<<<dim3(8, 8, 1), 256, 0, stream>>>(down_W, WdownT, 512, 512, M512);
    wtrans<<<dim3(8, 8, 1), 256, 0, stream>>>(up_W,   WupT,   512, 512, M512);
    wtrans<<<dim3(8, 8, 4), 256, 0, stream>>>(aWq,  Wqkv + 0 * M512, 512, 512, 3 * (long)M512);
    wtrans<<<dim3(8, 8, 4), 256, 0, stream>>>(aWk,  Wqkv + 1 * M512, 512, 512, 3 * (long)M512);
    wtrans<<<dim3(8, 8, 4), 256, 0, stream>>>(aWv,  Wqkv + 2 * M512, 512, 512, 3 * (long)M512);
    wtrans<<<dim3(8, 8, 4), 256, 0, stream>>>(afcW, WfT, 512, 512, M512);
    wtrans<<<dim3(8, 8, 2), 256, 0, stream>>>(fW1,  W1T, 512, 512, M512);
    wtrans<<<dim3(8, 8, 2), 256, 0, stream>>>(fW2,  W2T, 512, 512, M512);
    wconv<<<dim3(4096, 3), 256, 0, stream>>>(conv_W, WCt);

    // ---- bottleneck
    gemmN(x_enc, 0, WdownT, down_b, nullptr, Y, BB*1024, 0, 0, 0, 0, 0);
    convG(Y,  WCt,             conv_b + 0,    C1, BB*256);
    convG(C1, WCt + 1048576,   conv_b + 512,  C2, BB*64);
    convG(C2, WCt + 2*1048576, conv_b + 1024, C3, BB*16);
    pcat_copy<<<(BB*336*512)/256, 256, 0, stream>>>(C1, C2, C3, PCAT);
    gemmN(PCAT, 0, WupT, up_b, nullptr, TMP, BB*336, 0, 0, 336, LT, 1024);
    xenc_copy<<<(BB*1024*512)/256, 256, 0, stream>>>(x_enc, TMP);
    // ln with fused rownorm (XNh/XNl for layer-0 sim)
    ln_kernel<<<(BB*LT)/4, 256, 0, stream>>>(TMP, bc_g, bc_b, X, XB, XNh, XNl, 1e-5f);

    // ---- transformer layers
    for (int l = 0; l < 2; l++){
        sim_mfma<<<dim3(274, BB), 256, 0, stream>>>(XNh, XNl, SIMB);
        topk_sel<<<(BB*LT)/4, 256, 0, stream>>>(SIMB, MBm);

        // merged dual-QKV (both branches) from bf16 X
        gemm_qkv<<<dim3(24, 85), 256, 0, stream>>>(XB, Wqkv + (size_t)l * 6 * M512,
                                                   U, BB*LT, 3072, 512);
        // fused attention: flash (704 blocks) + sparse (10880 blocks)
        attn_fused<<<dim3(NFLASH + (BB*NHH*LT)/4), 256, 0, stream>>>(
            U, MBm, TIDX, TCNT, AOb0, AOb1);
        // both output projections in one launch
        gemm_fc2<<<dim3(8, 85, 2), 256, 0, stream>>>(AOb0, AOb1,
            WfT + (size_t)(2*l) * M512, WfT + (size_t)(2*l + 1) * M512,
            afcb + (size_t)(2*l) * 512, afcb + (size_t)(2*l + 1) * 512,
            X, TMP, TMP1, BB*LT, 512, 512);
        // fused dual-LN + add3
        ln2_add3<<<(BB*LT)/4, 256, 0, stream>>>(TMP, TMP1,
            alng + (size_t)(2*l) * 512, alnb + (size_t)(2*l) * 512,
            alng + (size_t)(2*l + 1) * 512, alnb + (size_t)(2*l + 1) * 512,
            X, XB, 1e-6f);

        // FFN (bf16 A everywhere)
        gemmN(XB,  1, W1T + (size_t)l * M512, fb1 + (size_t)l*512, nullptr, HfB, BB*LT, 2, 1, 0, 0, 0);
        gemmN(HfB, 1, W2T + (size_t)l * M512, fb2 + (size_t)l*512, X, TMP, BB*LT, 0, 0, 0, 0, 0);
        // final ln: fused rownorm only when a next layer consumes XNh/XNl
        ln_kernel<<<(BB*LT)/4, 256, 0, stream>>>(TMP, flng + (size_t)l*512, flnb + (size_t)l*512,
                                                 (l == 1) ? (float*)d_out : X,
                                                 (l == 1) ? nullptr : XB,
                                                 (l == 1) ? nullptr : XNh,
                                                 (l == 1) ? nullptr : XNl, 1e-6f);
    }
}

// Round 17
// 669.103 us; speedup vs baseline: 1.0810x; 1.0092x over previous
//
#include <hip/hip_runtime.h>
#include <float.h>
#include <math.h>
#include <stdint.h>

#define LT 1360
#define BB 4
#define DM 512
#define NHH 8
#define NBLE 2785280   // BB*LT*512 elements
#define MBW 24         // mask words (uint64) per row
#define QSCALE 0.18033688f   // 0.125 * log2(e)
#define NFLASH 704     // flash blocks in fused attention dispatch (32 bh x 22 qt)

typedef __attribute__((ext_vector_type(8))) short short8;
typedef __attribute__((ext_vector_type(4))) float f32x4;
typedef unsigned long long u64;

__device__ __forceinline__ ushort f2b(float x){
    uint32_t u = __float_as_uint(x);
    return (ushort)((u + 0x7fffu + ((u >> 16) & 1u)) >> 16);
}
__device__ __forceinline__ float b2f(ushort u){
    return __uint_as_float(((uint32_t)u) << 16);
}
// raw v_exp_f32 (2^x). Safe here: masked-out lanes cndmask to 0, live lanes bounded.
__device__ __forceinline__ float ex2(float x){
    float r;
    asm("v_exp_f32 %0, %1" : "=v"(r) : "v"(x));
    return r;
}
// packed f32x2 -> bf16x2, RNE (same rounding as f2b)
__device__ __forceinline__ uint32_t pkbf(float lo, float hi){
    uint32_t r;
    asm("v_cvt_pk_bf16_f32 %0, %1, %2" : "=v"(r) : "v"(lo), "v"(hi));
    return r;
}

// semantic sim buffer layout (per batch)
#define SG0 0
#define SG1 1048576
#define SG2 (SG1 + 65536)
#define SG3 (SG2 + 4096)
#define SBT (SG3 + 256)

__device__ __forceinline__ void blk_info(int i, int& bi, int& st, int& n){
    if (i < 1024){ bi = 0; st = 0;    n = 1024; }
    else if (i < 1280){ bi = 1; st = 1024; n = 256; }
    else if (i < 1344){ bi = 2; st = 1280; n = 64; }
    else { bi = 3; st = 1344; n = 16; }
}

// ---------------- temporal allowed-index lists (padded to 12 for speculative loads)
__global__ __launch_bounds__(256)
void build_tidx(int* __restrict__ idx, int* __restrict__ cnt){
    int i = blockIdx.x * 256 + threadIdx.x;
    if (i >= LT) return;
    int bi, st, n; blk_info(i, bi, st, n);
    int c = 0; int* row = idx + i * 12;
    int lo = (i - 2 > st) ? i - 2 : st;
    int hi = (i + 2 < st + n - 1) ? i + 2 : st + n - 1;
    for (int j = lo; j <= hi; j++) row[c++] = j;
    if (bi < 3) row[c++] = st + n + (i - st) / 4;
    if (bi > 0){
        int stc = st - n * 4;
        int base = stc + (i - st) * 4;
        for (int t = 0; t < 4; t++) row[c++] = base + t;
    }
    cnt[i] = c;
    for (int t = c; t < 12; t++) row[t] = 0;   // safe pad
}

// ---------------- ALL weight transposes in ONE dispatch (R16): 22 matrices x
// 64 tiles = 1408 blocks (5.5/CU) replaces 8 serialized tiny launches.
// Per-tile body identical to the old wtrans => bit-identical outputs.
// Matrix map: 0=down, 1=up, 2-5=Wq[l,b], 6-9=Wk, 10-13=Wv (interleaved into
// Wqkv at stride 3*M512), 14-17=fcW, 18-19=fW1, 20-21=fW2.
__global__ __launch_bounds__(256)
void wtrans_all(const float* __restrict__ dW, const float* __restrict__ uW,
                const float* __restrict__ qW, const float* __restrict__ kW,
                const float* __restrict__ vW, const float* __restrict__ fW,
                const float* __restrict__ w1, const float* __restrict__ w2,
                ushort* __restrict__ WdownT, ushort* __restrict__ WupT,
                ushort* __restrict__ Wqkv, ushort* __restrict__ WfT,
                ushort* __restrict__ W1T, ushort* __restrict__ W2T)
{
    const size_t M512 = 262144;
    int bid = blockIdx.x;
    int m = bid >> 6, t = bid & 63;
    int k0 = (t >> 3) << 6, n0 = (t & 7) << 6;
    const float* Ws; ushort* Wd;
    if (m == 0)      { Ws = dW;                          Wd = WdownT; }
    else if (m == 1) { Ws = uW;                          Wd = WupT; }
    else if (m < 6)  { int i = m - 2;  Ws = qW + (size_t)i * M512; Wd = Wqkv + (size_t)(3*i)     * M512; }
    else if (m < 10) { int i = m - 6;  Ws = kW + (size_t)i * M512; Wd = Wqkv + (size_t)(3*i + 1) * M512; }
    else if (m < 14) { int i = m - 10; Ws = vW + (size_t)i * M512; Wd = Wqkv + (size_t)(3*i + 2) * M512; }
    else if (m < 18) { int i = m - 14; Ws = fW + (size_t)i * M512; Wd = WfT + (size_t)i * M512; }
    else if (m < 20) { int i = m - 18; Ws = w1 + (size_t)i * M512; Wd = W1T + (size_t)i * M512; }
    else             { int i = m - 20; Ws = w2 + (size_t)i * M512; Wd = W2T + (size_t)i * M512; }
    __shared__ ushort tb[64][72];
    int tid = threadIdx.x;
    #pragma unroll
    for (int p = 0; p < 4; p++){
        int idx = tid + (p << 8);
        int r = idx >> 4, c4 = (idx & 15) << 2;
        float4 v = *(const float4*)(Ws + (size_t)(k0 + r) * 512 + n0 + c4);
        tb[c4+0][r] = f2b(v.x); tb[c4+1][r] = f2b(v.y);
        tb[c4+2][r] = f2b(v.z); tb[c4+3][r] = f2b(v.w);
    }
    __syncthreads();
    #pragma unroll
    for (int p = 0; p < 4; p++){
        int idx = tid + (p << 8);
        int r = idx >> 4, c4 = (idx & 15) << 2;
        *(uint2*)&Wd[(size_t)(n0 + r) * 512 + k0 + c4] = *(uint2*)&tb[r][c4];
    }
}

// ---------------- conv weight repack+cast
__global__ __launch_bounds__(256)
void wconv(const float* __restrict__ cw, ushort* __restrict__ wt){
    int conv = blockIdx.y;
    const float* src = cw + (size_t)conv * 512 * 512 * 4;
    ushort* dst = wt + (size_t)conv * 2048 * 512;
    int idx = blockIdx.x * 256 + threadIdx.x;
    int o = idx >> 11, rest = idx & 2047;
    int k = rest >> 9, ii = rest & 511;
    dst[idx] = f2b(src[((size_t)(o << 9) + ii) * 4 + k]);
}

// ---------------- merged dual-QKV GEMM: bf16 A, 64x128 tile, BK=64, reg-prefetch.
// N=3072 = [Q0|K0|V0|Q1|K1|V1]. Outputs: Q0@0, Q1@N, K0@2N, K1@3N, Vt1@4N, Vn0@5N.
// NOTE (R15): the 64x128 tile pays off HERE because grid = 24x85 = 2040
// blocks (8/CU). Porting it to the N=512 GEMMs (grid 340, 1.33/CU) REGRESSED
// +8us/dispatch — tail-wave quantization. Keep 64x64 for N=512.
__global__ __launch_bounds__(256)
void gemm_qkv(const ushort* __restrict__ A, const ushort* __restrict__ Bw,
              void* __restrict__ Cout, int M, int N, int K)
{
    __shared__ ushort As[64][72];
    __shared__ ushort Bs[128][72];
    int tid = threadIdx.x;
    int lane = tid & 63, w = tid >> 6, quad = lane >> 4, l15 = lane & 15;
    int gm = blockIdx.y << 6, gn = blockIdx.x << 7;
    int arow = tid >> 2, ac = (tid & 3) << 4;
    int brow = tid >> 1, bc = (tid & 1) << 5;
    f32x4 acc[4][2];
    #pragma unroll
    for (int mi = 0; mi < 4; mi++)
        #pragma unroll
        for (int ni = 0; ni < 2; ni++)
            acc[mi][ni] = (f32x4){0.f,0.f,0.f,0.f};
    const ushort* Ap = A + (size_t)(gm + arow) * K + ac;
    const ushort* Bp = Bw + (size_t)(gn + brow) * K + bc;
    uint4 a0r = *(const uint4*)(Ap);
    uint4 a1r = *(const uint4*)(Ap + 8);
    uint4 b0r = *(const uint4*)(Bp);
    uint4 b1r = *(const uint4*)(Bp + 8);
    uint4 b2r = *(const uint4*)(Bp + 16);
    uint4 b3r = *(const uint4*)(Bp + 24);
    *(uint4*)&As[arow][ac]     = a0r;  *(uint4*)&As[arow][ac + 8]  = a1r;
    *(uint4*)&Bs[brow][bc]     = b0r;  *(uint4*)&Bs[brow][bc + 8]  = b1r;
    *(uint4*)&Bs[brow][bc + 16] = b2r; *(uint4*)&Bs[brow][bc + 24] = b3r;
    __syncthreads();
    for (int k0 = 0; k0 < K; k0 += 64){
        bool nx = (k0 + 64 < K);
        if (nx){
            a0r = *(const uint4*)(Ap + k0 + 64);
            a1r = *(const uint4*)(Ap + k0 + 72);
            b0r = *(const uint4*)(Bp + k0 + 64);
            b1r = *(const uint4*)(Bp + k0 + 72);
            b2r = *(const uint4*)(Bp + k0 + 80);
            b3r = *(const uint4*)(Bp + k0 + 88);
        }
        __builtin_amdgcn_s_setprio(1);
        #pragma unroll
        for (int kk = 0; kk < 2; kk++){
            short8 af[4], bf[2];
            #pragma unroll
            for (int mi = 0; mi < 4; mi++)
                af[mi] = *(const short8*)&As[(mi << 4) + l15][(kk << 5) + (quad << 3)];
            #pragma unroll
            for (int ni = 0; ni < 2; ni++)
                bf[ni] = *(const short8*)&Bs[(w << 5) + (ni << 4) + l15][(kk << 5) + (quad << 3)];
            #pragma unroll
            for (int mi = 0; mi < 4; mi++)
                #pragma unroll
                for (int ni = 0; ni < 2; ni++)
                    acc[mi][ni] = __builtin_amdgcn_mfma_f32_16x16x32_bf16(af[mi], bf[ni], acc[mi][ni], 0, 0, 0);
        }
        __builtin_amdgcn_s_setprio(0);
        if (nx){
            __syncthreads();
            *(uint4*)&As[arow][ac]     = a0r;  *(uint4*)&As[arow][ac + 8]  = a1r;
            *(uint4*)&Bs[brow][bc]     = b0r;  *(uint4*)&Bs[brow][bc + 8]  = b1r;
            *(uint4*)&Bs[brow][bc + 16] = b2r; *(uint4*)&Bs[brow][bc + 24] = b3r;
            __syncthreads();
        }
    }
    int seg = gn >> 9, gc = gn & 511;
    ushort* Ob = (ushort*)Cout;
    if (seg == 2){
        // branch0 V: Vn0 only (scalar stores), @5N
        #pragma unroll
        for (int mi = 0; mi < 4; mi++)
            #pragma unroll
            for (int r = 0; r < 4; r++){
                int row = gm + (mi << 4) + (quad << 2) + r;
                #pragma unroll
                for (int ni = 0; ni < 2; ni++){
                    int cloc = (w << 5) + (ni << 4) + l15;
                    Ob[(size_t)5*NBLE + (size_t)row * 512 + gc + cloc] = f2b(acc[mi][ni][r]);
                }
            }
    } else if (seg == 5){
        // branch1 V: V^T only via LDS transpose, @4N
        __syncthreads();
        #pragma unroll
        for (int mi = 0; mi < 4; mi++)
            #pragma unroll
            for (int r = 0; r < 4; r++){
                int rloc = (mi << 4) + (quad << 2) + r;
                #pragma unroll
                for (int ni = 0; ni < 2; ni++){
                    int cloc = (w << 5) + (ni << 4) + l15;
                    Bs[cloc][rloc] = f2b(acc[mi][ni][r]);
                }
            }
        __syncthreads();
        int colw = tid >> 3;            // 0..31
        int jo = (tid & 7) << 3;        // row offset within tile, 0..56
        int rr = gm + jo;
        int bb = rr / LT;
        int ii = rr - bb * LT;
        #pragma unroll
        for (int cc = 0; cc < 4; cc++){
            int c = colw + (cc << 5);   // 0..127
            uint4 tv = *(const uint4*)&Bs[c][jo];
            ushort* dst = Ob + (size_t)4*NBLE + ((size_t)(bb * 512 + gc + c)) * LT + ii;
            *(uint4*)dst = tv;
        }
    } else {
        // Q/K segments: Q0@0 (scaled), K0@2N, Q1@N (scaled), K1@3N
        size_t base = (seg == 0) ? 0 : (seg == 1) ? (size_t)2*NBLE
                    : (seg == 3) ? (size_t)NBLE : (size_t)3*NBLE;
        float scl = (seg == 0 || seg == 3) ? QSCALE : 1.f;
        #pragma unroll
        for (int mi = 0; mi < 4; mi++)
            #pragma unroll
            for (int r = 0; r < 4; r++){
                int row = gm + (mi << 4) + (quad << 2) + r;
                #pragma unroll
                for (int ni = 0; ni < 2; ni++){
                    int c5 = gc + (w << 5) + (ni << 4) + l15;
                    Ob[base + (size_t)row * 512 + c5] = f2b(acc[mi][ni][r] * scl);
                }
            }
    }
}

// ---------------- bf16 MFMA GEMM, 64x64 tile, BK=64, reg-prefetch.
// ABF=1: A is bf16; ABF=0: A fp32 (converted at LDS-store time).
// NOTE: BK=128 regressed (R6); 64x128 tile at N=512 regressed (R15). Keep.
template<int ABF>
__global__ __launch_bounds__(256)
void gemm64t(const void* __restrict__ Avp, const ushort* __restrict__ Bw,
             const float* __restrict__ bias, const float* __restrict__ Rres,
             void* __restrict__ Cout, int M, int N, int K,
             int act, int omode, int mpb, int orpb, int ooff)
{
    __shared__ ushort As[64][72];
    __shared__ ushort Bs[64][72];
    int tid = threadIdx.x;
    int lane = tid & 63, w = tid >> 6, quad = lane >> 4, l15 = lane & 15;
    int gm = blockIdx.y << 6, gn = blockIdx.x << 6;
    int wr = (w >> 1) << 5, wc = (w & 1) << 5;
    int srow = tid >> 2, sc = (tid & 3) << 4;
    f32x4 acc[2][2];
    #pragma unroll
    for (int mi = 0; mi < 2; mi++)
        #pragma unroll
        for (int ni = 0; ni < 2; ni++)
            acc[mi][ni] = (f32x4){0.f,0.f,0.f,0.f};
    const float*  Af = (const float*)Avp;
    const ushort* Ab = (const ushort*)Avp;
    size_t aoff = (size_t)(gm + srow) * K + sc;
    const ushort* Bp = Bw + (size_t)(gn + srow) * K + sc;
    uint4 aR0, aR1, bR0, bR1;
    float4 f0, f1, f2v, f3v;
    if (ABF){
        aR0 = *(const uint4*)(Ab + aoff);
        aR1 = *(const uint4*)(Ab + aoff + 8);
    } else {
        f0  = *(const float4*)(Af + aoff);
        f1  = *(const float4*)(Af + aoff + 4);
        f2v = *(const float4*)(Af + aoff + 8);
        f3v = *(const float4*)(Af + aoff + 12);
    }
    bR0 = *(const uint4*)(Bp);
    bR1 = *(const uint4*)(Bp + 8);
    if (!ABF){
        aR0.x = (uint32_t)f2b(f0.x)  | ((uint32_t)f2b(f0.y)  << 16);
        aR0.y = (uint32_t)f2b(f0.z)  | ((uint32_t)f2b(f0.w)  << 16);
        aR0.z = (uint32_t)f2b(f1.x)  | ((uint32_t)f2b(f1.y)  << 16);
        aR0.w = (uint32_t)f2b(f1.z)  | ((uint32_t)f2b(f1.w)  << 16);
        aR1.x = (uint32_t)f2b(f2v.x) | ((uint32_t)f2b(f2v.y) << 16);
        aR1.y = (uint32_t)f2b(f2v.z) | ((uint32_t)f2b(f2v.w) << 16);
        aR1.z = (uint32_t)f2b(f3v.x) | ((uint32_t)f2b(f3v.y) << 16);
        aR1.w = (uint32_t)f2b(f3v.z) | ((uint32_t)f2b(f3v.w) << 16);
    }
    *(uint4*)&As[srow][sc]     = aR0;
    *(uint4*)&As[srow][sc + 8] = aR1;
    *(uint4*)&Bs[srow][sc]     = bR0;
    *(uint4*)&Bs[srow][sc + 8] = bR1;
    __syncthreads();
    for (int k0 = 0; k0 < K; k0 += 64){
        bool nx = (k0 + 64 < K);
        if (nx){
            if (ABF){
                aR0 = *(const uint4*)(Ab + aoff + k0 + 64);
                aR1 = *(const uint4*)(Ab + aoff + k0 + 72);
            } else {
                f0  = *(const float4*)(Af + aoff + k0 + 64);
                f1  = *(const float4*)(Af + aoff + k0 + 68);
                f2v = *(const float4*)(Af + aoff + k0 + 72);
                f3v = *(const float4*)(Af + aoff + k0 + 76);
            }
            bR0 = *(const uint4*)(Bp + k0 + 64);
            bR1 = *(const uint4*)(Bp + k0 + 72);
        }
        __builtin_amdgcn_s_setprio(1);
        #pragma unroll
        for (int kk = 0; kk < 2; kk++){
            short8 af0 = *(const short8*)&As[wr + l15][(kk << 5) + (quad << 3)];
            short8 af1 = *(const short8*)&As[wr + 16 + l15][(kk << 5) + (quad << 3)];
            short8 bf0 = *(const short8*)&Bs[wc + l15][(kk << 5) + (quad << 3)];
            short8 bf1 = *(const short8*)&Bs[wc + 16 + l15][(kk << 5) + (quad << 3)];
            acc[0][0] = __builtin_amdgcn_mfma_f32_16x16x32_bf16(af0, bf0, acc[0][0], 0, 0, 0);
            acc[0][1] = __builtin_amdgcn_mfma_f32_16x16x32_bf16(af0, bf1, acc[0][1], 0, 0, 0);
            acc[1][0] = __builtin_amdgcn_mfma_f32_16x16x32_bf16(af1, bf0, acc[1][0], 0, 0, 0);
            acc[1][1] = __builtin_amdgcn_mfma_f32_16x16x32_bf16(af1, bf1, acc[1][1], 0, 0, 0);
        }
        __builtin_amdgcn_s_setprio(0);
        if (nx){
            __syncthreads();
            if (!ABF){
                aR0.x = (uint32_t)f2b(f0.x)  | ((uint32_t)f2b(f0.y)  << 16);
                aR0.y = (uint32_t)f2b(f0.z)  | ((uint32_t)f2b(f0.w)  << 16);
                aR0.z = (uint32_t)f2b(f1.x)  | ((uint32_t)f2b(f1.y)  << 16);
                aR0.w = (uint32_t)f2b(f1.z)  | ((uint32_t)f2b(f1.w)  << 16);
                aR1.x = (uint32_t)f2b(f2v.x) | ((uint32_t)f2b(f2v.y) << 16);
                aR1.y = (uint32_t)f2b(f2v.z) | ((uint32_t)f2b(f2v.w) << 16);
                aR1.z = (uint32_t)f2b(f3v.x) | ((uint32_t)f2b(f3v.y) << 16);
                aR1.w = (uint32_t)f2b(f3v.z) | ((uint32_t)f2b(f3v.w) << 16);
            }
            *(uint4*)&As[srow][sc]     = aR0;
            *(uint4*)&As[srow][sc + 8] = aR1;
            *(uint4*)&Bs[srow][sc]     = bR0;
            *(uint4*)&Bs[srow][sc + 8] = bR1;
            __syncthreads();
        }
    }
    #pragma unroll
    for (int mi = 0; mi < 2; mi++){
        #pragma unroll
        for (int r = 0; r < 4; r++){
            int row = gm + wr + (mi << 4) + (quad << 2) + r;
            #pragma unroll
            for (int ni = 0; ni < 2; ni++){
                int col = gn + wc + (ni << 4) + l15;
                float v = acc[mi][ni][r];
                if (bias) v += bias[col];
                if (Rres) v += Rres[(size_t)row * N + col];
                if (act == 2){ v = fmaxf(v, 0.f); }
                if (omode == 0){
                    int orow = mpb ? (row / mpb) * orpb + ooff + (row % mpb) : row;
                    ((float*)Cout)[(size_t)orow * N + col] = v;
                } else {
                    ((ushort*)Cout)[(size_t)row * N + col] = f2b(v);
                }
            }
        }
    }
}

// ---------------- batched dual fc GEMM (grid.z selects branch): bf16 A,
// 64x64 tile, BK=64, reg-prefetch; out = A*W + bias + X (fp32).
__global__ __launch_bounds__(256)
void gemm_fc2(const ushort* __restrict__ A0, const ushort* __restrict__ A1,
              const ushort* __restrict__ B0, const ushort* __restrict__ B1,
              const float* __restrict__ bias0, const float* __restrict__ bias1,
              const float* __restrict__ Rres, float* __restrict__ C0,
              float* __restrict__ C1, int M, int N, int K)
{
    __shared__ ushort As[64][72];
    __shared__ ushort Bs[64][72];
    const ushort* Ab = blockIdx.z ? A1 : A0;
    const ushort* Bw = blockIdx.z ? B1 : B0;
    const float* bias = blockIdx.z ? bias1 : bias0;
    float* Cout = blockIdx.z ? C1 : C0;
    int tid = threadIdx.x;
    int lane = tid & 63, w = tid >> 6, quad = lane >> 4, l15 = lane & 15;
    int gm = blockIdx.y << 6, gn = blockIdx.x << 6;
    int wr = (w >> 1) << 5, wc = (w & 1) << 5;
    int srow = tid >> 2, sc = (tid & 3) << 4;
    f32x4 acc[2][2];
    #pragma unroll
    for (int mi = 0; mi < 2; mi++)
        #pragma unroll
        for (int ni = 0; ni < 2; ni++)
            acc[mi][ni] = (f32x4){0.f,0.f,0.f,0.f};
    size_t aoff = (size_t)(gm + srow) * K + sc;
    const ushort* Bp = Bw + (size_t)(gn + srow) * K + sc;
    uint4 aR0 = *(const uint4*)(Ab + aoff);
    uint4 aR1 = *(const uint4*)(Ab + aoff + 8);
    uint4 bR0 = *(const uint4*)(Bp);
    uint4 bR1 = *(const uint4*)(Bp + 8);
    *(uint4*)&As[srow][sc]     = aR0;
    *(uint4*)&As[srow][sc + 8] = aR1;
    *(uint4*)&Bs[srow][sc]     = bR0;
    *(uint4*)&Bs[srow][sc + 8] = bR1;
    __syncthreads();
    for (int k0 = 0; k0 < K; k0 += 64){
        bool nx = (k0 + 64 < K);
        if (nx){
            aR0 = *(const uint4*)(Ab + aoff + k0 + 64);
            aR1 = *(const uint4*)(Ab + aoff + k0 + 72);
            bR0 = *(const uint4*)(Bp + k0 + 64);
            bR1 = *(const uint4*)(Bp + k0 + 72);
        }
        __builtin_amdgcn_s_setprio(1);
        #pragma unroll
        for (int kk = 0; kk < 2; kk++){
            short8 af0 = *(const short8*)&As[wr + l15][(kk << 5) + (quad << 3)];
            short8 af1 = *(const short8*)&As[wr + 16 + l15][(kk << 5) + (quad << 3)];
            short8 bf0 = *(const short8*)&Bs[wc + l15][(kk << 5) + (quad << 3)];
            short8 bf1 = *(const short8*)&Bs[wc + 16 + l15][(kk << 5) + (quad << 3)];
            acc[0][0] = __builtin_amdgcn_mfma_f32_16x16x32_bf16(af0, bf0, acc[0][0], 0, 0, 0);
            acc[0][1] = __builtin_amdgcn_mfma_f32_16x16x32_bf16(af0, bf1, acc[0][1], 0, 0, 0);
            acc[1][0] = __builtin_amdgcn_mfma_f32_16x16x32_bf16(af1, bf0, acc[1][0], 0, 0, 0);
            acc[1][1] = __builtin_amdgcn_mfma_f32_16x16x32_bf16(af1, bf1, acc[1][1], 0, 0, 0);
        }
        __builtin_amdgcn_s_setprio(0);
        if (nx){
            __syncthreads();
            *(uint4*)&As[srow][sc]     = aR0;
            *(uint4*)&As[srow][sc + 8] = aR1;
            *(uint4*)&Bs[srow][sc]     = bR0;
            *(uint4*)&Bs[srow][sc + 8] = bR1;
            __syncthreads();
        }
    }
    #pragma unroll
    for (int mi = 0; mi < 2; mi++){
        #pragma unroll
        for (int r = 0; r < 4; r++){
            int row = gm + wr + (mi << 4) + (quad << 2) + r;
            #pragma unroll
            for (int ni = 0; ni < 2; ni++){
                int col = gn + wc + (ni << 4) + l15;
                float v = acc[mi][ni][r] + bias[col] + Rres[(size_t)row * N + col];
                Cout[(size_t)row * N + col] = v;
            }
        }
    }
}

// ---------------- split-K bf16 GEMM for tiny-M conv chain (v2: BK=64,
// register prefetch, setprio; accumulation order unchanged => bit-identical).
__global__ __launch_bounds__(256)
void gemm_sk(const float* __restrict__ A, const ushort* __restrict__ Bw,
             float* __restrict__ P, int M, int N, int K, int kslice)
{
    __shared__ ushort As[64][72];
    __shared__ ushort Bs[64][72];
    int tid = threadIdx.x;
    int lane = tid & 63, w = tid >> 6, quad = lane >> 4, l15 = lane & 15;
    int gm = blockIdx.y << 6, gn = blockIdx.x << 6;
    int wr = (w >> 1) << 5, wc = (w & 1) << 5;
    int srow = tid >> 2, sc = (tid & 3) << 4;
    int ks = blockIdx.z * kslice;
    f32x4 acc[2][2];
    #pragma unroll
    for (int mi = 0; mi < 2; mi++)
        #pragma unroll
        for (int ni = 0; ni < 2; ni++)
            acc[mi][ni] = (f32x4){0.f,0.f,0.f,0.f};
    size_t aoff = (size_t)(gm + srow) * K + ks + sc;
    const ushort* Bp = Bw + (size_t)(gn + srow) * K + ks + sc;
    uint4 aR0, aR1, bR0, bR1;
    float4 f0, f1, f2v, f3v;
    f0  = *(const float4*)(A + aoff);
    f1  = *(const float4*)(A + aoff + 4);
    f2v = *(const float4*)(A + aoff + 8);
    f3v = *(const float4*)(A + aoff + 12);
    bR0 = *(const uint4*)(Bp);
    bR1 = *(const uint4*)(Bp + 8);
    aR0.x = (uint32_t)f2b(f0.x)  | ((uint32_t)f2b(f0.y)  << 16);
    aR0.y = (uint32_t)f2b(f0.z)  | ((uint32_t)f2b(f0.w)  << 16);
    aR0.z = (uint32_t)f2b(f1.x)  | ((uint32_t)f2b(f1.y)  << 16);
    aR0.w = (uint32_t)f2b(f1.z)  | ((uint32_t)f2b(f1.w)  << 16);
    aR1.x = (uint32_t)f2b(f2v.x) | ((uint32_t)f2b(f2v.y) << 16);
    aR1.y = (uint32_t)f2b(f2v.z) | ((uint32_t)f2b(f2v.w) << 16);
    aR1.z = (uint32_t)f2b(f3v.x) | ((uint32_t)f2b(f3v.y) << 16);
    aR1.w = (uint32_t)f2b(f3v.z) | ((uint32_t)f2b(f3v.w) << 16);
    *(uint4*)&As[srow][sc]     = aR0;
    *(uint4*)&As[srow][sc + 8] = aR1;
    *(uint4*)&Bs[srow][sc]     = bR0;
    *(uint4*)&Bs[srow][sc + 8] = bR1;
    __syncthreads();
    for (int kc = 0; kc < kslice; kc += 64){
        bool nx = (kc + 64 < kslice);
        if (nx){
            f0  = *(const float4*)(A + aoff + kc + 64);
            f1  = *(const float4*)(A + aoff + kc + 68);
            f2v = *(const float4*)(A + aoff + kc + 72);
            f3v = *(const float4*)(A + aoff + kc + 76);
            bR0 = *(const uint4*)(Bp + kc + 64);
            bR1 = *(const uint4*)(Bp + kc + 72);
        }
        __builtin_amdgcn_s_setprio(1);
        #pragma unroll
        for (int kk = 0; kk < 2; kk++){
            short8 af0 = *(const short8*)&As[wr + l15][(kk << 5) + (quad << 3)];
            short8 af1 = *(const short8*)&As[wr + 16 + l15][(kk << 5) + (quad << 3)];
            short8 bf0 = *(const short8*)&Bs[wc + l15][(kk << 5) + (quad << 3)];
            short8 bf1 = *(const short8*)&Bs[wc + 16 + l15][(kk << 5) + (quad << 3)];
            acc[0][0] = __builtin_amdgcn_mfma_f32_16x16x32_bf16(af0, bf0, acc[0][0], 0, 0, 0);
            acc[0][1] = __builtin_amdgcn_mfma_f32_16x16x32_bf16(af0, bf1, acc[0][1], 0, 0, 0);
            acc[1][0] = __builtin_amdgcn_mfma_f32_16x16x32_bf16(af1, bf0, acc[1][0], 0, 0, 0);
            acc[1][1] = __builtin_amdgcn_mfma_f32_16x16x32_bf16(af1, bf1, acc[1][1], 0, 0, 0);
        }
        __builtin_amdgcn_s_setprio(0);
        if (nx){
            __syncthreads();
            aR0.x = (uint32_t)f2b(f0.x)  | ((uint32_t)f2b(f0.y)  << 16);
            aR0.y = (uint32_t)f2b(f0.z)  | ((uint32_t)f2b(f0.w)  << 16);
            aR0.z = (uint32_t)f2b(f1.x)  | ((uint32_t)f2b(f1.y)  << 16);
            aR0.w = (uint32_t)f2b(f1.z)  | ((uint32_t)f2b(f1.w)  << 16);
            aR1.x = (uint32_t)f2b(f2v.x) | ((uint32_t)f2b(f2v.y) << 16);
            aR1.y = (uint32_t)f2b(f2v.z) | ((uint32_t)f2b(f2v.w) << 16);
            aR1.z = (uint32_t)f2b(f3v.x) | ((uint32_t)f2b(f3v.y) << 16);
            aR1.w = (uint32_t)f2b(f3v.z) | ((uint32_t)f2b(f3v.w) << 16);
            *(uint4*)&As[srow][sc]     = aR0;
            *(uint4*)&As[srow][sc + 8] = aR1;
            *(uint4*)&Bs[srow][sc]     = bR0;
            *(uint4*)&Bs[srow][sc + 8] = bR1;
            __syncthreads();
        }
    }
    float* Pz = P + (size_t)blockIdx.z * M * N;
    #pragma unroll
    for (int mi = 0; mi < 2; mi++){
        #pragma unroll
        for (int r = 0; r < 4; r++){
            int row = gm + wr + (mi << 4) + (quad << 2) + r;
            #pragma unroll
            for (int ni = 0; ni < 2; ni++){
                int col = gn + wc + (ni << 4) + l15;
                Pz[(size_t)row * N + col] = acc[mi][ni][r];
            }
        }
    }
}

// ---------------- split-K reduce + bias + scaled ELU (conv epilogue)
__global__ __launch_bounds__(256)
void sk_reduce(const float* __restrict__ P, const float* __restrict__ bias,
               float* __restrict__ C, int MN, int S)
{
    int idx = (blockIdx.x * 256 + threadIdx.x) << 2;
    if (idx >= MN) return;
    float4 s = {0.f, 0.f, 0.f, 0.f};
    for (int z = 0; z < S; z++){
        float4 v = *(const float4*)(P + (size_t)z * MN + idx);
        s.x += v.x; s.y += v.y; s.z += v.z; s.w += v.w;
    }
    const float cscale = 0.9999950000375f;
    int col = idx & 511;
    float o[4] = {s.x, s.y, s.z, s.w};
    #pragma unroll
    for (int t = 0; t < 4; t++){
        float v = (o[t] + bias[col + t]) * cscale;
        o[t] = (v > 0.f) ? v : expm1f(v);
    }
    *(float4*)(C + idx) = (float4){o[0], o[1], o[2], o[3]};
}

// ---------------- semantic sim via split-bf16 MFMA (hi/lo precomputed)
// v2: register-staged prefetch + setprio on the 12-MFMA cluster.
__global__ __launch_bounds__(256)
void sim_mfma(const ushort* __restrict__ XH, const ushort* __restrict__ XL,
              float* __restrict__ SIM){
    __shared__ ushort Ah[64][40], Al[64][40], Bh[64][40], Bl[64][40];
    int x = blockIdx.x, b = blockIdx.y;
    int ti, tj, st, n, goff;
    if (x < 256){ ti = x >> 4; tj = x & 15; st = 0; n = 1024; goff = SG0; }
    else if (x < 272){ int y = x - 256; ti = y >> 2; tj = y & 3; st = 1024; n = 256; goff = SG1; }
    else if (x == 272){ ti = 0; tj = 0; st = 1280; n = 64; goff = SG2; }
    else { ti = 0; tj = 0; st = 1344; n = 16; goff = SG3; }
    const ushort* XbH = XH + (((size_t)b * LT + st) << 9);
    const ushort* XbL = XL + (((size_t)b * LT + st) << 9);
    float* Cb = SIM + (size_t)b * SBT + goff;
    int gm = ti << 6, gn = tj << 6;
    int tid = threadIdx.x;
    int lane = tid & 63, w = tid >> 6, quad = lane >> 4, l15 = lane & 15;
    int wr = (w >> 1) << 5, wc = (w & 1) << 5;
    int srow = tid >> 2, sc8 = (tid & 3) << 3;
    int ra = gm + srow; if (ra > n - 1) ra = n - 1;
    int rb = gn + srow; if (rb > n - 1) rb = n - 1;
    f32x4 acc[2][2];
    #pragma unroll
    for (int mi = 0; mi < 2; mi++)
        #pragma unroll
        for (int ni = 0; ni < 2; ni++)
            acc[mi][ni] = (f32x4){0.f,0.f,0.f,0.f};
    const ushort* pAh = XbH + ((size_t)ra << 9) + sc8;
    const ushort* pAl = XbL + ((size_t)ra << 9) + sc8;
    const ushort* pBh = XbH + ((size_t)rb << 9) + sc8;
    const ushort* pBl = XbL + ((size_t)rb << 9) + sc8;
    uint4 vah = *(const uint4*)pAh;
    uint4 val = *(const uint4*)pAl;
    uint4 vbh = *(const uint4*)pBh;
    uint4 vbl = *(const uint4*)pBl;
    *(uint4*)&Ah[srow][sc8] = vah;
    *(uint4*)&Al[srow][sc8] = val;
    *(uint4*)&Bh[srow][sc8] = vbh;
    *(uint4*)&Bl[srow][sc8] = vbl;
    __syncthreads();
    for (int k0 = 0; k0 < 512; k0 += 32){
        bool nx = (k0 + 32 < 512);
        if (nx){
            vah = *(const uint4*)(pAh + k0 + 32);
            val = *(const uint4*)(pAl + k0 + 32);
            vbh = *(const uint4*)(pBh + k0 + 32);
            vbl = *(const uint4*)(pBl + k0 + 32);
        }
        __builtin_amdgcn_s_setprio(1);
        short8 ah0 = *(const short8*)&Ah[wr + l15][quad << 3];
        short8 ah1 = *(const short8*)&Ah[wr + 16 + l15][quad << 3];
        short8 al0 = *(const short8*)&Al[wr + l15][quad << 3];
        short8 al1 = *(const short8*)&Al[wr + 16 + l15][quad << 3];
        short8 bh0 = *(const short8*)&Bh[wc + l15][quad << 3];
        short8 bh1 = *(const short8*)&Bh[wc + 16 + l15][quad << 3];
        short8 bl0 = *(const short8*)&Bl[wc + l15][quad << 3];
        short8 bl1 = *(const short8*)&Bl[wc + 16 + l15][quad << 3];
        acc[0][0] = __builtin_amdgcn_mfma_f32_16x16x32_bf16(ah0, bh0, acc[0][0], 0, 0, 0);
        acc[0][0] = __builtin_amdgcn_mfma_f32_16x16x32_bf16(ah0, bl0, acc[0][0], 0, 0, 0);
        acc[0][0] = __builtin_amdgcn_mfma_f32_16x16x32_bf16(al0, bh0, acc[0][0], 0, 0, 0);
        acc[0][1] = __builtin_amdgcn_mfma_f32_16x16x32_bf16(ah0, bh1, acc[0][1], 0, 0, 0);
        acc[0][1] = __builtin_amdgcn_mfma_f32_16x16x32_bf16(ah0, bl1, acc[0][1], 0, 0, 0);
        acc[0][1] = __builtin_amdgcn_mfma_f32_16x16x32_bf16(al0, bh1, acc[0][1], 0, 0, 0);
        acc[1][0] = __builtin_amdgcn_mfma_f32_16x16x32_bf16(ah1, bh0, acc[1][0], 0, 0, 0);
        acc[1][0] = __builtin_amdgcn_mfma_f32_16x16x32_bf16(ah1, bl0, acc[1][0], 0, 0, 0);
        acc[1][0] = __builtin_amdgcn_mfma_f32_16x16x32_bf16(al1, bh0, acc[1][0], 0, 0, 0);
        acc[1][1] = __builtin_amdgcn_mfma_f32_16x16x32_bf16(ah1, bh1, acc[1][1], 0, 0, 0);
        acc[1][1] = __builtin_amdgcn_mfma_f32_16x16x32_bf16(ah1, bl1, acc[1][1], 0, 0, 0);
        acc[1][1] = __builtin_amdgcn_mfma_f32_16x16x32_bf16(al1, bh1, acc[1][1], 0, 0, 0);
        __builtin_amdgcn_s_setprio(0);
        if (nx){
            __syncthreads();
            *(uint4*)&Ah[srow][sc8] = vah;
            *(uint4*)&Al[srow][sc8] = val;
            *(uint4*)&Bh[srow][sc8] = vbh;
            *(uint4*)&Bl[srow][sc8] = vbl;
            __syncthreads();
        }
    }
    #pragma unroll
    for (int mi = 0; mi < 2; mi++){
        #pragma unroll
        for (int r = 0; r < 4; r++){
            int row = gm + wr + (mi << 4) + (quad << 2) + r;
            if (row < n){
                #pragma unroll
                for (int ni = 0; ni < 2; ni++){
                    int col = gn + wc + (ni << 4) + l15;
                    if (col < n) Cb[(size_t)row * n + col] = acc[mi][ni][r];
                }
            }
        }
    }
}

// ---------------- concat conv pyramids
__global__ __launch_bounds__(256)
void pcat_copy(const float* __restrict__ C1, const float* __restrict__ C2,
               const float* __restrict__ C3, float* __restrict__ PC){
    int idx = blockIdx.x * 256 + threadIdx.x;
    int d = idx & 511;
    int r = (idx >> 9) % 336;
    int b = idx / (336 * 512);
    float v;
    if (r < 256)       v = C1[(((size_t)b * 256 + r) << 9) + d];
    else if (r < 320)  v = C2[(((size_t)b * 64 + (r - 256)) << 9) + d];
    else               v = C3[(((size_t)b * 16 + (r - 320)) << 9) + d];
    PC[idx] = v;
}

__global__ __launch_bounds__(256)
void xenc_copy(const float* __restrict__ xe, float* __restrict__ dst){
    int idx = blockIdx.x * 256 + threadIdx.x;
    int d = idx & 511;
    int l = (idx >> 9) & 1023;
    int b = idx >> 19;
    dst[(((size_t)b * LT + l) << 9) + d] = xe[idx];
}

// ---------------- LayerNorm over 512, wave per row; optional bf16 dual output
// + optional fused row-L2-normalize.
__global__ __launch_bounds__(256)
void ln_kernel(const float* __restrict__ in, const float* __restrict__ g,
               const float* __restrict__ bta, float* __restrict__ out,
               ushort* __restrict__ ob, ushort* __restrict__ xh,
               ushort* __restrict__ xl, float eps){
    int wid = threadIdx.x >> 6, lane = threadIdx.x & 63;
    int row = blockIdx.x * 4 + wid;
    const float* p = in + ((size_t)row << 9);
    float vals[8]; float s = 0.f, s2 = 0.f;
    #pragma unroll
    for (int t = 0; t < 8; t++){
        float v = p[lane + t * 64]; vals[t] = v; s += v; s2 += v * v;
    }
    #pragma unroll
    for (int off = 32; off; off >>= 1){
        s  += __shfl_xor(s,  off, 64);
        s2 += __shfl_xor(s2, off, 64);
    }
    float mu = s * (1.f / 512.f);
    float var = s2 * (1.f / 512.f) - mu * mu;
    float r = rsqrtf(var + eps);
    float* q = out + ((size_t)row << 9);
    ushort* qb = ob ? ob + ((size_t)row << 9) : nullptr;
    float nv[8]; float sn2 = 0.f;
    #pragma unroll
    for (int t = 0; t < 8; t++){
        int c = lane + t * 64;
        float v = (vals[t] - mu) * r * g[c] + bta[c];
        q[c] = v;
        if (qb) qb[c] = f2b(v);
        nv[t] = v; sn2 += v * v;
    }
    if (xh){
        #pragma unroll
        for (int off = 32; off; off >>= 1) sn2 += __shfl_xor(sn2, off, 64);
        float inv = 1.f / fmaxf(sqrtf(sn2), 1e-8f);
        ushort* qh = xh + ((size_t)row << 9);
        ushort* ql = xl + ((size_t)row << 9);
        #pragma unroll
        for (int t = 0; t < 8; t++){
            float v = nv[t] * inv;
            ushort h = f2b(v);
            qh[lane + t * 64] = h;
            ql[lane + t * 64] = f2b(v - b2f(h));
        }
    }
}

// ---------------- fused dual-LN + add3: X = (ln(in0) + ln(in1) + X)/3; bf16 out.
__global__ __launch_bounds__(256)
void ln2_add3(const float* __restrict__ in0, const float* __restrict__ in1,
              const float* __restrict__ g0, const float* __restrict__ b0,
              const float* __restrict__ g1, const float* __restrict__ b1,
              float* __restrict__ X, ushort* __restrict__ ob, float eps){
    int wid = threadIdx.x >> 6, lane = threadIdx.x & 63;
    int row = blockIdx.x * 4 + wid;
    const float* p0 = in0 + ((size_t)row << 9);
    const float* p1 = in1 + ((size_t)row << 9);
    float v0[8], v1[8];
    float s0 = 0.f, q0 = 0.f, s1 = 0.f, q1 = 0.f;
    #pragma unroll
    for (int t = 0; t < 8; t++){
        float a = p0[lane + t * 64]; v0[t] = a; s0 += a; q0 += a * a;
        float c = p1[lane + t * 64]; v1[t] = c; s1 += c; q1 += c * c;
    }
    #pragma unroll
    for (int off = 32; off; off >>= 1){
        s0 += __shfl_xor(s0, off, 64);
        q0 += __shfl_xor(q0, off, 64);
        s1 += __shfl_xor(s1, off, 64);
        q1 += __shfl_xor(q1, off, 64);
    }
    float mu0 = s0 * (1.f / 512.f);
    float r0 = rsqrtf(q0 * (1.f / 512.f) - mu0 * mu0 + eps);
    float mu1 = s1 * (1.f / 512.f);
    float r1 = rsqrtf(q1 * (1.f / 512.f) - mu1 * mu1 + eps);
    float* xp = X + ((size_t)row << 9);
    ushort* qb = ob + ((size_t)row << 9);
    #pragma unroll
    for (int t = 0; t < 8; t++){
        int c = lane + t * 64;
        float sn0 = (v0[t] - mu0) * r0 * g0[c] + b0[c];
        float sn1 = (v1[t] - mu1) * r1 * g1[c] + b1[c];
        float nv = (sn0 + sn1 + xp[c]) * (1.f / 3.f);
        xp[c] = nv;
        qb[c] = f2b(nv);
    }
}

// ---------------- top-k v2: per-lane bitonic sort + xor-butterfly bitonic
// top-32 merge -> exact 32nd-largest V32; ballot-built mask words.
__global__ __launch_bounds__(256)
void topk_sel(const float* __restrict__ SIM, u64* __restrict__ MB){
    int wid = threadIdx.x >> 6, lane = threadIdx.x & 63;
    int r = blockIdx.x * 4 + wid;        // 0..B*LT-1
    int b = r / LT, i = r % LT;
    int bi, st, n; blk_info(i, bi, st, n);
    u64* mrow = MB + ((size_t)b * LT + i) * MBW;
    if (n == 16){                         // all 16 in-block keys banned
        u64 myw = 0;
        if (lane == 21) myw = ~0ULL;
        if (lane < MBW) mrow[lane] = myw;
        return;
    }
    int goff = (bi == 0) ? SG0 : (bi == 1) ? SG1 : SG2;
    const float* srow = SIM + (size_t)b * SBT + goff + (size_t)(i - st) * n;
    int ns = n >> 6;
    float vals[16];
    #pragma unroll
    for (int t = 0; t < 16; t++)
        vals[t] = (t < ns) ? srow[lane + (t << 6)] : -FLT_MAX;

    float c[32];
    #pragma unroll
    for (int t = 0; t < 16; t++) c[t] = vals[t];
    #pragma unroll
    for (int k = 2; k <= 16; k <<= 1){
        #pragma unroll
        for (int j = k >> 1; j > 0; j >>= 1){
            #pragma unroll
            for (int t = 0; t < 16; t++){
                int l = t ^ j;
                if (l > t){
                    float lo = fminf(c[t], c[l]);
                    float hi = fmaxf(c[t], c[l]);
                    if ((t & k) == 0){ c[t] = hi; c[l] = lo; }
                    else             { c[t] = lo; c[l] = hi; }
                }
            }
        }
    }
    #pragma unroll
    for (int t = 16; t < 32; t++) c[t] = -FLT_MAX;

    float V32;
    #pragma unroll
    for (int rd = 0; rd < 6; rd++){
        float f[32];
        #pragma unroll
        for (int t = 0; t < 32; t++) f[t] = __shfl_xor(c[t], 1 << rd, 64);
        float m[32];
        #pragma unroll
        for (int t = 0; t < 32; t++) m[t] = fmaxf(c[t], f[31 - t]);
        if (rd < 5){
            #pragma unroll
            for (int d = 16; d >= 1; d >>= 1){
                #pragma unroll
                for (int t = 0; t < 32; t++){
                    if ((t & d) == 0){
                        float lo = fminf(m[t], m[t + d]);
                        m[t] = fmaxf(m[t], m[t + d]);
                        m[t + d] = lo;
                    }
                }
            }
            #pragma unroll
            for (int t = 0; t < 32; t++) c[t] = m[t];
        } else {
            float mn = m[0];
            #pragma unroll
            for (int t = 1; t < 32; t++) mn = fminf(mn, m[t]);
            V32 = mn;
        }
    }

    int cnt_gt = 0;
    #pragma unroll
    for (int t = 0; t < 16; t++){
        u64 bg = __ballot(vals[t] > V32);
        cnt_gt += __popcll(bg);
    }
    int need = 32 - cnt_gt;
    u64 lmask = (1ULL << lane) - 1;
    u64 myw = 0;
    if (lane == 21) myw = 0xFFFFFFFFFFFF0000ULL;   // pad: keys 1360..1407 banned
    int eqrun = 0;
    int w0 = st >> 6;
    #pragma unroll
    for (int t = 0; t < 16; t++){
        bool eq = (vals[t] == V32);
        u64 beq = __ballot(eq);
        int below = __popcll(beq & lmask);
        bool sel = (vals[t] > V32) || (eq && (eqrun + below) < need);
        eqrun += __popcll(beq);
        u64 wsel = __ballot(sel);
        if (t < ns && lane == w0 + t) myw = wsel;
    }
    if (lane < MBW) mrow[lane] = myw;
}

// ---------------- FUSED attention dispatch: blocks [0,NFLASH) run flash
// (branch 1); blocks [NFLASH, ...) run sparse temporal attention (branch 0).
// Double-buffered flash (R12-best). R13 single-buffer regressed; do not revisit.
__global__ __launch_bounds__(256)
void attn_fused(const ushort* __restrict__ U, const u64* __restrict__ MB,
                const int* __restrict__ IDX, const int* __restrict__ CNT,
                ushort* __restrict__ AO0, ushort* __restrict__ AO1)
{
    __shared__ ushort Ks[2][64][76];
    __shared__ ushort Vs[2][64][76];
    if (blockIdx.x < NFLASH){
        // ================= flash branch (v5 body, flattened grid) =========
        const ushort* Q  = U + (size_t)NBLE;
        const ushort* Kp = U + (size_t)3*NBLE;
        const ushort* Vt = U + (size_t)4*NBLE;
        int fid = blockIdx.x;
        int bh = fid & 31, b = bh >> 3, h = bh & 7;
        int q0 = (fid >> 5) << 6;
        int tid = threadIdx.x;
        int w = tid >> 6, lane = tid & 63, quad = lane >> 4, l15 = lane & 15;

        int qm = q0 + w * 16 + l15;
        int qmc = (qm < LT) ? qm : (LT - 1);
        const ushort* qp = Q + ((size_t)(b * LT + qmc) << 9) + h * 64 + (quad << 3);
        short8 qf0 = *(const short8*)qp;
        short8 qf1 = *(const short8*)(qp + 32);

        float l_part = 0.f;
        f32x4 Oacc[4];
        #pragma unroll
        for (int dt = 0; dt < 4; dt++) Oacc[dt] = (f32x4){0.f,0.f,0.f,0.f};

        int srow = tid >> 2, sc = (tid & 3) << 4;

        const ushort* kpp = Kp + ((size_t)(b * LT + srow) << 9) + h * 64 + sc;
        const ushort* vpp = Vt + (size_t)(b * 512 + h * 64 + srow) * LT + sc;
        const u64* mpp = MB + ((size_t)b * LT + qmc) * MBW;

        int srcA = ((quad & 1) << 5) + l15;
        int srcB = srcA + 16;
        bool ntHi = (quad & 2) != 0;

        {
            uint4 k0v = *(const uint4*)kpp;
            uint4 k1v = *(const uint4*)(kpp + 8);
            uint4 v0v = *(const uint4*)vpp;
            uint4 v1v = *(const uint4*)(vpp + 8);
            kpp += 64 * 512; vpp += 64;
            *(uint4*)&Ks[0][srow][sc]     = k0v;
            *(uint4*)&Ks[0][srow][sc + 8] = k1v;
            *(uint4*)&Vs[0][srow][sc]     = v0v;
            *(uint4*)&Vs[0][srow][sc + 8] = v1v;
        }
        __syncthreads();

        for (int kt = 0; kt < 22; kt++){
            int cur = kt & 1;
            bool havenext = (kt + 1 < 22);
            uint4 kn0, kn1, vn0, vn1;
            if (havenext){
                kn0 = *(const uint4*)kpp;
                kn1 = *(const uint4*)(kpp + 8);
                vn0 = *(const uint4*)vpp;
                vn1 = *(const uint4*)(vpp + 8);
                kpp += 64 * 512; vpp += 64;
            }
            u64 mw = mpp[kt];
            f32x4 s[4];
            #pragma unroll
            for (int nt = 0; nt < 4; nt++) s[nt] = (f32x4){0.f,0.f,0.f,0.f};
            __builtin_amdgcn_s_setprio(1);
            #pragma unroll
            for (int nt = 0; nt < 4; nt++){
                short8 kf0 = *(const short8*)&Ks[cur][(nt << 4) + l15][quad << 3];
                short8 kf1 = *(const short8*)&Ks[cur][(nt << 4) + l15][32 + (quad << 3)];
                s[nt] = __builtin_amdgcn_mfma_f32_16x16x32_bf16(kf0, qf0, s[nt], 0, 0, 0);
                s[nt] = __builtin_amdgcn_mfma_f32_16x16x32_bf16(kf1, qf1, s[nt], 0, 0, 0);
            }
            __builtin_amdgcn_s_setprio(0);
            u64 msh = mw >> (quad << 2);
            uint32_t pk01[4], pk23[4];
            #pragma unroll
            for (int nt = 0; nt < 4; nt++){
                float p0 = ((uint32_t)(msh >> (nt * 16 + 0)) & 1u) ? 0.f : ex2(s[nt][0]);
                float p1 = ((uint32_t)(msh >> (nt * 16 + 1)) & 1u) ? 0.f : ex2(s[nt][1]);
                float p2 = ((uint32_t)(msh >> (nt * 16 + 2)) & 1u) ? 0.f : ex2(s[nt][2]);
                float p3 = ((uint32_t)(msh >> (nt * 16 + 3)) & 1u) ? 0.f : ex2(s[nt][3]);
                l_part += (p0 + p1) + (p2 + p3);
                pk01[nt] = pkbf(p0, p1);
                pk23[nt] = pkbf(p2, p3);
            }
            uint4 pa, pb;
            {
                uint32_t t0, t1;
                t0 = __shfl(pk01[0], srcA, 64); t1 = __shfl(pk01[1], srcA, 64);
                pa.x = ntHi ? t1 : t0;
                t0 = __shfl(pk23[0], srcA, 64); t1 = __shfl(pk23[1], srcA, 64);
                pa.y = ntHi ? t1 : t0;
                t0 = __shfl(pk01[0], srcB, 64); t1 = __shfl(pk01[1], srcB, 64);
                pa.z = ntHi ? t1 : t0;
                t0 = __shfl(pk23[0], srcB, 64); t1 = __shfl(pk23[1], srcB, 64);
                pa.w = ntHi ? t1 : t0;
                t0 = __shfl(pk01[2], srcA, 64); t1 = __shfl(pk01[3], srcA, 64);
                pb.x = ntHi ? t1 : t0;
                t0 = __shfl(pk23[2], srcA, 64); t1 = __shfl(pk23[3], srcA, 64);
                pb.y = ntHi ? t1 : t0;
                t0 = __shfl(pk01[2], srcB, 64); t1 = __shfl(pk01[3], srcB, 64);
                pb.z = ntHi ? t1 : t0;
                t0 = __shfl(pk23[2], srcB, 64); t1 = __shfl(pk23[3], srcB, 64);
                pb.w = ntHi ? t1 : t0;
            }
            short8 pf0 = *(const short8*)&pa;
            short8 pf1 = *(const short8*)&pb;
            __builtin_amdgcn_s_setprio(1);
            #pragma unroll
            for (int dt = 0; dt < 4; dt++){
                short8 vf0 = *(const short8*)&Vs[cur][(dt << 4) + l15][quad << 3];
                short8 vf1 = *(const short8*)&Vs[cur][(dt << 4) + l15][32 + (quad << 3)];
                Oacc[dt] = __builtin_amdgcn_mfma_f32_16x16x32_bf16(pf0, vf0, Oacc[dt], 0, 0, 0);
                Oacc[dt] = __builtin_amdgcn_mfma_f32_16x16x32_bf16(pf1, vf1, Oacc[dt], 0, 0, 0);
            }
            __builtin_amdgcn_s_setprio(0);
            if (havenext){
                int nb = cur ^ 1;
                *(uint4*)&Ks[nb][srow][sc]     = kn0;
                *(uint4*)&Ks[nb][srow][sc + 8] = kn1;
                *(uint4*)&Vs[nb][srow][sc]     = vn0;
                *(uint4*)&Vs[nb][srow][sc + 8] = vn1;
            }
            __syncthreads();
        }
        l_part += __shfl_xor(l_part, 16, 64);
        l_part += __shfl_xor(l_part, 32, 64);
        #pragma unroll
        for (int r = 0; r < 4; r++){
            int qrow = q0 + (w << 4) + (quad << 2) + r;
            if (qrow < LT){
                float lr = __shfl(l_part, (lane & 48) + (quad << 2) + r, 64);
                float inv = 1.f / lr;
                #pragma unroll
                for (int dt = 0; dt < 4; dt++)
                    AO1[((size_t)(b * LT + qrow) << 9) + h * 64 + (dt << 4) + l15] =
                        f2b(Oacc[dt][r] * inv);
            }
        }
    } else {
        // ================= sparse branch v2: quad-parallel keys ===========
        const ushort* Q  = U;
        const ushort* Kp = U + (size_t)2*NBLE;
        const ushort* Vn = U + (size_t)5*NBLE;
        int wid = threadIdx.x >> 6, lane = threadIdx.x & 63;
        int row = (blockIdx.x - NFLASH) * 4 + wid;
        int b = row / (NHH * LT);
        int rem = row % (NHH * LT);
        int h = rem / LT, i = rem % LT;
        int c = CNT[i];
        int quad = lane >> 4, l15 = lane & 15;
        int d0 = l15 << 2;                 // 4 consecutive d per lane
        int jl = IDX[i * 12 + (lane % 12)];
        const ushort* qp = Q + (((size_t)b * LT + i) << 9) + h * 64 + d0;
        uint2 qv = *(const uint2*)qp;
        float qd0 = b2f((ushort)qv.x), qd1 = b2f((ushort)(qv.x >> 16));
        float qd2 = b2f((ushort)qv.y), qd3 = b2f((ushort)(qv.y >> 16));
        const ushort* kb = Kp + (((size_t)b * LT) << 9) + h * 64 + d0;
        const ushort* vb = Vn + (((size_t)b * LT) << 9) + h * 64 + d0;
        float o0 = 0.f, o1 = 0.f, o2 = 0.f, o3 = 0.f;
        float lsum = 0.f;
        #pragma unroll
        for (int rr = 0; rr < 3; rr++){
            int t = (rr << 2) + quad;      // this quad's key index
            int j = __shfl(jl, t, 64);
            uint2 kv2 = *(const uint2*)(kb + ((size_t)j << 9));
            uint2 vv2 = *(const uint2*)(vb + ((size_t)j << 9));
            float s = qd0 * b2f((ushort)kv2.x) + qd1 * b2f((ushort)(kv2.x >> 16))
                    + qd2 * b2f((ushort)kv2.y) + qd3 * b2f((ushort)(kv2.y >> 16));
            s += __shfl_xor(s, 1, 64);
            s += __shfl_xor(s, 2, 64);
            s += __shfl_xor(s, 4, 64);
            s += __shfl_xor(s, 8, 64);     // intra-quad reduce (offsets < 16)
            float p = (t < c) ? ex2(s) : 0.f;
            lsum += p;
            o0 += p * b2f((ushort)vv2.x);
            o1 += p * b2f((ushort)(vv2.x >> 16));
            o2 += p * b2f((ushort)vv2.y);
            o3 += p * b2f((ushort)(vv2.y >> 16));
        }
        // cross-quad reduce: total over all 12 keys for each d-slot
        o0 += __shfl_xor(o0, 16, 64); o0 += __shfl_xor(o0, 32, 64);
        o1 += __shfl_xor(o1, 16, 64); o1 += __shfl_xor(o1, 32, 64);
        o2 += __shfl_xor(o2, 16, 64); o2 += __shfl_xor(o2, 32, 64);
        o3 += __shfl_xor(o3, 16, 64); o3 += __shfl_xor(o3, 32, 64);
        lsum += __shfl_xor(lsum, 16, 64);
        lsum += __shfl_xor(lsum, 32, 64);
        float inv = 1.f / lsum;
        if (quad == 0){
            uint2 ov;
            ov.x = pkbf(o0 * inv, o1 * inv);
            ov.y = pkbf(o2 * inv, o3 * inv);
            *(uint2*)(AO0 + (((size_t)b * LT + i) << 9) + h * 64 + d0) = ov;
        }
    }
}

extern "C" void kernel_launch(void* const* d_in, const int* in_sizes, int n_in,
                              void* d_out, int out_size, void* d_ws, size_t ws_size,
                              hipStream_t stream)
{
    const float* x_enc   = (const float*)d_in[0];
    const float* down_W  = (const float*)d_in[1];
    const float* down_b  = (const float*)d_in[2];
    const float* conv_W  = (const float*)d_in[3];
    const float* conv_b  = (const float*)d_in[4];
    const float* up_W    = (const float*)d_in[5];
    const float* up_b    = (const float*)d_in[6];
    const float* bc_g    = (const float*)d_in[7];
    const float* bc_b    = (const float*)d_in[8];
    const float* aWq     = (const float*)d_in[9];
    const float* aWk     = (const float*)d_in[10];
    const float* aWv     = (const float*)d_in[11];
    const float* afcW    = (const float*)d_in[12];
    const float* afcb    = (const float*)d_in[13];
    const float* alng    = (const float*)d_in[14];
    const float* alnb    = (const float*)d_in[15];
    const float* fW1     = (const float*)d_in[16];
    const float* fb1     = (const float*)d_in[17];
    const float* fW2     = (const float*)d_in[18];
    const float* fb2     = (const float*)d_in[19];
    const float* flng    = (const float*)d_in[20];
    const float* flnb    = (const float*)d_in[21];

    const size_t NBL = (size_t)NBLE;
    float* X   = (float*)d_ws;
    float* TMP = X   + NBL;
    float* Qb  = TMP + NBL;
    float* Kb  = Qb  + NBL;
    float* Vb  = Kb  + NBL;
    float* AO  = Vb  + NBL;
    float* TO  = AO  + NBL;
    float* SO  = TO  + NBL;
    u64* MBm = (u64*)(SO + NBL);                      // B*LT*24 words
    int* TIDX = (int*)(MBm + (size_t)BB * LT * MBW);
    int* TCNT = TIDX + (size_t)LT * 12;
    ushort* WG = (ushort*)(TCNT + LT);
    const size_t M512 = 262144;
    ushort* WdownT = WG;                 size_t wo = M512;
    ushort* WupT   = WG + wo;            wo += M512;
    ushort* Wqkv   = WG + wo;            wo += 12 * M512;   // 4 layers x [Wq|Wk|Wv]^T
    ushort* WfT    = WG + wo;            wo += 4 * M512;
    ushort* W1T    = WG + wo;            wo += 2 * M512;
    ushort* W2T    = WG + wo;            wo += 2 * M512;
    ushort* WCt    = WG + wo;            wo += 3 * 1048576;
    float* LP = (float*)(WG + wo);                        // (kept for sizing)
    (void)LP;
    size_t need = 8 * NBL * sizeof(float) + (size_t)BB * LT * MBW * 8
                + (size_t)LT * 13 * 4 + wo * sizeof(ushort)
                + (size_t)2 * BB * NHH * LT * 4;
    if (ws_size < need) return;

    // aliases (lifetimes disjoint)
    float* Y    = Qb;
    float* C1   = Kb;
    float* C2   = C1 + (size_t)BB*256*512;
    float* C3   = C2 + (size_t)BB*64*512;
    float* PCAT = Vb;
    float* SKP  = AO;                     // split-K partials (bottleneck only)
    ushort* XNh = (ushort*)AO;            // hi/lo bf16 normalized rows
    ushort* XNl = XNh + NBLE;
    float* SIMB = Qb;
    ushort* U   = (ushort*)Qb;            // merged QKV: Q0@0 Q1@N K0@2N K1@3N Vt1@4N Vn0@5N
    ushort* XB  = (ushort*)SO;            // bf16 X (QKV/FFN1 A-operand)
    ushort* AOb0 = (ushort*)AO;           // branch0 attention out [0,N)
    ushort* AOb1 = AOb0 + NBLE;           // branch1 attention out [N,2N)
    ushort* HfB = (ushort*)Qb;            // bf16 FFN hidden
    float* TMP1 = TO;                     // second fc output (TO region reused)

    auto gemmN = [&](const void* A, int abf, const ushort* Bw, const float* bias,
                     const float* res, void* C, int M,
                     int act, int omode, int mpb, int orpb, int ooff){
        dim3 grid(8, M / 64);
        if (abf) gemm64t<1><<<grid, 256, 0, stream>>>(A, Bw, bias, res, C, M, 512, 512,
                                                      act, omode, mpb, orpb, ooff);
        else     gemm64t<0><<<grid, 256, 0, stream>>>(A, Bw, bias, res, C, M, 512, 512,
                                                      act, omode, mpb, orpb, ooff);
    };
    auto convG = [&](const float* A, const ushort* Bw, const float* bias,
                     float* C, int M){
        const int S = 8, K = 2048, N = 512;
        gemm_sk<<<dim3(8, M / 64, S), 256, 0, stream>>>(A, Bw, SKP, M, N, K, K / S);
        sk_reduce<<<(M * N) / 1024, 256, 0, stream>>>(SKP, bias, C, M * N, S);
    };

    build_tidx<<<(LT + 255) / 256, 256, 0, stream>>>(TIDX, TCNT);
    // single-dispatch weight prep: 22 matrices x 64 tiles (was 8 launches)
    wtrans_all<<<1408, 256, 0, stream>>>(down_W, up_W, aWq, aWk, aWv, afcW,
                                         fW1, fW2, WdownT, WupT, Wqkv, WfT,
                                         W1T, W2T);
    wconv<<<dim3(4096, 3), 256, 0, stream>>>(conv_W, WCt);

    // ---- bottleneck
    gemmN(x_enc, 0, WdownT, down_b, nullptr, Y, BB*1024, 0, 0, 0, 0, 0);
    convG(Y,  WCt,             conv_b + 0,    C1, BB*256);
    convG(C1, WCt + 1048576,   conv_b + 512,  C2, BB*64);
    convG(C2, WCt + 2*1048576, conv_b + 1024, C3, BB*16);
    pcat_copy<<<(BB*336*512)/256, 256, 0, stream>>>(C1, C2, C3, PCAT);
    gemmN(PCAT, 0, WupT, up_b, nullptr, TMP, BB*336, 0, 0, 336, LT, 1024);
    xenc_copy<<<(BB*1024*512)/256, 256, 0, stream>>>(x_enc, TMP);
    // ln with fused rownorm (XNh/XNl for layer-0 sim)
    ln_kernel<<<(BB*LT)/4, 256, 0, stream>>>(TMP, bc_g, bc_b, X, XB, XNh, XNl, 1e-5f);

    // ---- transformer layers
    for (int l = 0; l < 2; l++){
        sim_mfma<<<dim3(274, BB), 256, 0, stream>>>(XNh, XNl, SIMB);
        topk_sel<<<(BB*LT)/4, 256, 0, stream>>>(SIMB, MBm);

        // merged dual-QKV (both branches) from bf16 X
        gemm_qkv<<<dim3(24, 85), 256, 0, stream>>>(XB, Wqkv + (size_t)l * 6 * M512,
                                                   U, BB*LT, 3072, 512);
        // fused attention: flash (704 blocks) + sparse (10880 blocks)
        attn_fused<<<dim3(NFLASH + (BB*NHH*LT)/4), 256, 0, stream>>>(
            U, MBm, TIDX, TCNT, AOb0, AOb1);
        // both output projections in one launch
        gemm_fc2<<<dim3(8, 85, 2), 256, 0, stream>>>(AOb0, AOb1,
            WfT + (size_t)(2*l) * M512, WfT + (size_t)(2*l + 1) * M512,
            afcb + (size_t)(2*l) * 512, afcb + (size_t)(2*l + 1) * 512,
            X, TMP, TMP1, BB*LT, 512, 512);
        // fused dual-LN + add3
        ln2_add3<<<(BB*LT)/4, 256, 0, stream>>>(TMP, TMP1,
            alng + (size_t)(2*l) * 512, alnb + (size_t)(2*l) * 512,
            alng + (size_t)(2*l + 1) * 512, alnb + (size_t)(2*l + 1) * 512,
            X, XB, 1e-6f);

        // FFN (bf16 A everywhere)
        gemmN(XB,  1, W1T + (size_t)l * M512, fb1 + (size_t)l*512, nullptr, HfB, BB*LT, 2, 1, 0, 0, 0);
        gemmN(HfB, 1, W2T + (size_t)l * M512, fb2 + (size_t)l*512, X, TMP, BB*LT, 0, 0, 0, 0, 0);
        // final ln: fused rownorm only when a next layer consumes XNh/XNl
        ln_kernel<<<(BB*LT)/4, 256, 0, stream>>>(TMP, flng + (size_t)l*512, flnb + (size_t)l*512,
                                                 (l == 1) ? (float*)d_out : X,
                                                 (l == 1) ? nullptr : XB,
                                                 (l == 1) ? nullptr : XNh,
                                                 (l == 1) ? nullptr : XNl, 1e-6f);
    }
}